// Round 2
// baseline (2361.570 us; speedup 1.0000x reference)
//
#include <hip/hip_runtime.h>
#include <math.h>
#include <float.h>

#define NPIX 16384
#define CC 192
#define BB 4
#define HHH 128
#define WWW 128
#define HID 510
#define HID2 1020
#define KKEEP 172
#define KSPLIT 16

// ---------------- conv1x1 / channel-mix GEMM ----------------
// Y[b,co,p] = sum_ci W[co,ci] * X[b,ci,p] + bias[co] (+ res)
template<int CO_TILE, bool PER_BATCH_W, bool ADD_RES>
__global__ __launch_bounds__(256) void k_conv1x1(
    const float* __restrict__ X, const float* __restrict__ W,
    const float* __restrict__ bias, const float* __restrict__ res,
    float* __restrict__ Y, int Cin, int Cout)
{
  const int b = blockIdx.z;
  const int co0 = blockIdx.x * CO_TILE;
  const int p = blockIdx.y * 1024 + threadIdx.x * 4;
  const float* Wb = W + (PER_BATCH_W ? (size_t)b * Cout * Cin : 0);
  float4 acc[CO_TILE];
  #pragma unroll
  for (int j = 0; j < CO_TILE; ++j) acc[j] = make_float4(0.f, 0.f, 0.f, 0.f);
  const float* Xb = X + (size_t)b * Cin * NPIX + p;
  for (int ci = 0; ci < Cin; ++ci) {
    const float4 x4 = *reinterpret_cast<const float4*>(Xb + (size_t)ci * NPIX);
    #pragma unroll
    for (int j = 0; j < CO_TILE; ++j) {
      const float w = Wb[(co0 + j) * Cin + ci];  // block-uniform -> scalar load
      acc[j].x += w * x4.x; acc[j].y += w * x4.y;
      acc[j].z += w * x4.z; acc[j].w += w * x4.w;
    }
  }
  #pragma unroll
  for (int j = 0; j < CO_TILE; ++j) {
    const int co = co0 + j;
    float4 o = acc[j];
    const float bv = bias[co];
    o.x += bv; o.y += bv; o.z += bv; o.w += bv;
    if (ADD_RES) {
      const float4 r = *reinterpret_cast<const float4*>(res + (size_t)(b * Cout + co) * NPIX + p);
      o.x += r.x; o.y += r.y; o.z += r.z; o.w += r.w;
    }
    *reinterpret_cast<float4*>(Y + (size_t)(b * Cout + co) * NPIX + p) = o;
  }
}

// ---------------- depthwise 3x3 helper (4 horizontal pixels) ----------------
__device__ __forceinline__ void dw4(const float* __restrict__ Xc,
                                    const float* __restrict__ wt, float bv,
                                    int h, int w, float out[4])
{
  float a0, a1, a2, a3;
  a0 = a1 = a2 = a3 = bv;
  #pragma unroll
  for (int dy = 0; dy < 3; ++dy) {
    const int hh = h + dy - 1;
    if (hh < 0 || hh >= HHH) continue;
    const float* row = Xc + hh * WWW + w;
    const float xm = (w > 0) ? row[-1] : 0.f;
    const float4 xc = *reinterpret_cast<const float4*>(row);
    const float xp = (w < WWW - 4) ? row[4] : 0.f;
    const float w0 = wt[dy * 3 + 0], w1 = wt[dy * 3 + 1], w2 = wt[dy * 3 + 2];
    a0 += w0 * xm   + w1 * xc.x + w2 * xc.y;
    a1 += w0 * xc.x + w1 * xc.y + w2 * xc.z;
    a2 += w0 * xc.y + w1 * xc.z + w2 * xc.w;
    a3 += w0 * xc.z + w1 * xc.w + w2 * xp;
  }
  out[0] = a0; out[1] = a1; out[2] = a2; out[3] = a3;
}

__global__ __launch_bounds__(256) void k_dw3x3(
    const float* __restrict__ X, const float* __restrict__ W9,
    const float* __restrict__ bias, float* __restrict__ Y, int Cn)
{
  const int b = blockIdx.z, c = blockIdx.y;
  const int p = blockIdx.x * 1024 + threadIdx.x * 4;
  const int h = p >> 7, w = p & 127;
  const float* Xc = X + (size_t)(b * Cn + c) * NPIX;
  float o[4];
  dw4(Xc, W9 + c * 9, bias[c], h, w, o);
  *reinterpret_cast<float4*>(Y + (size_t)(b * Cn + c) * NPIX + p) =
      make_float4(o[0], o[1], o[2], o[3]);
}

// ---------------- row L2 norm (reciprocal) ----------------
__global__ __launch_bounds__(256) void k_rownorm(const float* __restrict__ X,
                                                 float* __restrict__ R)
{
  const int row = blockIdx.x;
  const float* Xr = X + (size_t)row * NPIX;
  float s = 0.f;
  for (int i = threadIdx.x * 4; i < NPIX; i += 1024) {
    const float4 v = *reinterpret_cast<const float4*>(Xr + i);
    s += v.x * v.x + v.y * v.y + v.z * v.z + v.w * v.w;
  }
  __shared__ float sm[256];
  sm[threadIdx.x] = s; __syncthreads();
  for (int st = 128; st > 0; st >>= 1) {
    if (threadIdx.x < st) sm[threadIdx.x] += sm[threadIdx.x + st];
    __syncthreads();
  }
  if (threadIdx.x == 0) R[row] = 1.f / fmaxf(sqrtf(sm[0]), 1e-12f);
}

// ---------------- attn logits, split-K partial GEMM ----------------
__global__ __launch_bounds__(256) void k_attn_partial(
    const float* __restrict__ q, const float* __restrict__ k,
    float* __restrict__ part)
{
  const int b = blockIdx.z;
  const int tr = blockIdx.x / 3, tc = blockIdx.x % 3;
  const int r0 = tr * 64, c0 = tc * 64;
  const int k0 = blockIdx.y * (NPIX / KSPLIT);
  __shared__ float qs[64][33];
  __shared__ float ks[64][33];
  const int tid = threadIdx.x;
  const int ty = tid >> 4, tx = tid & 15;
  float acc[4][4];
  #pragma unroll
  for (int i = 0; i < 4; ++i)
    #pragma unroll
    for (int j = 0; j < 4; ++j) acc[i][j] = 0.f;
  for (int kc = 0; kc < NPIX / KSPLIT; kc += 32) {
    #pragma unroll
    for (int i = 0; i < 8; ++i) {
      const int idx = tid + i * 256;
      const int r = idx >> 5, kk = idx & 31;
      qs[r][kk] = q[(size_t)(b * CC + r0 + r) * NPIX + k0 + kc + kk];
      ks[r][kk] = k[(size_t)(b * CC + c0 + r) * NPIX + k0 + kc + kk];
    }
    __syncthreads();
    #pragma unroll 8
    for (int kk = 0; kk < 32; ++kk) {
      float av[4], bv[4];
      #pragma unroll
      for (int i = 0; i < 4; ++i) av[i] = qs[ty * 4 + i][kk];
      #pragma unroll
      for (int j = 0; j < 4; ++j) bv[j] = ks[tx * 4 + j][kk];
      #pragma unroll
      for (int i = 0; i < 4; ++i)
        #pragma unroll
        for (int j = 0; j < 4; ++j) acc[i][j] += av[i] * bv[j];
    }
    __syncthreads();
  }
  float* pp = part + (size_t)(blockIdx.y * BB + b) * CC * CC;
  #pragma unroll
  for (int i = 0; i < 4; ++i)
    #pragma unroll
    for (int j = 0; j < 4; ++j)
      pp[(r0 + ty * 4 + i) * CC + c0 + tx * 4 + j] = acc[i][j];
}

// ---------------- reduce + scale + softmax + topk mask ----------------
__global__ __launch_bounds__(192) void k_softmax_topk(
    const float* __restrict__ part, const float* __restrict__ rq,
    const float* __restrict__ rk, const float* __restrict__ temp,
    float* __restrict__ attnm)
{
  const int c = blockIdx.x, b = blockIdx.y, d = threadIdx.x;
  float s = 0.f;
  for (int ksp = 0; ksp < KSPLIT; ++ksp)
    s += part[(size_t)(ksp * BB + b) * CC * CC + c * CC + d];
  const float logit = s * rq[b * CC + c] * rk[b * CC + d] * temp[0];
  __shared__ float sa[CC], sb[CC];
  sa[d] = logit; __syncthreads();
  float mx = -FLT_MAX;
  for (int j = 0; j < CC; ++j) mx = fmaxf(mx, sa[j]);
  const float e = expf(logit - mx);
  sb[d] = e; __syncthreads();
  float sum = 0.f;
  for (int j = 0; j < CC; ++j) sum += sb[j];
  const float pv = e / sum;
  __syncthreads();
  sa[d] = pv; __syncthreads();
  int greater = 0;
  for (int j = 0; j < CC; ++j) greater += (sa[j] > pv) ? 1 : 0;
  const float cand = (greater < KKEEP) ? pv : FLT_MAX;
  sb[d] = cand; __syncthreads();
  float thr = FLT_MAX;
  for (int j = 0; j < CC; ++j) thr = fminf(thr, sb[j]);
  attnm[(size_t)(b * CC + c) * CC + d] = (pv >= thr) ? pv : 0.f;
}

// ---------------- M[b] = ow @ attnm[b] ----------------
__global__ __launch_bounds__(192) void k_mix(
    const float* __restrict__ ow, const float* __restrict__ attnm,
    float* __restrict__ M)
{
  const int c = blockIdx.x, b = blockIdx.y, d = threadIdx.x;
  float acc = 0.f;
  for (int e = 0; e < CC; ++e)
    acc += ow[c * CC + e] * attnm[(size_t)(b * CC + e) * CC + d];
  M[(size_t)(b * CC + c) * CC + d] = acc;
}

// ---------------- LayerNorm over channels (per pixel) ----------------
__global__ __launch_bounds__(256) void k_ln(
    const float* __restrict__ X, const float* __restrict__ lw,
    const float* __restrict__ lb, float* __restrict__ Y)
{
  const int b = blockIdx.y;
  const int n = blockIdx.x * 256 + threadIdx.x;
  const float* Xb = X + (size_t)b * CC * NPIX + n;
  float s = 0.f, s2 = 0.f;
  for (int ci = 0; ci < CC; ++ci) {
    const float v = Xb[(size_t)ci * NPIX];
    s += v; s2 += v * v;
  }
  const float mu = s * (1.f / CC);
  const float var = fmaxf(s2 * (1.f / CC) - mu * mu, 0.f);
  const float rstd = rsqrtf(var + 1e-5f);
  float* Yb = Y + (size_t)b * CC * NPIX + n;
  for (int ci = 0; ci < CC; ++ci) {
    const float v = Xb[(size_t)ci * NPIX];
    Yb[(size_t)ci * NPIX] = (v - mu) * rstd * lw[ci] + lb[ci];
  }
}

// ---------------- fused depthwise 3x3 + GLU ----------------
__device__ __forceinline__ float gelu_exact(float x) {
  return 0.5f * x * (1.f + erff(x * 0.70710678118654752f));
}

__global__ __launch_bounds__(256) void k_dwglu(
    const float* __restrict__ Hf, const float* __restrict__ W9,
    const float* __restrict__ bias, float* __restrict__ G)
{
  const int b = blockIdx.z, c = blockIdx.y;  // c in [0, HID)
  const int p = blockIdx.x * 1024 + threadIdx.x * 4;
  const int h = p >> 7, w = p & 127;
  float o1[4], o2[4];
  dw4(Hf + (size_t)(b * HID2 + c) * NPIX,        W9 + c * 9,          bias[c],        h, w, o1);
  dw4(Hf + (size_t)(b * HID2 + c + HID) * NPIX,  W9 + (c + HID) * 9,  bias[c + HID],  h, w, o2);
  float4 o;
  o.x = o1[0] * gelu_exact(o2[0]);
  o.y = o1[1] * gelu_exact(o2[1]);
  o.z = o1[2] * gelu_exact(o2[2]);
  o.w = o1[3] * gelu_exact(o2[3]);
  *reinterpret_cast<float4*>(G + (size_t)(b * HID + c) * NPIX + p) = o;
}

// ---------------- launch ----------------
// Workspace budget (peak 2S + 100.3 MB = 200,933,376 B ~= 192 MiB):
//   bufA [0,S)        : q  -> Fa (residual, live through final conv)
//   bufB [S,2S)       : k  -> xn
//   bufC [2S,3S)      : v  (dead after Fa GEMM)
//   smalls [3S, 3S+10.7MB): rq/rk/part/attnm/M (dead before FFN)
//   FFN per-batch     : h_b [2S, 2S+66.9MB), g_b [2S+66.9MB, 2S+100.3MB)
//                       (overwrites v + smalls region, both dead by then)
//   stage-1 conv temp : d_out itself (fully rewritten by final conv)
extern "C" void kernel_launch(void* const* d_in, const int* in_sizes, int n_in,
                              void* d_out, int out_size, void* d_ws, size_t ws_size,
                              hipStream_t stream)
{
  const float* Q    = (const float*)d_in[0];
  const float* Fn   = (const float*)d_in[1];
  const float* temp = (const float*)d_in[2];
  const float* qw1  = (const float*)d_in[3];
  const float* qb1  = (const float*)d_in[4];
  const float* qw2  = (const float*)d_in[5];
  const float* qb2  = (const float*)d_in[6];
  const float* kw1  = (const float*)d_in[7];
  const float* kb1  = (const float*)d_in[8];
  const float* kw2  = (const float*)d_in[9];
  const float* kb2  = (const float*)d_in[10];
  const float* vw1  = (const float*)d_in[11];
  const float* vb1  = (const float*)d_in[12];
  const float* vw2  = (const float*)d_in[13];
  const float* vb2  = (const float*)d_in[14];
  const float* ow   = (const float*)d_in[15];
  const float* ob   = (const float*)d_in[16];
  const float* lnw  = (const float*)d_in[17];
  const float* lnb  = (const float*)d_in[18];
  const float* fiw  = (const float*)d_in[19];
  const float* fib  = (const float*)d_in[20];
  const float* fdw  = (const float*)d_in[21];
  const float* fdb  = (const float*)d_in[22];
  const float* fow  = (const float*)d_in[23];
  const float* fob  = (const float*)d_in[24];
  float* out = (float*)d_out;

  char* ws = (char*)d_ws;
  const size_t S = (size_t)BB * CC * NPIX * 4;   // 50,331,648 B
  float* bufA = (float*)(ws + 0 * S);
  float* bufB = (float*)(ws + 1 * S);
  float* bufC = (float*)(ws + 2 * S);
  float* bufT = out;                              // stage-1 conv temp = d_out
  char*  smb  = ws + 3 * S;
  float* rq    = (float*)(smb);
  float* rk    = (float*)(smb + 4096);
  float* part  = (float*)(smb + 8192);                       // 9,437,184 B
  float* attnm = (float*)(smb + 8192 + 9437184);             // 589,824 B
  float* Mm    = (float*)(smb + 8192 + 9437184 + 589824);    // 589,824 B
  // per-batch FFN scratch (after v / smalls are dead)
  float* hfi_b = (float*)(ws + 2 * S);                       // 66,846,720 B
  float* g_b   = (float*)(ws + 2 * S + (size_t)HID2 * NPIX * 4); // 33,423,360 B

  dim3 blk(256);
  dim3 g1x1(CC / 12, 16, BB);

  // q = dw3x3(conv1x1(Q))
  k_conv1x1<12, false, false><<<g1x1, blk, 0, stream>>>(Q, qw1, qb1, nullptr, bufT, CC, CC);
  k_dw3x3<<<dim3(16, CC, BB), blk, 0, stream>>>(bufT, qw2, qb2, bufA, CC);
  // k = dw3x3(conv1x1(Fn))
  k_conv1x1<12, false, false><<<g1x1, blk, 0, stream>>>(Fn, kw1, kb1, nullptr, bufT, CC, CC);
  k_dw3x3<<<dim3(16, CC, BB), blk, 0, stream>>>(bufT, kw2, kb2, bufB, CC);
  // v = dw3x3(conv1x1(Fn))
  k_conv1x1<12, false, false><<<g1x1, blk, 0, stream>>>(Fn, vw1, vb1, nullptr, bufT, CC, CC);
  k_dw3x3<<<dim3(16, CC, BB), blk, 0, stream>>>(bufT, vw2, vb2, bufC, CC);
  // reciprocal row norms
  k_rownorm<<<dim3(BB * CC), blk, 0, stream>>>(bufA, rq);
  k_rownorm<<<dim3(BB * CC), blk, 0, stream>>>(bufB, rk);
  // attn logits (split-K, deterministic fixed-order reduce in softmax kernel)
  k_attn_partial<<<dim3(9, KSPLIT, BB), blk, 0, stream>>>(bufA, bufB, part);
  k_softmax_topk<<<dim3(CC, BB), dim3(192), 0, stream>>>(part, rq, rk, temp, attnm);
  // M = ow @ attnm ;  Fa = M @ v + ob  (fuses out-proj with attn@v)
  k_mix<<<dim3(CC, BB), dim3(192), 0, stream>>>(ow, attnm, Mm);
  k_conv1x1<12, true, false><<<g1x1, blk, 0, stream>>>(bufC, Mm, ob, nullptr, bufA, CC, CC);
  // LayerNorm over channels
  k_ln<<<dim3(64, BB), blk, 0, stream>>>(bufA, lnw, lnb, bufB);
  // FFN per batch: fi 1x1 -> fused dw3x3+GLU -> fo 1x1 + residual
  for (int b = 0; b < BB; ++b) {
    const float* xn_b = bufB + (size_t)b * CC * NPIX;
    const float* fa_b = bufA + (size_t)b * CC * NPIX;
    float* out_b = out + (size_t)b * CC * NPIX;
    k_conv1x1<12, false, false><<<dim3(HID2 / 12, 16, 1), blk, 0, stream>>>(
        xn_b, fiw, fib, nullptr, hfi_b, CC, HID2);
    k_dwglu<<<dim3(16, HID, 1), blk, 0, stream>>>(hfi_b, fdw, fdb, g_b);
    k_conv1x1<12, false, true><<<dim3(CC / 12, 16, 1), blk, 0, stream>>>(
        g_b, fow, fob, fa_b, out_b, HID, CC);
  }
}

// Round 3
// 1385.114 us; speedup vs baseline: 1.7050x; 1.7050x over previous
//
#include <hip/hip_runtime.h>
#include <math.h>
#include <float.h>

#define NPIX 16384
#define CC 192
#define BB 4
#define HHH 128
#define WWW 128
#define HID 510
#define HID2 1020
#define KKEEP 172
#define KSPLIT 16

typedef unsigned short ushort;

__device__ __forceinline__ float bf2f(ushort u) {
  union { float f; unsigned int i; } x; x.i = ((unsigned int)u) << 16; return x.f;
}
__device__ __forceinline__ ushort f2bf(float f) {
  union { float f; unsigned int i; } x; x.f = f;
  unsigned int r = (x.i + 0x7FFFu + ((x.i >> 16) & 1u)) >> 16;
  return (ushort)r;
}

struct __align__(16) us8 { ushort u[8]; };
struct __align__(8)  us4 { ushort u[4]; };

// ---------------- LDS-tiled conv1x1 GEMM ----------------
// Y[b,co,p] = sum_ci W[co,ci]*X[b,ci,p] + bias[co] (+res)
// tile: 64 co x 256 px, K-chunk 32.  256 threads: tc=tid>>4 (16 co-grps of 4),
// tp=tid&15 (16 px-grps); thread owns 4 co x 16 px (4x float4 at px tp*4+64i).
template<bool IN_BF16, bool OUT_BF16, bool ADD_RES, bool PER_BATCH_W>
__global__ __launch_bounds__(256) void k_gemm(
    const void* __restrict__ Xv, const float* __restrict__ W,
    const float* __restrict__ bias, const float* __restrict__ res,
    void* __restrict__ Yv, int Cin, int Cout)
{
  __shared__ float Xs[32][256];
  __shared__ float Ws[32][64];
  const int b = blockIdx.z;
  const int co0 = blockIdx.x * 64;
  const int px0 = blockIdx.y * 256;
  const int tid = threadIdx.x;
  const int tc = tid >> 4, tp = tid & 15;
  const float* Wb = W + (PER_BATCH_W ? (size_t)b * Cout * Cin : 0);

  float4 acc[4][4];
  #pragma unroll
  for (int j = 0; j < 4; ++j)
    #pragma unroll
    for (int i = 0; i < 4; ++i) acc[j][i] = make_float4(0.f, 0.f, 0.f, 0.f);

  for (int kk0 = 0; kk0 < Cin; kk0 += 32) {
    // stage W transposed: Ws[kk][co]
    #pragma unroll
    for (int i = 0; i < 8; ++i) {
      const int idx = tid + i * 256;
      const int co = idx & 63, kk = idx >> 6;
      float w = 0.f;
      if (co0 + co < Cout && kk0 + kk < Cin)
        w = Wb[(size_t)(co0 + co) * Cin + kk0 + kk];
      Ws[kk][co] = w;
    }
    // stage X: Xs[kk][px]
    if (IN_BF16) {
      const ushort* Xg = (const ushort*)Xv + (size_t)b * Cin * NPIX;
      #pragma unroll
      for (int i = 0; i < 4; ++i) {
        const int idx = tid + i * 256;
        const int r = idx >> 5, v = idx & 31;
        if (kk0 + r < Cin) {
          const us8 x = *reinterpret_cast<const us8*>(Xg + (size_t)(kk0 + r) * NPIX + px0 + v * 8);
          #pragma unroll
          for (int t = 0; t < 8; ++t) Xs[r][v * 8 + t] = bf2f(x.u[t]);
        } else {
          #pragma unroll
          for (int t = 0; t < 8; ++t) Xs[r][v * 8 + t] = 0.f;
        }
      }
    } else {
      const float* Xg = (const float*)Xv + (size_t)b * Cin * NPIX;
      #pragma unroll
      for (int i = 0; i < 8; ++i) {
        const int idx = tid + i * 256;
        const int r = idx >> 6, v = idx & 63;
        float4 x = make_float4(0.f, 0.f, 0.f, 0.f);
        if (kk0 + r < Cin)
          x = *reinterpret_cast<const float4*>(Xg + (size_t)(kk0 + r) * NPIX + px0 + v * 4);
        *reinterpret_cast<float4*>(&Xs[r][v * 4]) = x;
      }
    }
    __syncthreads();
    #pragma unroll 8
    for (int kk = 0; kk < 32; ++kk) {
      const float4 wv = *reinterpret_cast<const float4*>(&Ws[kk][tc * 4]);
      float4 xv[4];
      #pragma unroll
      for (int i = 0; i < 4; ++i)
        xv[i] = *reinterpret_cast<const float4*>(&Xs[kk][tp * 4 + i * 64]);
      #pragma unroll
      for (int i = 0; i < 4; ++i) {
        acc[0][i].x += wv.x * xv[i].x; acc[0][i].y += wv.x * xv[i].y;
        acc[0][i].z += wv.x * xv[i].z; acc[0][i].w += wv.x * xv[i].w;
        acc[1][i].x += wv.y * xv[i].x; acc[1][i].y += wv.y * xv[i].y;
        acc[1][i].z += wv.y * xv[i].z; acc[1][i].w += wv.y * xv[i].w;
        acc[2][i].x += wv.z * xv[i].x; acc[2][i].y += wv.z * xv[i].y;
        acc[2][i].z += wv.z * xv[i].z; acc[2][i].w += wv.z * xv[i].w;
        acc[3][i].x += wv.w * xv[i].x; acc[3][i].y += wv.w * xv[i].y;
        acc[3][i].z += wv.w * xv[i].z; acc[3][i].w += wv.w * xv[i].w;
      }
    }
    __syncthreads();
  }

  #pragma unroll
  for (int j = 0; j < 4; ++j) {
    const int co = co0 + tc * 4 + j;
    if (co >= Cout) continue;
    const float bv = bias ? bias[co] : 0.f;
    #pragma unroll
    for (int i = 0; i < 4; ++i) {
      const int px = px0 + tp * 4 + i * 64;
      float4 o = acc[j][i];
      o.x += bv; o.y += bv; o.z += bv; o.w += bv;
      if (ADD_RES) {
        const float4 r = *reinterpret_cast<const float4*>(
            res + (size_t)(b * Cout + co) * NPIX + px);
        o.x += r.x; o.y += r.y; o.z += r.z; o.w += r.w;
      }
      if (OUT_BF16) {
        us4 s; s.u[0] = f2bf(o.x); s.u[1] = f2bf(o.y);
               s.u[2] = f2bf(o.z); s.u[3] = f2bf(o.w);
        *reinterpret_cast<us4*>((ushort*)Yv + (size_t)(b * Cout + co) * NPIX + px) = s;
      } else {
        *reinterpret_cast<float4*>((float*)Yv + (size_t)(b * Cout + co) * NPIX + px) = o;
      }
    }
  }
}

// ---------------- depthwise 3x3 (fp32) ----------------
__device__ __forceinline__ void dw4(const float* __restrict__ Xc,
                                    const float* __restrict__ wt, float bv,
                                    int h, int w, float out[4])
{
  float a0, a1, a2, a3;
  a0 = a1 = a2 = a3 = bv;
  #pragma unroll
  for (int dy = 0; dy < 3; ++dy) {
    const int hh = h + dy - 1;
    if (hh < 0 || hh >= HHH) continue;
    const float* row = Xc + hh * WWW + w;
    const float xm = (w > 0) ? row[-1] : 0.f;
    const float4 xc = *reinterpret_cast<const float4*>(row);
    const float xp = (w < WWW - 4) ? row[4] : 0.f;
    const float w0 = wt[dy * 3 + 0], w1 = wt[dy * 3 + 1], w2 = wt[dy * 3 + 2];
    a0 += w0 * xm   + w1 * xc.x + w2 * xc.y;
    a1 += w0 * xc.x + w1 * xc.y + w2 * xc.z;
    a2 += w0 * xc.y + w1 * xc.z + w2 * xc.w;
    a3 += w0 * xc.z + w1 * xc.w + w2 * xp;
  }
  out[0] = a0; out[1] = a1; out[2] = a2; out[3] = a3;
}

__global__ __launch_bounds__(256) void k_dw3x3(
    const float* __restrict__ X, const float* __restrict__ W9,
    const float* __restrict__ bias, float* __restrict__ Y, int Cn)
{
  const int b = blockIdx.z, c = blockIdx.y;
  const int p = blockIdx.x * 1024 + threadIdx.x * 4;
  const int h = p >> 7, w = p & 127;
  const float* Xc = X + (size_t)(b * Cn + c) * NPIX;
  float o[4];
  dw4(Xc, W9 + c * 9, bias[c], h, w, o);
  *reinterpret_cast<float4*>(Y + (size_t)(b * Cn + c) * NPIX + p) =
      make_float4(o[0], o[1], o[2], o[3]);
}

// ---------------- row L2 norm ----------------
__global__ __launch_bounds__(256) void k_rownorm(const float* __restrict__ X,
                                                 float* __restrict__ R)
{
  const int row = blockIdx.x;
  const float* Xr = X + (size_t)row * NPIX;
  float s = 0.f;
  for (int i = threadIdx.x * 4; i < NPIX; i += 1024) {
    const float4 v = *reinterpret_cast<const float4*>(Xr + i);
    s += v.x * v.x + v.y * v.y + v.z * v.z + v.w * v.w;
  }
  __shared__ float sm[256];
  sm[threadIdx.x] = s; __syncthreads();
  for (int st = 128; st > 0; st >>= 1) {
    if (threadIdx.x < st) sm[threadIdx.x] += sm[threadIdx.x + st];
    __syncthreads();
  }
  if (threadIdx.x == 0) R[row] = 1.f / fmaxf(sqrtf(sm[0]), 1e-12f);
}

// ---------------- attn logits, split-K partial GEMM (fp32) ----------------
__global__ __launch_bounds__(256) void k_attn_partial(
    const float* __restrict__ q, const float* __restrict__ k,
    float* __restrict__ part)
{
  const int b = blockIdx.z;
  const int tr = blockIdx.x / 3, tc = blockIdx.x % 3;
  const int r0 = tr * 64, c0 = tc * 64;
  const int k0 = blockIdx.y * (NPIX / KSPLIT);
  __shared__ float qs[64][33];
  __shared__ float ks[64][33];
  const int tid = threadIdx.x;
  const int ty = tid >> 4, tx = tid & 15;
  float acc[4][4];
  #pragma unroll
  for (int i = 0; i < 4; ++i)
    #pragma unroll
    for (int j = 0; j < 4; ++j) acc[i][j] = 0.f;
  for (int kc = 0; kc < NPIX / KSPLIT; kc += 32) {
    #pragma unroll
    for (int i = 0; i < 8; ++i) {
      const int idx = tid + i * 256;
      const int r = idx >> 5, kk = idx & 31;
      qs[r][kk] = q[(size_t)(b * CC + r0 + r) * NPIX + k0 + kc + kk];
      ks[r][kk] = k[(size_t)(b * CC + c0 + r) * NPIX + k0 + kc + kk];
    }
    __syncthreads();
    #pragma unroll 8
    for (int kk = 0; kk < 32; ++kk) {
      float av[4], bv[4];
      #pragma unroll
      for (int i = 0; i < 4; ++i) av[i] = qs[ty * 4 + i][kk];
      #pragma unroll
      for (int j = 0; j < 4; ++j) bv[j] = ks[tx * 4 + j][kk];
      #pragma unroll
      for (int i = 0; i < 4; ++i)
        #pragma unroll
        for (int j = 0; j < 4; ++j) acc[i][j] += av[i] * bv[j];
    }
    __syncthreads();
  }
  float* pp = part + (size_t)(blockIdx.y * BB + b) * CC * CC;
  #pragma unroll
  for (int i = 0; i < 4; ++i)
    #pragma unroll
    for (int j = 0; j < 4; ++j)
      pp[(r0 + ty * 4 + i) * CC + c0 + tx * 4 + j] = acc[i][j];
}

// ---------------- reduce + scale + softmax + topk mask ----------------
__global__ __launch_bounds__(192) void k_softmax_topk(
    const float* __restrict__ part, const float* __restrict__ rq,
    const float* __restrict__ rk, const float* __restrict__ temp,
    float* __restrict__ attnm)
{
  const int c = blockIdx.x, b = blockIdx.y, d = threadIdx.x;
  float s = 0.f;
  for (int ksp = 0; ksp < KSPLIT; ++ksp)
    s += part[(size_t)(ksp * BB + b) * CC * CC + c * CC + d];
  const float logit = s * rq[b * CC + c] * rk[b * CC + d] * temp[0];
  __shared__ float sa[CC], sb[CC];
  sa[d] = logit; __syncthreads();
  float mx = -FLT_MAX;
  for (int j = 0; j < CC; ++j) mx = fmaxf(mx, sa[j]);
  const float e = expf(logit - mx);
  sb[d] = e; __syncthreads();
  float sum = 0.f;
  for (int j = 0; j < CC; ++j) sum += sb[j];
  const float pv = e / sum;
  __syncthreads();
  sa[d] = pv; __syncthreads();
  int greater = 0;
  for (int j = 0; j < CC; ++j) greater += (sa[j] > pv) ? 1 : 0;
  const float cand = (greater < KKEEP) ? pv : FLT_MAX;
  sb[d] = cand; __syncthreads();
  float thr = FLT_MAX;
  for (int j = 0; j < CC; ++j) thr = fminf(thr, sb[j]);
  attnm[(size_t)(b * CC + c) * CC + d] = (pv >= thr) ? pv : 0.f;
}

// ---------------- M[b] = ow @ attnm[b] ----------------
__global__ __launch_bounds__(192) void k_mix(
    const float* __restrict__ ow, const float* __restrict__ attnm,
    float* __restrict__ M)
{
  const int c = blockIdx.x, b = blockIdx.y, d = threadIdx.x;
  float acc = 0.f;
  for (int e = 0; e < CC; ++e)
    acc += ow[c * CC + e] * attnm[(size_t)(b * CC + e) * CC + d];
  M[(size_t)(b * CC + c) * CC + d] = acc;
}

// ---------------- LayerNorm over channels -> bf16 ----------------
__global__ __launch_bounds__(256) void k_ln_bf16(
    const float* __restrict__ X, const float* __restrict__ lw,
    const float* __restrict__ lb, ushort* __restrict__ Y)
{
  const int b = blockIdx.y;
  const int n = blockIdx.x * 256 + threadIdx.x;
  const float* Xb = X + (size_t)b * CC * NPIX + n;
  float s = 0.f, s2 = 0.f;
  for (int ci = 0; ci < CC; ++ci) {
    const float v = Xb[(size_t)ci * NPIX];
    s += v; s2 += v * v;
  }
  const float mu = s * (1.f / CC);
  const float var = fmaxf(s2 * (1.f / CC) - mu * mu, 0.f);
  const float rstd = rsqrtf(var + 1e-5f);
  ushort* Yb = Y + (size_t)b * CC * NPIX + n;
  for (int ci = 0; ci < CC; ++ci) {
    const float v = Xb[(size_t)ci * NPIX];
    Yb[(size_t)ci * NPIX] = f2bf((v - mu) * rstd * lw[ci] + lb[ci]);
  }
}

// ---------------- fused depthwise 3x3 + GLU (bf16 in/out) ----------------
__device__ __forceinline__ float gelu_exact(float x) {
  return 0.5f * x * (1.f + erff(x * 0.70710678118654752f));
}

__device__ __forceinline__ void dw4_bf(const ushort* __restrict__ Xc,
                                       const float* __restrict__ wt, float bv,
                                       int h, int w, float out[4])
{
  float a0, a1, a2, a3;
  a0 = a1 = a2 = a3 = bv;
  #pragma unroll
  for (int dy = 0; dy < 3; ++dy) {
    const int hh = h + dy - 1;
    if (hh < 0 || hh >= HHH) continue;
    const ushort* row = Xc + hh * WWW + w;
    const float xm = (w > 0) ? bf2f(row[-1]) : 0.f;
    const us4 xcb = *reinterpret_cast<const us4*>(row);
    const float x0 = bf2f(xcb.u[0]), x1 = bf2f(xcb.u[1]);
    const float x2 = bf2f(xcb.u[2]), x3 = bf2f(xcb.u[3]);
    const float xp = (w < WWW - 4) ? bf2f(row[4]) : 0.f;
    const float w0 = wt[dy * 3 + 0], w1 = wt[dy * 3 + 1], w2 = wt[dy * 3 + 2];
    a0 += w0 * xm + w1 * x0 + w2 * x1;
    a1 += w0 * x0 + w1 * x1 + w2 * x2;
    a2 += w0 * x1 + w1 * x2 + w2 * x3;
    a3 += w0 * x2 + w1 * x3 + w2 * xp;
  }
  out[0] = a0; out[1] = a1; out[2] = a2; out[3] = a3;
}

__global__ __launch_bounds__(256) void k_dwglu_bf(
    const ushort* __restrict__ Hf, const float* __restrict__ W9,
    const float* __restrict__ bias, ushort* __restrict__ G, int b)
{
  const int c = blockIdx.y;  // [0, HID)
  const int p = blockIdx.x * 1024 + threadIdx.x * 4;
  const int h = p >> 7, w = p & 127;
  float o1[4], o2[4];
  dw4_bf(Hf + (size_t)c * NPIX,         W9 + c * 9,         bias[c],       h, w, o1);
  dw4_bf(Hf + (size_t)(c + HID) * NPIX, W9 + (c + HID) * 9, bias[c + HID], h, w, o2);
  us4 s;
  s.u[0] = f2bf(o1[0] * gelu_exact(o2[0]));
  s.u[1] = f2bf(o1[1] * gelu_exact(o2[1]));
  s.u[2] = f2bf(o1[2] * gelu_exact(o2[2]));
  s.u[3] = f2bf(o1[3] * gelu_exact(o2[3]));
  *reinterpret_cast<us4*>(G + (size_t)(b * HID + c) * NPIX + p) = s;
}

// ---------------- launch ----------------
// Workspace (peak 175.8 MB, < known-good 200.9 MB):
//   [0,S)                  : q -> Fa (fp32, live to end)
//   [S,2S)                 : k (fp32, dead after attn)
//   [2S,3S)                : v (fp32, dead after Fa gemm)
//   [3S,3S+10.7M)          : rq/rk/part/attnm/M (dead after Fa gemm)
//   FFN overlay (all dead by then):
//   xn  bf16 [S, S+25.2M)        (over old k)
//   h_b bf16 [S+25.2M, +33.4M)   (per batch)
//   g   bf16 [S+58.6M, +66.8M)   (all batches)
extern "C" void kernel_launch(void* const* d_in, const int* in_sizes, int n_in,
                              void* d_out, int out_size, void* d_ws, size_t ws_size,
                              hipStream_t stream)
{
  const float* Q    = (const float*)d_in[0];
  const float* Fn   = (const float*)d_in[1];
  const float* temp = (const float*)d_in[2];
  const float* qw1  = (const float*)d_in[3];
  const float* qb1  = (const float*)d_in[4];
  const float* qw2  = (const float*)d_in[5];
  const float* qb2  = (const float*)d_in[6];
  const float* kw1  = (const float*)d_in[7];
  const float* kb1  = (const float*)d_in[8];
  const float* kw2  = (const float*)d_in[9];
  const float* kb2  = (const float*)d_in[10];
  const float* vw1  = (const float*)d_in[11];
  const float* vb1  = (const float*)d_in[12];
  const float* vw2  = (const float*)d_in[13];
  const float* vb2  = (const float*)d_in[14];
  const float* ow   = (const float*)d_in[15];
  const float* ob   = (const float*)d_in[16];
  const float* lnw  = (const float*)d_in[17];
  const float* lnb  = (const float*)d_in[18];
  const float* fiw  = (const float*)d_in[19];
  const float* fib  = (const float*)d_in[20];
  const float* fdw  = (const float*)d_in[21];
  const float* fdb  = (const float*)d_in[22];
  const float* fow  = (const float*)d_in[23];
  const float* fob  = (const float*)d_in[24];
  float* out = (float*)d_out;

  char* ws = (char*)d_ws;
  const size_t S = (size_t)BB * CC * NPIX * 4;   // 50,331,648
  float* bufA = (float*)(ws + 0 * S);
  float* bufB = (float*)(ws + 1 * S);
  float* bufC = (float*)(ws + 2 * S);
  float* bufT = out;                              // stage-1 temp = d_out
  char*  smb  = ws + 3 * S;
  float* rq    = (float*)(smb);
  float* rk    = (float*)(smb + 4096);
  float* part  = (float*)(smb + 8192);
  float* attnm = (float*)(smb + 8192 + 9437184);
  float* Mm    = (float*)(smb + 8192 + 9437184 + 589824);
  ushort* xnb  = (ushort*)(ws + S);                            // 25,165,824
  ushort* h_b  = (ushort*)(ws + S + 25165824);                 // 33,423,360
  ushort* gall = (ushort*)(ws + S + 25165824 + 33423360);      // 66,846,720

  dim3 blk(256);
  dim3 gC(3, 64, BB);        // Cout=192 gemms, all batches

  // q/k/v = dw3x3(conv1x1(.))
  k_gemm<false, false, false, false><<<gC, blk, 0, stream>>>(Q, qw1, qb1, nullptr, bufT, CC, CC);
  k_dw3x3<<<dim3(16, CC, BB), blk, 0, stream>>>(bufT, qw2, qb2, bufA, CC);
  k_gemm<false, false, false, false><<<gC, blk, 0, stream>>>(Fn, kw1, kb1, nullptr, bufT, CC, CC);
  k_dw3x3<<<dim3(16, CC, BB), blk, 0, stream>>>(bufT, kw2, kb2, bufB, CC);
  k_gemm<false, false, false, false><<<gC, blk, 0, stream>>>(Fn, vw1, vb1, nullptr, bufT, CC, CC);
  k_dw3x3<<<dim3(16, CC, BB), blk, 0, stream>>>(bufT, vw2, vb2, bufC, CC);
  // row norms
  k_rownorm<<<dim3(BB * CC), blk, 0, stream>>>(bufA, rq);
  k_rownorm<<<dim3(BB * CC), blk, 0, stream>>>(bufB, rk);
  // attention logits + softmax/topk + weight-fold
  k_attn_partial<<<dim3(9, KSPLIT, BB), blk, 0, stream>>>(bufA, bufB, part);
  k_softmax_topk<<<dim3(CC, BB), dim3(192), 0, stream>>>(part, rq, rk, temp, attnm);
  k_mix<<<dim3(CC, BB), dim3(192), 0, stream>>>(ow, attnm, Mm);
  // Fa = M @ v + ob
  k_gemm<false, false, false, true><<<gC, blk, 0, stream>>>(bufC, Mm, ob, nullptr, bufA, CC, CC);
  // LayerNorm -> bf16 xn
  k_ln_bf16<<<dim3(64, BB), blk, 0, stream>>>(bufA, lnw, lnb, xnb);
  // FFN: per-batch fi + dwglu (h per-batch, g all-batch), then merged fo
  for (int b = 0; b < BB; ++b) {
    const ushort* xn_b = xnb + (size_t)b * CC * NPIX;
    k_gemm<true, true, false, false><<<dim3(16, 64, 1), blk, 0, stream>>>(
        xn_b, fiw, fib, nullptr, h_b, CC, HID2);
    k_dwglu_bf<<<dim3(16, HID, 1), blk, 0, stream>>>(h_b, fdw, fdb, gall, b);
  }
  k_gemm<true, false, true, false><<<gC, blk, 0, stream>>>(
      gall, fow, fob, bufA, out, HID, CC);
}

// Round 4
// 1287.035 us; speedup vs baseline: 1.8349x; 1.0762x over previous
//
#include <hip/hip_runtime.h>
#include <math.h>
#include <float.h>

#define NPIX 16384
#define CC 192
#define BB 4
#define HHH 128
#define WWW 128
#define HID 510
#define HID2 1020
#define KKEEP 172
#define KSPLIT 16

typedef unsigned short ushort;
using f32x4  = __attribute__((ext_vector_type(4))) float;
using bf16x8 = __attribute__((ext_vector_type(8))) short;

__device__ __forceinline__ float bf2f(ushort u) {
  union { float f; unsigned int i; } x; x.i = ((unsigned int)u) << 16; return x.f;
}
__device__ __forceinline__ ushort f2bf(float f) {
  union { float f; unsigned int i; } x; x.f = f;
  unsigned int r = (x.i + 0x7FFFu + ((x.i >> 16) & 1u)) >> 16;
  return (ushort)r;
}

struct __align__(16) us8 { ushort u[8]; };
struct __align__(8)  us4 { ushort u[4]; };

// ================= NT-MFMA GEMM =================
// C[m][n] = sum_k A[m][k] * B[n][k]  (+bias[m]) (+res)
// A: fp32 [M][lda], converted in staging to bf16 (PASSES==1) or hi/lo pair (PASSES==3).
// B: bf16 planes Bh (+Bl if PASSES==3), [N][ldb], K-contiguous.
// Block: 64m x 128n, BK=32, 256 thr = 4 waves (2x2), wave tile 32x64.
// MFMA 16x16x32 bf16. Fragment k-bijection c(hi,j)=hi*8+j used for BOTH A and B
// (valid by A/B mirror symmetry); D layout: col=lane&15, row=(lane>>4)*4+reg (m89).
template<int PASSES, bool OUT_BF16, bool ADD_RES>
__global__ __launch_bounds__(256) void k_ntgemm(
    const float* __restrict__ A,
    const ushort* __restrict__ Bh, const ushort* __restrict__ Bl,
    const float* __restrict__ bias, const float* __restrict__ res,
    void* __restrict__ Cptr,
    int Mvalid, int Nvalid, int K, int Kvalid,
    int lda, int ldb, int ldc,
    long long sAb, long long sBb, long long sCb)
{
  constexpr int PL = (PASSES == 3) ? 2 : 1;
  __shared__ ushort As[PL][64][40];
  __shared__ ushort Bs[PL][128][40];

  const int b = blockIdx.z;
  const int m0 = blockIdx.x * 64;
  const int n0 = blockIdx.y * 128;
  const int tid = threadIdx.x;
  const int lane = tid & 63;
  const int wave = tid >> 6;
  const int wm = wave >> 1, wn = wave & 1;

  const float*  Ab  = A  + (size_t)b * sAb;
  const ushort* Bhb = Bh + (size_t)b * sBb;
  const ushort* Blb = (PL == 2) ? (Bl + (size_t)b * sBb) : nullptr;

  f32x4 acc[2][4];
  #pragma unroll
  for (int i = 0; i < 2; ++i)
    #pragma unroll
    for (int j = 0; j < 4; ++j) acc[i][j] = (f32x4){0.f, 0.f, 0.f, 0.f};

  const int am = tid >> 2, ak = (tid & 3) * 8;   // A staging: 64 x 32
  const int bn = tid >> 1, bk = (tid & 1) * 16;  // B staging: 128 x 32

  for (int kk0 = 0; kk0 < K; kk0 += 32) {
    // ---- stage A (fp32 -> bf16 [pair]) ----
    {
      float v[8];
      const bool mok = (m0 + am) < Mvalid;
      #pragma unroll
      for (int t = 0; t < 8; ++t) {
        const int k = kk0 + ak + t;
        v[t] = (mok && k < Kvalid) ? Ab[(size_t)(m0 + am) * lda + k] : 0.f;
      }
      bf16x8 h8, l8;
      #pragma unroll
      for (int t = 0; t < 8; ++t) {
        const ushort h = f2bf(v[t]);
        h8[t] = (short)h;
        if (PL == 2) l8[t] = (short)f2bf(v[t] - bf2f(h));
      }
      *reinterpret_cast<bf16x8*>(&As[0][am][ak]) = h8;
      if (PL == 2) *reinterpret_cast<bf16x8*>(&As[1][am][ak]) = l8;
    }
    // ---- stage B (bf16 planes) ----
    {
      const bool nok = (n0 + bn) < Nvalid;
      const size_t off = (size_t)(n0 + bn) * ldb + kk0 + bk;
      us8 z; 
      #pragma unroll
      for (int t = 0; t < 8; ++t) z.u[t] = 0;
      us8 v0 = nok ? *reinterpret_cast<const us8*>(Bhb + off)     : z;
      us8 v1 = nok ? *reinterpret_cast<const us8*>(Bhb + off + 8) : z;
      *reinterpret_cast<us8*>(&Bs[0][bn][bk])     = v0;
      *reinterpret_cast<us8*>(&Bs[0][bn][bk + 8]) = v1;
      if (PL == 2) {
        us8 w0 = nok ? *reinterpret_cast<const us8*>(Blb + off)     : z;
        us8 w1 = nok ? *reinterpret_cast<const us8*>(Blb + off + 8) : z;
        *reinterpret_cast<us8*>(&Bs[1][bn][bk])     = w0;
        *reinterpret_cast<us8*>(&Bs[1][bn][bk + 8]) = w1;
      }
    }
    __syncthreads();
    // ---- MFMA ----
    bf16x8 af[2][PL], bfg[4][PL];
    #pragma unroll
    for (int mi = 0; mi < 2; ++mi)
      #pragma unroll
      for (int p = 0; p < PL; ++p)
        af[mi][p] = *reinterpret_cast<const bf16x8*>(
            &As[p][wm * 32 + mi * 16 + (lane & 15)][(lane >> 4) * 8]);
    #pragma unroll
    for (int ni = 0; ni < 4; ++ni)
      #pragma unroll
      for (int p = 0; p < PL; ++p)
        bfg[ni][p] = *reinterpret_cast<const bf16x8*>(
            &Bs[p][wn * 64 + ni * 16 + (lane & 15)][(lane >> 4) * 8]);
    #pragma unroll
    for (int mi = 0; mi < 2; ++mi)
      #pragma unroll
      for (int ni = 0; ni < 4; ++ni) {
        acc[mi][ni] = __builtin_amdgcn_mfma_f32_16x16x32_bf16(
            af[mi][0], bfg[ni][0], acc[mi][ni], 0, 0, 0);
        if (PL == 2) {
          acc[mi][ni] = __builtin_amdgcn_mfma_f32_16x16x32_bf16(
              af[mi][0], bfg[ni][1], acc[mi][ni], 0, 0, 0);
          acc[mi][ni] = __builtin_amdgcn_mfma_f32_16x16x32_bf16(
              af[mi][1], bfg[ni][0], acc[mi][ni], 0, 0, 0);
        }
      }
    __syncthreads();
  }

  // ---- epilogue ----
  #pragma unroll
  for (int mi = 0; mi < 2; ++mi)
    #pragma unroll
    for (int r = 0; r < 4; ++r) {
      const int m = m0 + wm * 32 + mi * 16 + (lane >> 4) * 4 + r;
      if (m >= Mvalid) continue;
      const float bv = bias[m];
      #pragma unroll
      for (int ni = 0; ni < 4; ++ni) {
        const int n = n0 + wn * 64 + ni * 16 + (lane & 15);
        if (n >= Nvalid) continue;
        float v = acc[mi][ni][r] + bv;
        if (ADD_RES) v += res[(size_t)b * sCb + (size_t)m * ldc + n];
        if (OUT_BF16)
          ((ushort*)Cptr)[(size_t)b * sCb + (size_t)m * ldc + n] = f2bf(v);
        else
          ((float*)Cptr)[(size_t)b * sCb + (size_t)m * ldc + n] = v;
      }
    }
}

// ================= transpose + split =================
// fp32 [192][NPIX] (batch z) -> hi/lo bf16 [NPIX][192]
__global__ __launch_bounds__(256) void k_transpose_split(
    const float* __restrict__ X, ushort* __restrict__ Xh, ushort* __restrict__ Xl)
{
  __shared__ float ld[32][260];
  const int tid = threadIdx.x;
  const int r = tid >> 3, seg = tid & 7;
  const float* src = X + ((size_t)blockIdx.z * CC + blockIdx.y * 32 + r) * NPIX
                       + blockIdx.x * 256 + seg * 32;
  #pragma unroll
  for (int i = 0; i < 8; ++i) {
    const float4 v = *reinterpret_cast<const float4*>(src + i * 4);
    *reinterpret_cast<float4*>(&ld[r][seg * 32 + i * 4]) = v;
  }
  __syncthreads();
  const size_t dst = ((size_t)blockIdx.z * NPIX + blockIdx.x * 256 + tid) * CC
                     + blockIdx.y * 32;
  #pragma unroll
  for (int c8 = 0; c8 < 4; ++c8) {
    bf16x8 h8, l8;
    #pragma unroll
    for (int t = 0; t < 8; ++t) {
      const float v = ld[c8 * 8 + t][tid];
      const ushort h = f2bf(v);
      h8[t] = (short)h;
      l8[t] = (short)f2bf(v - bf2f(h));
    }
    *reinterpret_cast<bf16x8*>(Xh + dst + c8 * 8) = h8;
    *reinterpret_cast<bf16x8*>(Xl + dst + c8 * 8) = l8;
  }
}

// ================= depthwise 3x3 =================
__device__ __forceinline__ void dw4(const float* __restrict__ Xc,
                                    const float* __restrict__ wt, float bv,
                                    int h, int w, float out[4])
{
  float a0, a1, a2, a3;
  a0 = a1 = a2 = a3 = bv;
  #pragma unroll
  for (int dy = 0; dy < 3; ++dy) {
    const int hh = h + dy - 1;
    if (hh < 0 || hh >= HHH) continue;
    const float* row = Xc + hh * WWW + w;
    const float xm = (w > 0) ? row[-1] : 0.f;
    const float4 xc = *reinterpret_cast<const float4*>(row);
    const float xp = (w < WWW - 4) ? row[4] : 0.f;
    const float w0 = wt[dy * 3 + 0], w1 = wt[dy * 3 + 1], w2 = wt[dy * 3 + 2];
    a0 += w0 * xm   + w1 * xc.x + w2 * xc.y;
    a1 += w0 * xc.x + w1 * xc.y + w2 * xc.z;
    a2 += w0 * xc.y + w1 * xc.z + w2 * xc.w;
    a3 += w0 * xc.z + w1 * xc.w + w2 * xp;
  }
  out[0] = a0; out[1] = a1; out[2] = a2; out[3] = a3;
}

__global__ __launch_bounds__(256) void k_dw3x3(
    const float* __restrict__ X, const float* __restrict__ W9,
    const float* __restrict__ bias, float* __restrict__ Y)
{
  const int b = blockIdx.z, c = blockIdx.y;
  const int p = blockIdx.x * 1024 + threadIdx.x * 4;
  const int h = p >> 7, w = p & 127;
  float o[4];
  dw4(X + (size_t)(b * CC + c) * NPIX, W9 + c * 9, bias[c], h, w, o);
  *reinterpret_cast<float4*>(Y + (size_t)(b * CC + c) * NPIX + p) =
      make_float4(o[0], o[1], o[2], o[3]);
}

// dw3x3 -> hi/lo bf16 planes [c][px]
__global__ __launch_bounds__(256) void k_dw3x3_split(
    const float* __restrict__ X, const float* __restrict__ W9,
    const float* __restrict__ bias, ushort* __restrict__ Yh,
    ushort* __restrict__ Yl)
{
  const int b = blockIdx.z, c = blockIdx.y;
  const int p = blockIdx.x * 1024 + threadIdx.x * 4;
  const int h = p >> 7, w = p & 127;
  float o[4];
  dw4(X + (size_t)(b * CC + c) * NPIX, W9 + c * 9, bias[c], h, w, o);
  us4 hi, lo;
  #pragma unroll
  for (int t = 0; t < 4; ++t) {
    const ushort hv = f2bf(o[t]);
    hi.u[t] = hv;
    lo.u[t] = f2bf(o[t] - bf2f(hv));
  }
  const size_t off = (size_t)(b * CC + c) * NPIX + p;
  *reinterpret_cast<us4*>(Yh + off) = hi;
  *reinterpret_cast<us4*>(Yl + off) = lo;
}

// ================= row L2 norm (hi/lo input) =================
__global__ __launch_bounds__(256) void k_rownorm_pair(
    const ushort* __restrict__ Xh, const ushort* __restrict__ Xl,
    float* __restrict__ R)
{
  const int row = blockIdx.x;
  const ushort* H = Xh + (size_t)row * NPIX;
  const ushort* L = Xl + (size_t)row * NPIX;
  float s = 0.f;
  for (int i = threadIdx.x * 8; i < NPIX; i += 2048) {
    const us8 a = *reinterpret_cast<const us8*>(H + i);
    const us8 b = *reinterpret_cast<const us8*>(L + i);
    #pragma unroll
    for (int t = 0; t < 8; ++t) {
      const float v = bf2f(a.u[t]) + bf2f(b.u[t]);
      s += v * v;
    }
  }
  __shared__ float sm[256];
  sm[threadIdx.x] = s; __syncthreads();
  for (int st = 128; st > 0; st >>= 1) {
    if (threadIdx.x < st) sm[threadIdx.x] += sm[threadIdx.x + st];
    __syncthreads();
  }
  if (threadIdx.x == 0) R[row] = 1.f / fmaxf(sqrtf(sm[0]), 1e-12f);
}

// ================= attn logits, split-K fp32 (exact path) =================
__global__ __launch_bounds__(256) void k_attn_partial(
    const ushort* __restrict__ qh, const ushort* __restrict__ ql,
    const ushort* __restrict__ kh, const ushort* __restrict__ kl,
    float* __restrict__ part)
{
  const int b = blockIdx.z;
  const int tr = blockIdx.x / 3, tc = blockIdx.x % 3;
  const int r0 = tr * 64, c0 = tc * 64;
  const int k0 = blockIdx.y * (NPIX / KSPLIT);
  __shared__ float qs[64][33];
  __shared__ float ks[64][33];
  const int tid = threadIdx.x;
  const int ty = tid >> 4, tx = tid & 15;
  float acc[4][4];
  #pragma unroll
  for (int i = 0; i < 4; ++i)
    #pragma unroll
    for (int j = 0; j < 4; ++j) acc[i][j] = 0.f;
  for (int kc = 0; kc < NPIX / KSPLIT; kc += 32) {
    #pragma unroll
    for (int i = 0; i < 8; ++i) {
      const int idx = tid + i * 256;
      const int r = idx >> 5, kk = idx & 31;
      const size_t gq = (size_t)(b * CC + r0 + r) * NPIX + k0 + kc + kk;
      const size_t gk = (size_t)(b * CC + c0 + r) * NPIX + k0 + kc + kk;
      qs[r][kk] = bf2f(qh[gq]) + bf2f(ql[gq]);
      ks[r][kk] = bf2f(kh[gk]) + bf2f(kl[gk]);
    }
    __syncthreads();
    #pragma unroll 8
    for (int kk = 0; kk < 32; ++kk) {
      float av[4], bv[4];
      #pragma unroll
      for (int i = 0; i < 4; ++i) av[i] = qs[ty * 4 + i][kk];
      #pragma unroll
      for (int j = 0; j < 4; ++j) bv[j] = ks[tx * 4 + j][kk];
      #pragma unroll
      for (int i = 0; i < 4; ++i)
        #pragma unroll
        for (int j = 0; j < 4; ++j) acc[i][j] += av[i] * bv[j];
    }
    __syncthreads();
  }
  float* pp = part + (size_t)(blockIdx.y * BB + b) * CC * CC;
  #pragma unroll
  for (int i = 0; i < 4; ++i)
    #pragma unroll
    for (int j = 0; j < 4; ++j)
      pp[(r0 + ty * 4 + i) * CC + c0 + tx * 4 + j] = acc[i][j];
}

// ================= softmax + topk mask =================
__global__ __launch_bounds__(192) void k_softmax_topk(
    const float* __restrict__ part, const float* __restrict__ rq,
    const float* __restrict__ rk, const float* __restrict__ temp,
    float* __restrict__ attnm)
{
  const int c = blockIdx.x, b = blockIdx.y, d = threadIdx.x;
  float s = 0.f;
  for (int ksp = 0; ksp < KSPLIT; ++ksp)
    s += part[(size_t)(ksp * BB + b) * CC * CC + c * CC + d];
  const float logit = s * rq[b * CC + c] * rk[b * CC + d] * temp[0];
  __shared__ float sa[CC], sb[CC];
  sa[d] = logit; __syncthreads();
  float mx = -FLT_MAX;
  for (int j = 0; j < CC; ++j) mx = fmaxf(mx, sa[j]);
  const float e = expf(logit - mx);
  sb[d] = e; __syncthreads();
  float sum = 0.f;
  for (int j = 0; j < CC; ++j) sum += sb[j];
  const float pv = e / sum;
  __syncthreads();
  sa[d] = pv; __syncthreads();
  int greater = 0;
  for (int j = 0; j < CC; ++j) greater += (sa[j] > pv) ? 1 : 0;
  const float cand = (greater < KKEEP) ? pv : FLT_MAX;
  sb[d] = cand; __syncthreads();
  float thr = FLT_MAX;
  for (int j = 0; j < CC; ++j) thr = fminf(thr, sb[j]);
  attnm[(size_t)(b * CC + c) * CC + d] = (pv >= thr) ? pv : 0.f;
}

// ================= M[b] = ow @ attnm[b] =================
__global__ __launch_bounds__(192) void k_mix(
    const float* __restrict__ ow, const float* __restrict__ attnm,
    float* __restrict__ M)
{
  const int c = blockIdx.x, b = blockIdx.y, d = threadIdx.x;
  float acc = 0.f;
  for (int e = 0; e < CC; ++e)
    acc += ow[c * CC + e] * attnm[(size_t)(b * CC + e) * CC + d];
  M[(size_t)(b * CC + c) * CC + d] = acc;
}

// ================= LayerNorm -> transposed bf16 [px][192] =================
__global__ __launch_bounds__(256) void k_ln_t(
    const float* __restrict__ X, const float* __restrict__ lw,
    const float* __restrict__ lb, ushort* __restrict__ Y)
{
  const int b = blockIdx.y;
  const int n = blockIdx.x * 256 + threadIdx.x;
  const float* Xb = X + (size_t)b * CC * NPIX + n;
  float s = 0.f, s2 = 0.f;
  for (int ci = 0; ci < CC; ++ci) {
    const float v = Xb[(size_t)ci * NPIX];
    s += v; s2 += v * v;
  }
  const float mu = s * (1.f / CC);
  const float var = fmaxf(s2 * (1.f / CC) - mu * mu, 0.f);
  const float rstd = rsqrtf(var + 1e-5f);
  ushort* Yb = Y + ((size_t)b * NPIX + n) * CC;
  for (int c8 = 0; c8 < CC / 8; ++c8) {
    bf16x8 sv;
    #pragma unroll
    for (int t = 0; t < 8; ++t) {
      const int c = c8 * 8 + t;
      const float v = Xb[(size_t)c * NPIX];
      sv[t] = (short)f2bf((v - mu) * rstd * lw[c] + lb[c]);
    }
    *reinterpret_cast<bf16x8*>(Yb + c8 * 8) = sv;
  }
}

// ================= fused depthwise 3x3 + GLU, transposed out =================
__device__ __forceinline__ float gelu_exact(float x) {
  return 0.5f * x * (1.f + erff(x * 0.70710678118654752f));
}

// h_b bf16 [1020][NPIX] -> gt[b] bf16 [NPIX][512] (cols 510,511 zeroed)
__global__ __launch_bounds__(256) void k_dwglu_t(
    const ushort* __restrict__ Hb, const float* __restrict__ fdw,
    const float* __restrict__ fdb, ushort* __restrict__ gt, int b)
{
  __shared__ ushort hs[64][4][128];
  const int tid = threadIdx.x;
  const int h0 = blockIdx.x * 2;
  const int c0 = blockIdx.y * 32;
  const int npairs = min(32, HID - c0);
  // stage 64 channels x 4 rows x 128 w
  #pragma unroll
  for (int i = 0; i < 16; ++i) {
    const int u = i * 256 + tid;
    const int ch = u >> 6;
    const int row = (u >> 4) & 3;
    const int w0 = (u & 15) * 8;
    const int grow = h0 - 1 + row;
    const int cloc = (ch < 32) ? ch : (ch - 32);
    const int gch = (ch < 32) ? (c0 + ch) : (HID + c0 + ch - 32);
    us8 v;
    #pragma unroll
    for (int t = 0; t < 8; ++t) v.u[t] = 0;
    if (c0 + cloc < HID && grow >= 0 && grow < HHH)
      v = *reinterpret_cast<const us8*>(Hb + (size_t)gch * NPIX + grow * WWW + w0);
    *reinterpret_cast<us8*>(&hs[ch][row][w0]) = v;
  }
  __syncthreads();
  const int dh = tid >> 7, w = tid & 127;
  const int px = (h0 + dh) * WWW + w;
  for (int jc = 0; jc < 4; ++jc) {
    bf16x8 sv;
    #pragma unroll
    for (int jj = 0; jj < 8; ++jj) {
      const int j = jc * 8 + jj;
      float val = 0.f;
      if (j < npairs) {
        float x1 = fdb[c0 + j], x2 = fdb[HID + c0 + j];
        const float* w1 = fdw + (size_t)(c0 + j) * 9;
        const float* w2 = fdw + (size_t)(HID + c0 + j) * 9;
        #pragma unroll
        for (int dy = 0; dy < 3; ++dy)
          #pragma unroll
          for (int dx = 0; dx < 3; ++dx) {
            const int ww = w + dx - 1;
            if (ww >= 0 && ww < WWW) {
              x1 += w1[dy * 3 + dx] * bf2f(hs[j][dh + dy][ww]);
              x2 += w2[dy * 3 + dx] * bf2f(hs[32 + j][dh + dy][ww]);
            }
          }
        val = x1 * gelu_exact(x2);
      }
      sv[jj] = (short)f2bf(val);
    }
    *reinterpret_cast<bf16x8*>(gt + ((size_t)b * NPIX + px) * 512 + c0 + jc * 8) = sv;
  }
}

// ================= launch =================
// Workspace layout (P = 25,165,824 B; peak 8P = 201.3 MB — same as passing R2):
//  Qt  pair [0,2P) -> dead after q stage1
//  Fnt pair [2P,4P) -> dead after v stage1
//  q   pair [4P,6P) -> dead after attn
//  k   pair [0,2P)  (over Qt) -> dead after attn
//  v fp32   [6P,8P) -> dead after transpose
//  vt  pair [2P,4P) (over Fnt) -> dead after Fa gemm
//  smalls   [6P,..) rq/rk/part/attnm/Mm -> dead after Fa gemm
//  Fa fp32  [0,2P)  (over k) -> live to end
//  xnt bf16 [2P,3P) (over vt)
//  h_b bf16 [3P, 3P+33.4M)
//  gt  bf16 [3P+33.4M, 3P+100.5M)  (ends at 176.0 MB)
extern "C" void kernel_launch(void* const* d_in, const int* in_sizes, int n_in,
                              void* d_out, int out_size, void* d_ws, size_t ws_size,
                              hipStream_t stream)
{
  const float* Q    = (const float*)d_in[0];
  const float* Fn   = (const float*)d_in[1];
  const float* temp = (const float*)d_in[2];
  const float* qw1  = (const float*)d_in[3];
  const float* qb1  = (const float*)d_in[4];
  const float* qw2  = (const float*)d_in[5];
  const float* qb2  = (const float*)d_in[6];
  const float* kw1  = (const float*)d_in[7];
  const float* kb1  = (const float*)d_in[8];
  const float* kw2  = (const float*)d_in[9];
  const float* kb2  = (const float*)d_in[10];
  const float* vw1  = (const float*)d_in[11];
  const float* vb1  = (const float*)d_in[12];
  const float* vw2  = (const float*)d_in[13];
  const float* vb2  = (const float*)d_in[14];
  const float* ow   = (const float*)d_in[15];
  const float* ob   = (const float*)d_in[16];
  const float* lnw  = (const float*)d_in[17];
  const float* lnb  = (const float*)d_in[18];
  const float* fiw  = (const float*)d_in[19];
  const float* fib  = (const float*)d_in[20];
  const float* fdw  = (const float*)d_in[21];
  const float* fdb  = (const float*)d_in[22];
  const float* fow  = (const float*)d_in[23];
  const float* fob  = (const float*)d_in[24];
  float* out = (float*)d_out;

  char* ws = (char*)d_ws;
  const size_t P = 25165824UL;
  ushort* Qth = (ushort*)(ws + 0 * P);
  ushort* Qtl = (ushort*)(ws + 1 * P);
  ushort* Fth = (ushort*)(ws + 2 * P);
  ushort* Ftl = (ushort*)(ws + 3 * P);
  ushort* qh  = (ushort*)(ws + 4 * P);
  ushort* ql  = (ushort*)(ws + 5 * P);
  ushort* kh  = (ushort*)(ws + 0 * P);
  ushort* kl  = (ushort*)(ws + 1 * P);
  float*  vbuf = (float*)(ws + 6 * P);
  ushort* vth = (ushort*)(ws + 2 * P);
  ushort* vtl = (ushort*)(ws + 3 * P);
  char*  smb  = ws + 6 * P;
  float* rq    = (float*)(smb);
  float* rk    = (float*)(smb + 4096);
  float* part  = (float*)(smb + 8192);                       // 9,437,184
  float* attnm = (float*)(smb + 8192 + 9437184);             // 589,824
  float* Mm    = (float*)(smb + 8192 + 9437184 + 589824);    // 589,824
  float* Fa   = (float*)(ws + 0 * P);
  ushort* xnt = (ushort*)(ws + 2 * P);
  ushort* h_b = (ushort*)(ws + 3 * P);
  ushort* gt  = (ushort*)(ws + 3 * P + 33423360UL);
  float* bufT = out;  // stage-1 conv output scratch

  const long long sQK = (long long)CC * NPIX;   // fp32/bf16 [c][px] batch stride
  const long long sT  = (long long)NPIX * CC;   // transposed [px][c] batch stride

  dim3 blk(256);

  // transposes of inputs
  k_transpose_split<<<dim3(64, 6, BB), blk, 0, stream>>>(Q,  Qth, Qtl);
  k_transpose_split<<<dim3(64, 6, BB), blk, 0, stream>>>(Fn, Fth, Ftl);
  // q = dw(conv1x1(Q)) -> pair
  k_ntgemm<3, false, false><<<dim3(3, 128, BB), blk, 0, stream>>>(
      qw1, Qth, Qtl, qb1, nullptr, bufT, CC, NPIX, CC, CC, CC, CC, NPIX,
      0, sT, sQK);
  k_dw3x3_split<<<dim3(16, CC, BB), blk, 0, stream>>>(bufT, qw2, qb2, qh, ql);
  // k = dw(conv1x1(Fn)) -> pair (over dead Qt)
  k_ntgemm<3, false, false><<<dim3(3, 128, BB), blk, 0, stream>>>(
      kw1, Fth, Ftl, kb1, nullptr, bufT, CC, NPIX, CC, CC, CC, CC, NPIX,
      0, sT, sQK);
  k_dw3x3_split<<<dim3(16, CC, BB), blk, 0, stream>>>(bufT, kw2, kb2, kh, kl);
  // v = dw(conv1x1(Fn)) fp32, then transpose-split -> vt (over dead Fnt)
  k_ntgemm<3, false, false><<<dim3(3, 128, BB), blk, 0, stream>>>(
      vw1, Fth, Ftl, vb1, nullptr, bufT, CC, NPIX, CC, CC, CC, CC, NPIX,
      0, sT, sQK);
  k_dw3x3<<<dim3(16, CC, BB), blk, 0, stream>>>(bufT, vw2, vb2, vbuf);
  k_transpose_split<<<dim3(64, 6, BB), blk, 0, stream>>>(vbuf, vth, vtl);
  // norms + attention (exact fp32 path)
  k_rownorm_pair<<<dim3(BB * CC), blk, 0, stream>>>(qh, ql, rq);
  k_rownorm_pair<<<dim3(BB * CC), blk, 0, stream>>>(kh, kl, rk);
  k_attn_partial<<<dim3(9, KSPLIT, BB), blk, 0, stream>>>(qh, ql, kh, kl, part);
  k_softmax_topk<<<dim3(CC, BB), dim3(192), 0, stream>>>(part, rq, rk, temp, attnm);
  k_mix<<<dim3(CC, BB), dim3(192), 0, stream>>>(ow, attnm, Mm);
  // Fa = Mm @ v + ob  (split 3-pass, per-batch A)
  k_ntgemm<3, false, false><<<dim3(3, 128, BB), blk, 0, stream>>>(
      Mm, vth, vtl, ob, nullptr, Fa, CC, NPIX, CC, CC, CC, CC, NPIX,
      (long long)CC * CC, sT, sQK);
  // LN -> xnt (transposed bf16)
  k_ln_t<<<dim3(64, BB), blk, 0, stream>>>(Fa, lnw, lnb, xnt);
  // FFN: per-batch fi + dwglu; merged fo
  for (int b = 0; b < BB; ++b) {
    k_ntgemm<1, true, false><<<dim3(16, 128, 1), blk, 0, stream>>>(
        fiw, xnt + (size_t)b * NPIX * CC, nullptr, fib, nullptr, h_b,
        HID2, NPIX, CC, CC, CC, CC, NPIX, 0, 0, 0);
    k_dwglu_t<<<dim3(64, 16, 1), blk, 0, stream>>>(h_b, fdw, fdb, gt, b);
  }
  k_ntgemm<1, false, true><<<dim3(3, 128, BB), blk, 0, stream>>>(
      fow, gt, nullptr, fob, Fa, out, CC, NPIX, 512, HID, HID, 512, NPIX,
      0, (long long)NPIX * 512, sQK);
}

// Round 5
// 1023.195 us; speedup vs baseline: 2.3080x; 1.2579x over previous
//
#include <hip/hip_runtime.h>
#include <math.h>
#include <float.h>

#define NPIX 16384
#define CC 192
#define BB 4
#define HHH 128
#define WWW 128
#define HID 510
#define HID2 1020
#define KKEEP 172
#define KSPLIT 16

typedef unsigned short ushort;
typedef unsigned int uint32;
using f32x4  = __attribute__((ext_vector_type(4))) float;
using bf16x8 = __attribute__((ext_vector_type(8))) short;

__device__ __forceinline__ float bf2f(ushort u) {
  union { float f; unsigned int i; } x; x.i = ((unsigned int)u) << 16; return x.f;
}
__device__ __forceinline__ ushort f2bf(float f) {
  union { float f; unsigned int i; } x; x.f = f;
  unsigned int r = (x.i + 0x7FFFu + ((x.i >> 16) & 1u)) >> 16;
  return (ushort)r;
}

struct __align__(16) us8 { ushort u[8]; };
struct __align__(8)  us4 { ushort u[4]; };

// ================= TN-MFMA GEMM (3-pass split-bf16, fp32 out) =================
// C[m][n] = sum_k A[m][k] * B[k][n] + bias[m]
// A fp32 [M][lda] (K-contig), B fp32 [K][ldb] (n-contig; transposed during LDS
// staging into hi/lo bf16 planes). Block 64m x 128n, BK=32, 4 waves (2x2).
// Requires: M%64==0, N%128==0, K%32==0 (all call sites satisfy).
__global__ __launch_bounds__(256) void k_gemm_tn(
    const float* __restrict__ A, const float* __restrict__ B,
    const float* __restrict__ bias, float* __restrict__ C,
    int K, int lda,
    long long sAb, long long sBb, long long sCb)
{
  __shared__ ushort As[2][64][40];
  __shared__ ushort Bs[2][128][40];

  const int b = blockIdx.z;
  const int m0 = blockIdx.x * 64;
  const int n0 = blockIdx.y * 128;
  const int tid = threadIdx.x;
  const int lane = tid & 63;
  const int wave = tid >> 6;
  const int wm = wave >> 1, wn = wave & 1;

  const float* Ab = A + (size_t)b * sAb;
  const float* Bb = B + (size_t)b * sBb;

  f32x4 acc[2][4];
  #pragma unroll
  for (int i = 0; i < 2; ++i)
    #pragma unroll
    for (int j = 0; j < 4; ++j) acc[i][j] = (f32x4){0.f, 0.f, 0.f, 0.f};

  const int am = tid >> 2, ak = (tid & 3) * 8;   // A stage: 64 x 32

  for (int kk0 = 0; kk0 < K; kk0 += 32) {
    // ---- stage A: fp32 -> hi/lo bf16 ----
    {
      float v[8];
      #pragma unroll
      for (int t = 0; t < 8; ++t)
        v[t] = Ab[(size_t)(m0 + am) * lda + kk0 + ak + t];
      bf16x8 h8, l8;
      #pragma unroll
      for (int t = 0; t < 8; ++t) {
        const ushort h = f2bf(v[t]);
        h8[t] = (short)h;
        l8[t] = (short)f2bf(v[t] - bf2f(h));
      }
      *reinterpret_cast<bf16x8*>(&As[0][am][ak]) = h8;
      *reinterpret_cast<bf16x8*>(&As[1][am][ak]) = l8;
    }
    // ---- stage B transposed: [32k][128n] fp32 -> Bs[p][n][k] hi/lo ----
    #pragma unroll
    for (int i = 0; i < 2; ++i) {
      const int u = i * 256 + tid;
      const int krp = u >> 5;          // 0..15 -> k = 2*krp
      const int n = (u & 31) * 4;
      const float4 f0 = *reinterpret_cast<const float4*>(
          Bb + (size_t)(kk0 + 2 * krp) * NPIX + n0 + n);
      const float4 f1 = *reinterpret_cast<const float4*>(
          Bb + (size_t)(kk0 + 2 * krp + 1) * NPIX + n0 + n);
      const float e0[4] = {f0.x, f0.y, f0.z, f0.w};
      const float e1[4] = {f1.x, f1.y, f1.z, f1.w};
      #pragma unroll
      for (int j = 0; j < 4; ++j) {
        const ushort h0 = f2bf(e0[j]), h1 = f2bf(e1[j]);
        const ushort l0 = f2bf(e0[j] - bf2f(h0)), l1 = f2bf(e1[j] - bf2f(h1));
        *reinterpret_cast<uint32*>(&Bs[0][n + j][2 * krp]) =
            (uint32)h0 | ((uint32)h1 << 16);
        *reinterpret_cast<uint32*>(&Bs[1][n + j][2 * krp]) =
            (uint32)l0 | ((uint32)l1 << 16);
      }
    }
    __syncthreads();
    // ---- MFMA ----
    bf16x8 af[2][2], bfg[4][2];
    #pragma unroll
    for (int mi = 0; mi < 2; ++mi)
      #pragma unroll
      for (int p = 0; p < 2; ++p)
        af[mi][p] = *reinterpret_cast<const bf16x8*>(
            &As[p][wm * 32 + mi * 16 + (lane & 15)][(lane >> 4) * 8]);
    #pragma unroll
    for (int ni = 0; ni < 4; ++ni)
      #pragma unroll
      for (int p = 0; p < 2; ++p)
        bfg[ni][p] = *reinterpret_cast<const bf16x8*>(
            &Bs[p][wn * 64 + ni * 16 + (lane & 15)][(lane >> 4) * 8]);
    #pragma unroll
    for (int mi = 0; mi < 2; ++mi)
      #pragma unroll
      for (int ni = 0; ni < 4; ++ni) {
        acc[mi][ni] = __builtin_amdgcn_mfma_f32_16x16x32_bf16(
            af[mi][0], bfg[ni][0], acc[mi][ni], 0, 0, 0);
        acc[mi][ni] = __builtin_amdgcn_mfma_f32_16x16x32_bf16(
            af[mi][0], bfg[ni][1], acc[mi][ni], 0, 0, 0);
        acc[mi][ni] = __builtin_amdgcn_mfma_f32_16x16x32_bf16(
            af[mi][1], bfg[ni][0], acc[mi][ni], 0, 0, 0);
      }
    __syncthreads();
  }

  #pragma unroll
  for (int mi = 0; mi < 2; ++mi)
    #pragma unroll
    for (int r = 0; r < 4; ++r) {
      const int m = m0 + wm * 32 + mi * 16 + (lane >> 4) * 4 + r;
      const float bv = bias[m];
      #pragma unroll
      for (int ni = 0; ni < 4; ++ni) {
        const int n = n0 + wn * 64 + ni * 16 + (lane & 15);
        C[(size_t)b * sCb + (size_t)m * NPIX + n] = acc[mi][ni][r] + bv;
      }
    }
}

// ================= NT-MFMA GEMM (B = bf16 planes; from R4, verified) =========
template<int PASSES, bool OUT_BF16, bool ADD_RES>
__global__ __launch_bounds__(256) void k_ntgemm(
    const float* __restrict__ A,
    const ushort* __restrict__ Bh, const ushort* __restrict__ Bl,
    const float* __restrict__ bias, const float* __restrict__ res,
    void* __restrict__ Cptr,
    int Mvalid, int Nvalid, int K, int Kvalid,
    int lda, int ldb, int ldc,
    long long sAb, long long sBb, long long sCb)
{
  constexpr int PL = (PASSES == 3) ? 2 : 1;
  __shared__ ushort As[PL][64][40];
  __shared__ ushort Bs[PL][128][40];

  const int b = blockIdx.z;
  const int m0 = blockIdx.x * 64;
  const int n0 = blockIdx.y * 128;
  const int tid = threadIdx.x;
  const int lane = tid & 63;
  const int wave = tid >> 6;
  const int wm = wave >> 1, wn = wave & 1;

  const float*  Ab  = A  + (size_t)b * sAb;
  const ushort* Bhb = Bh + (size_t)b * sBb;
  const ushort* Blb = (PL == 2) ? (Bl + (size_t)b * sBb) : nullptr;

  f32x4 acc[2][4];
  #pragma unroll
  for (int i = 0; i < 2; ++i)
    #pragma unroll
    for (int j = 0; j < 4; ++j) acc[i][j] = (f32x4){0.f, 0.f, 0.f, 0.f};

  const int am = tid >> 2, ak = (tid & 3) * 8;
  const int bn = tid >> 1, bk = (tid & 1) * 16;

  for (int kk0 = 0; kk0 < K; kk0 += 32) {
    {
      float v[8];
      const bool mok = (m0 + am) < Mvalid;
      #pragma unroll
      for (int t = 0; t < 8; ++t) {
        const int k = kk0 + ak + t;
        v[t] = (mok && k < Kvalid) ? Ab[(size_t)(m0 + am) * lda + k] : 0.f;
      }
      bf16x8 h8, l8;
      #pragma unroll
      for (int t = 0; t < 8; ++t) {
        const ushort h = f2bf(v[t]);
        h8[t] = (short)h;
        if (PL == 2) l8[t] = (short)f2bf(v[t] - bf2f(h));
      }
      *reinterpret_cast<bf16x8*>(&As[0][am][ak]) = h8;
      if (PL == 2) *reinterpret_cast<bf16x8*>(&As[1][am][ak]) = l8;
    }
    {
      const bool nok = (n0 + bn) < Nvalid;
      const size_t off = (size_t)(n0 + bn) * ldb + kk0 + bk;
      us8 z;
      #pragma unroll
      for (int t = 0; t < 8; ++t) z.u[t] = 0;
      us8 v0 = nok ? *reinterpret_cast<const us8*>(Bhb + off)     : z;
      us8 v1 = nok ? *reinterpret_cast<const us8*>(Bhb + off + 8) : z;
      *reinterpret_cast<us8*>(&Bs[0][bn][bk])     = v0;
      *reinterpret_cast<us8*>(&Bs[0][bn][bk + 8]) = v1;
      if (PL == 2) {
        us8 w0 = nok ? *reinterpret_cast<const us8*>(Blb + off)     : z;
        us8 w1 = nok ? *reinterpret_cast<const us8*>(Blb + off + 8) : z;
        *reinterpret_cast<us8*>(&Bs[1][bn][bk])     = w0;
        *reinterpret_cast<us8*>(&Bs[1][bn][bk + 8]) = w1;
      }
    }
    __syncthreads();
    bf16x8 af[2][PL], bfg[4][PL];
    #pragma unroll
    for (int mi = 0; mi < 2; ++mi)
      #pragma unroll
      for (int p = 0; p < PL; ++p)
        af[mi][p] = *reinterpret_cast<const bf16x8*>(
            &As[p][wm * 32 + mi * 16 + (lane & 15)][(lane >> 4) * 8]);
    #pragma unroll
    for (int ni = 0; ni < 4; ++ni)
      #pragma unroll
      for (int p = 0; p < PL; ++p)
        bfg[ni][p] = *reinterpret_cast<const bf16x8*>(
            &Bs[p][wn * 64 + ni * 16 + (lane & 15)][(lane >> 4) * 8]);
    #pragma unroll
    for (int mi = 0; mi < 2; ++mi)
      #pragma unroll
      for (int ni = 0; ni < 4; ++ni) {
        acc[mi][ni] = __builtin_amdgcn_mfma_f32_16x16x32_bf16(
            af[mi][0], bfg[ni][0], acc[mi][ni], 0, 0, 0);
        if (PL == 2) {
          acc[mi][ni] = __builtin_amdgcn_mfma_f32_16x16x32_bf16(
              af[mi][0], bfg[ni][1], acc[mi][ni], 0, 0, 0);
          acc[mi][ni] = __builtin_amdgcn_mfma_f32_16x16x32_bf16(
              af[mi][1], bfg[ni][0], acc[mi][ni], 0, 0, 0);
        }
      }
    __syncthreads();
  }

  #pragma unroll
  for (int mi = 0; mi < 2; ++mi)
    #pragma unroll
    for (int r = 0; r < 4; ++r) {
      const int m = m0 + wm * 32 + mi * 16 + (lane >> 4) * 4 + r;
      if (m >= Mvalid) continue;
      const float bv = bias[m];
      #pragma unroll
      for (int ni = 0; ni < 4; ++ni) {
        const int n = n0 + wn * 64 + ni * 16 + (lane & 15);
        if (n >= Nvalid) continue;
        float v = acc[mi][ni][r] + bv;
        if (ADD_RES) v += res[(size_t)b * sCb + (size_t)m * ldc + n];
        if (OUT_BF16)
          ((ushort*)Cptr)[(size_t)b * sCb + (size_t)m * ldc + n] = f2bf(v);
        else
          ((float*)Cptr)[(size_t)b * sCb + (size_t)m * ldc + n] = v;
      }
    }
}

// ================= attn logits: MFMA 3-pass split-K =================
// part[chunk][b][c][d] = sum over K-chunk of q[c,:]*k[d,:]
__global__ __launch_bounds__(256) void k_attn_mfma(
    const ushort* __restrict__ qh, const ushort* __restrict__ ql,
    const ushort* __restrict__ kh, const ushort* __restrict__ kl,
    float* __restrict__ part)
{
  __shared__ ushort As[2][64][40];
  __shared__ ushort Bs[2][64][40];
  const int b = blockIdx.z;
  const int tr = blockIdx.x / 3, tc = blockIdx.x % 3;
  const int r0 = tr * 64, c0 = tc * 64;
  const int k0 = blockIdx.y * (NPIX / KSPLIT);
  const int tid = threadIdx.x;
  const int lane = tid & 63;
  const int wave = tid >> 6;
  const int wm = wave >> 1, wn = wave & 1;

  f32x4 acc[2][2];
  #pragma unroll
  for (int i = 0; i < 2; ++i)
    #pragma unroll
    for (int j = 0; j < 2; ++j) acc[i][j] = (f32x4){0.f, 0.f, 0.f, 0.f};

  const int ar = tid >> 2, ak = (tid & 3) * 8;

  for (int kc = 0; kc < NPIX / KSPLIT; kc += 32) {
    const size_t qo = (size_t)(b * CC + r0 + ar) * NPIX + k0 + kc + ak;
    const size_t ko = (size_t)(b * CC + c0 + ar) * NPIX + k0 + kc + ak;
    *reinterpret_cast<us8*>(&As[0][ar][ak]) = *reinterpret_cast<const us8*>(qh + qo);
    *reinterpret_cast<us8*>(&As[1][ar][ak]) = *reinterpret_cast<const us8*>(ql + qo);
    *reinterpret_cast<us8*>(&Bs[0][ar][ak]) = *reinterpret_cast<const us8*>(kh + ko);
    *reinterpret_cast<us8*>(&Bs[1][ar][ak]) = *reinterpret_cast<const us8*>(kl + ko);
    __syncthreads();
    bf16x8 af[2][2], bfr[2][2];
    #pragma unroll
    for (int mi = 0; mi < 2; ++mi)
      #pragma unroll
      for (int p = 0; p < 2; ++p)
        af[mi][p] = *reinterpret_cast<const bf16x8*>(
            &As[p][wm * 32 + mi * 16 + (lane & 15)][(lane >> 4) * 8]);
    #pragma unroll
    for (int ni = 0; ni < 2; ++ni)
      #pragma unroll
      for (int p = 0; p < 2; ++p)
        bfr[ni][p] = *reinterpret_cast<const bf16x8*>(
            &Bs[p][wn * 32 + ni * 16 + (lane & 15)][(lane >> 4) * 8]);
    #pragma unroll
    for (int mi = 0; mi < 2; ++mi)
      #pragma unroll
      for (int ni = 0; ni < 2; ++ni) {
        acc[mi][ni] = __builtin_amdgcn_mfma_f32_16x16x32_bf16(
            af[mi][0], bfr[ni][0], acc[mi][ni], 0, 0, 0);
        acc[mi][ni] = __builtin_amdgcn_mfma_f32_16x16x32_bf16(
            af[mi][0], bfr[ni][1], acc[mi][ni], 0, 0, 0);
        acc[mi][ni] = __builtin_amdgcn_mfma_f32_16x16x32_bf16(
            af[mi][1], bfr[ni][0], acc[mi][ni], 0, 0, 0);
      }
    __syncthreads();
  }

  float* pp = part + (size_t)(blockIdx.y * BB + b) * CC * CC;
  #pragma unroll
  for (int mi = 0; mi < 2; ++mi)
    #pragma unroll
    for (int r = 0; r < 4; ++r) {
      const int row = r0 + wm * 32 + mi * 16 + (lane >> 4) * 4 + r;
      #pragma unroll
      for (int ni = 0; ni < 2; ++ni) {
        const int col = c0 + wn * 32 + ni * 16 + (lane & 15);
        pp[(size_t)row * CC + col] = acc[mi][ni][r];
      }
    }
}

// ================= depthwise 3x3 =================
__device__ __forceinline__ void dw4(const float* __restrict__ Xc,
                                    const float* __restrict__ wt, float bv,
                                    int h, int w, float out[4])
{
  float a0, a1, a2, a3;
  a0 = a1 = a2 = a3 = bv;
  #pragma unroll
  for (int dy = 0; dy < 3; ++dy) {
    const int hh = h + dy - 1;
    if (hh < 0 || hh >= HHH) continue;
    const float* row = Xc + hh * WWW + w;
    const float xm = (w > 0) ? row[-1] : 0.f;
    const float4 xc = *reinterpret_cast<const float4*>(row);
    const float xp = (w < WWW - 4) ? row[4] : 0.f;
    const float w0 = wt[dy * 3 + 0], w1 = wt[dy * 3 + 1], w2 = wt[dy * 3 + 2];
    a0 += w0 * xm   + w1 * xc.x + w2 * xc.y;
    a1 += w0 * xc.x + w1 * xc.y + w2 * xc.z;
    a2 += w0 * xc.y + w1 * xc.z + w2 * xc.w;
    a3 += w0 * xc.z + w1 * xc.w + w2 * xp;
  }
  out[0] = a0; out[1] = a1; out[2] = a2; out[3] = a3;
}

__global__ __launch_bounds__(256) void k_dw3x3(
    const float* __restrict__ X, const float* __restrict__ W9,
    const float* __restrict__ bias, float* __restrict__ Y)
{
  const int b = blockIdx.z, c = blockIdx.y;
  const int p = blockIdx.x * 1024 + threadIdx.x * 4;
  const int h = p >> 7, w = p & 127;
  float o[4];
  dw4(X + (size_t)(b * CC + c) * NPIX, W9 + c * 9, bias[c], h, w, o);
  *reinterpret_cast<float4*>(Y + (size_t)(b * CC + c) * NPIX + p) =
      make_float4(o[0], o[1], o[2], o[3]);
}

__global__ __launch_bounds__(256) void k_dw3x3_split(
    const float* __restrict__ X, const float* __restrict__ W9,
    const float* __restrict__ bias, ushort* __restrict__ Yh,
    ushort* __restrict__ Yl)
{
  const int b = blockIdx.z, c = blockIdx.y;
  const int p = blockIdx.x * 1024 + threadIdx.x * 4;
  const int h = p >> 7, w = p & 127;
  float o[4];
  dw4(X + (size_t)(b * CC + c) * NPIX, W9 + c * 9, bias[c], h, w, o);
  us4 hi, lo;
  #pragma unroll
  for (int t = 0; t < 4; ++t) {
    const ushort hv = f2bf(o[t]);
    hi.u[t] = hv;
    lo.u[t] = f2bf(o[t] - bf2f(hv));
  }
  const size_t off = (size_t)(b * CC + c) * NPIX + p;
  *reinterpret_cast<us4*>(Yh + off) = hi;
  *reinterpret_cast<us4*>(Yl + off) = lo;
}

// ================= row L2 norms (q & k merged) =================
__global__ __launch_bounds__(256) void k_rownorm2(
    const ushort* __restrict__ qh, const ushort* __restrict__ ql,
    const ushort* __restrict__ kh, const ushort* __restrict__ kl,
    float* __restrict__ rq, float* __restrict__ rk)
{
  const int row = blockIdx.x;
  const ushort* H = blockIdx.y ? kh : qh;
  const ushort* L = blockIdx.y ? kl : ql;
  float* R = blockIdx.y ? rk : rq;
  const ushort* Hr = H + (size_t)row * NPIX;
  const ushort* Lr = L + (size_t)row * NPIX;
  float s = 0.f;
  for (int i = threadIdx.x * 8; i < NPIX; i += 2048) {
    const us8 a = *reinterpret_cast<const us8*>(Hr + i);
    const us8 bb = *reinterpret_cast<const us8*>(Lr + i);
    #pragma unroll
    for (int t = 0; t < 8; ++t) {
      const float v = bf2f(a.u[t]) + bf2f(bb.u[t]);
      s += v * v;
    }
  }
  __shared__ float sm[256];
  sm[threadIdx.x] = s; __syncthreads();
  for (int st = 128; st > 0; st >>= 1) {
    if (threadIdx.x < st) sm[threadIdx.x] += sm[threadIdx.x + st];
    __syncthreads();
  }
  if (threadIdx.x == 0) R[row] = 1.f / fmaxf(sqrtf(sm[0]), 1e-12f);
}

// ================= softmax + topk mask =================
__global__ __launch_bounds__(192) void k_softmax_topk(
    const float* __restrict__ part, const float* __restrict__ rq,
    const float* __restrict__ rk, const float* __restrict__ temp,
    float* __restrict__ attnm)
{
  const int c = blockIdx.x, b = blockIdx.y, d = threadIdx.x;
  float s = 0.f;
  for (int ksp = 0; ksp < KSPLIT; ++ksp)
    s += part[(size_t)(ksp * BB + b) * CC * CC + c * CC + d];
  const float logit = s * rq[b * CC + c] * rk[b * CC + d] * temp[0];
  __shared__ float sa[CC], sb[CC];
  sa[d] = logit; __syncthreads();
  float mx = -FLT_MAX;
  for (int j = 0; j < CC; ++j) mx = fmaxf(mx, sa[j]);
  const float e = expf(logit - mx);
  sb[d] = e; __syncthreads();
  float sum = 0.f;
  for (int j = 0; j < CC; ++j) sum += sb[j];
  const float pv = e / sum;
  __syncthreads();
  sa[d] = pv; __syncthreads();
  int greater = 0;
  for (int j = 0; j < CC; ++j) greater += (sa[j] > pv) ? 1 : 0;
  const float cand = (greater < KKEEP) ? pv : FLT_MAX;
  sb[d] = cand; __syncthreads();
  float thr = FLT_MAX;
  for (int j = 0; j < CC; ++j) thr = fminf(thr, sb[j]);
  attnm[(size_t)(b * CC + c) * CC + d] = (pv >= thr) ? pv : 0.f;
}

// ================= M[b] = ow @ attnm[b] =================
__global__ __launch_bounds__(192) void k_mix(
    const float* __restrict__ ow, const float* __restrict__ attnm,
    float* __restrict__ M)
{
  const int c = blockIdx.x, b = blockIdx.y, d = threadIdx.x;
  float acc = 0.f;
  for (int e = 0; e < CC; ++e)
    acc += ow[c * CC + e] * attnm[(size_t)(b * CC + e) * CC + d];
  M[(size_t)(b * CC + c) * CC + d] = acc;
}

// ================= LayerNorm -> transposed bf16 [px][192] =================
__global__ __launch_bounds__(256) void k_ln_t(
    const float* __restrict__ X, const float* __restrict__ lw,
    const float* __restrict__ lb, ushort* __restrict__ Y)
{
  const int b = blockIdx.y;
  const int n = blockIdx.x * 256 + threadIdx.x;
  const float* Xb = X + (size_t)b * CC * NPIX + n;
  float s = 0.f, s2 = 0.f;
  for (int ci = 0; ci < CC; ++ci) {
    const float v = Xb[(size_t)ci * NPIX];
    s += v; s2 += v * v;
  }
  const float mu = s * (1.f / CC);
  const float var = fmaxf(s2 * (1.f / CC) - mu * mu, 0.f);
  const float rstd = rsqrtf(var + 1e-5f);
  ushort* Yb = Y + ((size_t)b * NPIX + n) * CC;
  for (int c8 = 0; c8 < CC / 8; ++c8) {
    bf16x8 sv;
    #pragma unroll
    for (int t = 0; t < 8; ++t) {
      const int c = c8 * 8 + t;
      const float v = Xb[(size_t)c * NPIX];
      sv[t] = (short)f2bf((v - mu) * rstd * lw[c] + lb[c]);
    }
    *reinterpret_cast<bf16x8*>(Yb + c8 * 8) = sv;
  }
}

// ================= fused depthwise 3x3 + GLU, coalesced transposed out ======
__device__ __forceinline__ float gelu_exact(float x) {
  return 0.5f * x * (1.f + erff(x * 0.70710678118654752f));
}

// h_b bf16 [1020][NPIX] -> gt[b] bf16 [NPIX][512] (cols 510,511 zero)
__global__ __launch_bounds__(256) void k_dwglu_t(
    const ushort* __restrict__ Hb, const float* __restrict__ fdw,
    const float* __restrict__ fdb, ushort* __restrict__ gt, int b)
{
  __shared__ ushort hs[64][4][128];
  __shared__ ushort gs[256][32];
  const int tid = threadIdx.x;
  const int h0 = blockIdx.x * 2;
  const int c0 = blockIdx.y * 32;
  const int npairs = min(32, HID - c0);
  #pragma unroll
  for (int i = 0; i < 16; ++i) {
    const int u = i * 256 + tid;
    const int ch = u >> 6;
    const int row = (u >> 4) & 3;
    const int w0 = (u & 15) * 8;
    const int grow = h0 - 1 + row;
    const int cloc = (ch < 32) ? ch : (ch - 32);
    const int gch = (ch < 32) ? (c0 + ch) : (HID + c0 + ch - 32);
    us8 v;
    #pragma unroll
    for (int t = 0; t < 8; ++t) v.u[t] = 0;
    if (c0 + cloc < HID && grow >= 0 && grow < HHH)
      v = *reinterpret_cast<const us8*>(Hb + (size_t)gch * NPIX + grow * WWW + w0);
    *reinterpret_cast<us8*>(&hs[ch][row][w0]) = v;
  }
  __syncthreads();
  const int dh = tid >> 7, w = tid & 127;
  for (int jc = 0; jc < 4; ++jc) {
    bf16x8 sv;
    #pragma unroll
    for (int jj = 0; jj < 8; ++jj) {
      const int j = jc * 8 + jj;
      float val = 0.f;
      if (j < npairs) {
        float x1 = fdb[c0 + j], x2 = fdb[HID + c0 + j];
        const float* w1 = fdw + (size_t)(c0 + j) * 9;
        const float* w2 = fdw + (size_t)(HID + c0 + j) * 9;
        #pragma unroll
        for (int dy = 0; dy < 3; ++dy)
          #pragma unroll
          for (int dx = 0; dx < 3; ++dx) {
            const int ww = w + dx - 1;
            if (ww >= 0 && ww < WWW) {
              x1 += w1[dy * 3 + dx] * bf2f(hs[j][dh + dy][ww]);
              x2 += w2[dy * 3 + dx] * bf2f(hs[32 + j][dh + dy][ww]);
            }
          }
        val = x1 * gelu_exact(x2);
      }
      sv[jj] = (short)f2bf(val);
    }
    *reinterpret_cast<bf16x8*>(&gs[tid][jc * 8]) = sv;
  }
  __syncthreads();
  // coalesced write-out: 4 lanes cover 64 B contiguous per pixel
  #pragma unroll
  for (int pp = 0; pp < 4; ++pp) {
    const int px_l = pp * 64 + (tid >> 2);
    const int cseg = (tid & 3) * 8;
    const int px = (h0 + (px_l >> 7)) * WWW + (px_l & 127);
    const us8 v = *reinterpret_cast<const us8*>(&gs[px_l][cseg]);
    *reinterpret_cast<us8*>(gt + ((size_t)b * NPIX + px) * 512 + c0 + cseg) = v;
  }
}

// ================= launch =================
// Workspace (P = 25,165,824; peak 176 MB — same as passing R4):
//  qh [0,P) ql [P,2P) kh [2P,3P) kl [3P,4P)     (dead after attn)
//  vbuf fp32 [4P,6P)                            (dead after Fa gemm)
//  smalls [6P, 6P+10.7M): rq/rk/part/attnm/Mm   (dead after Fa gemm)
//  Fa fp32 [0,2P) ; xnt bf16 [2P,3P)
//  h_b bf16 [3P, 3P+33.4M) ; gt bf16 [3P+33.4M, 3P+100.3M)
//  stage-1 temp = d_out (fully rewritten by final fo gemm)
extern "C" void kernel_launch(void* const* d_in, const int* in_sizes, int n_in,
                              void* d_out, int out_size, void* d_ws, size_t ws_size,
                              hipStream_t stream)
{
  const float* Q    = (const float*)d_in[0];
  const float* Fn   = (const float*)d_in[1];
  const float* temp = (const float*)d_in[2];
  const float* qw1  = (const float*)d_in[3];
  const float* qb1  = (const float*)d_in[4];
  const float* qw2  = (const float*)d_in[5];
  const float* qb2  = (const float*)d_in[6];
  const float* kw1  = (const float*)d_in[7];
  const float* kb1  = (const float*)d_in[8];
  const float* kw2  = (const float*)d_in[9];
  const float* kb2  = (const float*)d_in[10];
  const float* vw1  = (const float*)d_in[11];
  const float* vb1  = (const float*)d_in[12];
  const float* vw2  = (const float*)d_in[13];
  const float* vb2  = (const float*)d_in[14];
  const float* ow   = (const float*)d_in[15];
  const float* ob   = (const float*)d_in[16];
  const float* lnw  = (const float*)d_in[17];
  const float* lnb  = (const float*)d_in[18];
  const float* fiw  = (const float*)d_in[19];
  const float* fib  = (const float*)d_in[20];
  const float* fdw  = (const float*)d_in[21];
  const float* fdb  = (const float*)d_in[22];
  const float* fow  = (const float*)d_in[23];
  const float* fob  = (const float*)d_in[24];
  float* out = (float*)d_out;

  char* ws = (char*)d_ws;
  const size_t P = 25165824UL;
  ushort* qh = (ushort*)(ws + 0 * P);
  ushort* ql = (ushort*)(ws + 1 * P);
  ushort* kh = (ushort*)(ws + 2 * P);
  ushort* kl = (ushort*)(ws + 3 * P);
  float*  vbuf = (float*)(ws + 4 * P);
  char* smb = ws + 6 * P;
  float* rq    = (float*)(smb);
  float* rk    = (float*)(smb + 4096);
  float* part  = (float*)(smb + 8192);                       // 9,437,184
  float* attnm = (float*)(smb + 8192 + 9437184);
  float* Mm    = (float*)(smb + 8192 + 9437184 + 589824);
  float*  Fa  = (float*)(ws + 0 * P);
  ushort* xnt = (ushort*)(ws + 2 * P);
  ushort* h_b = (ushort*)(ws + 3 * P);
  ushort* gt  = (ushort*)(ws + 3 * P + 33423360UL);
  float* bufT = out;

  const long long sX = (long long)CC * NPIX;   // [c][px] batch stride

  dim3 blk(256);
  dim3 gTN(3, 128, BB);

  // stage-1 1x1 convs via TN-MFMA (B = input fp32 directly, no transpose pass)
  k_gemm_tn<<<gTN, blk, 0, stream>>>(qw1, Q,  qb1, bufT, CC, CC, 0, sX, sX);
  k_dw3x3_split<<<dim3(16, CC, BB), blk, 0, stream>>>(bufT, qw2, qb2, qh, ql);
  k_gemm_tn<<<gTN, blk, 0, stream>>>(kw1, Fn, kb1, bufT, CC, CC, 0, sX, sX);
  k_dw3x3_split<<<dim3(16, CC, BB), blk, 0, stream>>>(bufT, kw2, kb2, kh, kl);
  k_gemm_tn<<<gTN, blk, 0, stream>>>(vw1, Fn, vb1, bufT, CC, CC, 0, sX, sX);
  k_dw3x3<<<dim3(16, CC, BB), blk, 0, stream>>>(bufT, vw2, vb2, vbuf);
  // norms + attention
  k_rownorm2<<<dim3(BB * CC, 2), blk, 0, stream>>>(qh, ql, kh, kl, rq, rk);
  k_attn_mfma<<<dim3(9, KSPLIT, BB), blk, 0, stream>>>(qh, ql, kh, kl, part);
  k_softmax_topk<<<dim3(CC, BB), dim3(192), 0, stream>>>(part, rq, rk, temp, attnm);
  k_mix<<<dim3(CC, BB), dim3(192), 0, stream>>>(ow, attnm, Mm);
  // Fa = Mm @ v + ob  (TN: B = vbuf fp32, no vt materialization)
  k_gemm_tn<<<gTN, blk, 0, stream>>>(Mm, vbuf, ob, Fa, CC, CC,
                                     (long long)CC * CC, sX, sX);
  // LN -> xnt
  k_ln_t<<<dim3(64, BB), blk, 0, stream>>>(Fa, lnw, lnb, xnt);
  // FFN per batch: fi (NT, bf16 B-planes) + dwglu; merged fo
  for (int b = 0; b < BB; ++b) {
    k_ntgemm<1, true, false><<<dim3(16, 128, 1), blk, 0, stream>>>(
        fiw, xnt + (size_t)b * NPIX * CC, nullptr, fib, nullptr, h_b,
        HID2, NPIX, CC, CC, CC, CC, NPIX, 0, 0, 0);
    k_dwglu_t<<<dim3(64, 16, 1), blk, 0, stream>>>(h_b, fdw, fdb, gt, b);
  }
  k_ntgemm<1, false, true><<<gTN, blk, 0, stream>>>(
      fow, gt, nullptr, fob, Fa, out, CC, NPIX, 512, HID, HID, 512, NPIX,
      0, (long long)NPIX * 512, sX);
}

// Round 6
// 984.070 us; speedup vs baseline: 2.3998x; 1.0398x over previous
//
#include <hip/hip_runtime.h>
#include <math.h>
#include <float.h>

#define NPIX 16384
#define CC 192
#define BB 4
#define HHH 128
#define WWW 128
#define HID 510
#define HID2 1020
#define KKEEP 172
#define KSPLIT 16

typedef unsigned short ushort;
typedef unsigned int uint32;
using f32x4  = __attribute__((ext_vector_type(4))) float;
using bf16x8 = __attribute__((ext_vector_type(8))) short;

__device__ __forceinline__ float bf2f(ushort u) {
  union { float f; unsigned int i; } x; x.i = ((unsigned int)u) << 16; return x.f;
}
__device__ __forceinline__ ushort f2bf(float f) {
  union { float f; unsigned int i; } x; x.f = f;
  unsigned int r = (x.i + 0x7FFFu + ((x.i >> 16) & 1u)) >> 16;
  return (ushort)r;
}

struct __align__(16) us8 { ushort u[8]; };
struct __align__(8)  us4 { ushort u[4]; };

// ================= TN-MFMA GEMM (3-pass split-bf16, fp32 out) =================
// C[m][n] = sum_k A[m][k]*B[k][n] + bias[m].  A fp32 [M][lda] K-contig,
// B fp32 [K][NPIX] n-contig (transposed in staging). Grid: x=n (fast), y=m.
__global__ __launch_bounds__(256) void k_gemm_tn(
    const float* __restrict__ A, const float* __restrict__ B,
    const float* __restrict__ bias, float* __restrict__ C,
    int K, int lda,
    long long sAb, long long sBb, long long sCb)
{
  __shared__ ushort As[2][64][40];
  __shared__ ushort Bs[2][128][40];

  const int b = blockIdx.z;
  const int m0 = blockIdx.y * 64;
  const int n0 = blockIdx.x * 128;
  const int tid = threadIdx.x;
  const int lane = tid & 63;
  const int wave = tid >> 6;
  const int wm = wave >> 1, wn = wave & 1;

  const float* Ab = A + (size_t)b * sAb;
  const float* Bb = B + (size_t)b * sBb;

  f32x4 acc[2][4];
  #pragma unroll
  for (int i = 0; i < 2; ++i)
    #pragma unroll
    for (int j = 0; j < 4; ++j) acc[i][j] = (f32x4){0.f, 0.f, 0.f, 0.f};

  const int am = tid >> 2, ak = (tid & 3) * 8;

  for (int kk0 = 0; kk0 < K; kk0 += 32) {
    {
      float v[8];
      #pragma unroll
      for (int t = 0; t < 8; ++t)
        v[t] = Ab[(size_t)(m0 + am) * lda + kk0 + ak + t];
      bf16x8 h8, l8;
      #pragma unroll
      for (int t = 0; t < 8; ++t) {
        const ushort h = f2bf(v[t]);
        h8[t] = (short)h;
        l8[t] = (short)f2bf(v[t] - bf2f(h));
      }
      *reinterpret_cast<bf16x8*>(&As[0][am][ak]) = h8;
      *reinterpret_cast<bf16x8*>(&As[1][am][ak]) = l8;
    }
    #pragma unroll
    for (int i = 0; i < 2; ++i) {
      const int u = i * 256 + tid;
      const int krp = u >> 5;
      const int n = (u & 31) * 4;
      const float4 f0 = *reinterpret_cast<const float4*>(
          Bb + (size_t)(kk0 + 2 * krp) * NPIX + n0 + n);
      const float4 f1 = *reinterpret_cast<const float4*>(
          Bb + (size_t)(kk0 + 2 * krp + 1) * NPIX + n0 + n);
      const float e0[4] = {f0.x, f0.y, f0.z, f0.w};
      const float e1[4] = {f1.x, f1.y, f1.z, f1.w};
      #pragma unroll
      for (int j = 0; j < 4; ++j) {
        const ushort h0 = f2bf(e0[j]), h1 = f2bf(e1[j]);
        const ushort l0 = f2bf(e0[j] - bf2f(h0)), l1 = f2bf(e1[j] - bf2f(h1));
        *reinterpret_cast<uint32*>(&Bs[0][n + j][2 * krp]) =
            (uint32)h0 | ((uint32)h1 << 16);
        *reinterpret_cast<uint32*>(&Bs[1][n + j][2 * krp]) =
            (uint32)l0 | ((uint32)l1 << 16);
      }
    }
    __syncthreads();
    bf16x8 af[2][2], bfg[4][2];
    #pragma unroll
    for (int mi = 0; mi < 2; ++mi)
      #pragma unroll
      for (int p = 0; p < 2; ++p)
        af[mi][p] = *reinterpret_cast<const bf16x8*>(
            &As[p][wm * 32 + mi * 16 + (lane & 15)][(lane >> 4) * 8]);
    #pragma unroll
    for (int ni = 0; ni < 4; ++ni)
      #pragma unroll
      for (int p = 0; p < 2; ++p)
        bfg[ni][p] = *reinterpret_cast<const bf16x8*>(
            &Bs[p][wn * 64 + ni * 16 + (lane & 15)][(lane >> 4) * 8]);
    #pragma unroll
    for (int mi = 0; mi < 2; ++mi)
      #pragma unroll
      for (int ni = 0; ni < 4; ++ni) {
        acc[mi][ni] = __builtin_amdgcn_mfma_f32_16x16x32_bf16(
            af[mi][0], bfg[ni][0], acc[mi][ni], 0, 0, 0);
        acc[mi][ni] = __builtin_amdgcn_mfma_f32_16x16x32_bf16(
            af[mi][0], bfg[ni][1], acc[mi][ni], 0, 0, 0);
        acc[mi][ni] = __builtin_amdgcn_mfma_f32_16x16x32_bf16(
            af[mi][1], bfg[ni][0], acc[mi][ni], 0, 0, 0);
      }
    __syncthreads();
  }

  #pragma unroll
  for (int mi = 0; mi < 2; ++mi)
    #pragma unroll
    for (int r = 0; r < 4; ++r) {
      const int m = m0 + wm * 32 + mi * 16 + (lane >> 4) * 4 + r;
      const float bv = bias[m];
      #pragma unroll
      for (int ni = 0; ni < 4; ++ni) {
        const int n = n0 + wn * 64 + ni * 16 + (lane & 15);
        C[(size_t)b * sCb + (size_t)m * NPIX + n] = acc[mi][ni][r] + bv;
      }
    }
}

// ================= NT-MFMA GEMM (fo: B bf16 planes, fp32 out + res) ==========
// Grid: x=n (fast), y=m.  B-staging coalesced: 4 lanes/row cover 64 B.
template<bool ADD_RES>
__global__ __launch_bounds__(256) void k_ntgemm(
    const float* __restrict__ A, const ushort* __restrict__ Bh,
    const float* __restrict__ bias, const float* __restrict__ res,
    float* __restrict__ C,
    int Mvalid, int K, int Kvalid, int lda, int ldb,
    long long sBb, long long sCb)
{
  __shared__ ushort As[64][40];
  __shared__ ushort Bs[128][40];

  const int b = blockIdx.z;
  const int m0 = blockIdx.y * 64;
  const int n0 = blockIdx.x * 128;
  const int tid = threadIdx.x;
  const int lane = tid & 63;
  const int wave = tid >> 6;
  const int wm = wave >> 1, wn = wave & 1;

  const ushort* Bhb = Bh + (size_t)b * sBb;

  f32x4 acc[2][4];
  #pragma unroll
  for (int i = 0; i < 2; ++i)
    #pragma unroll
    for (int j = 0; j < 4; ++j) acc[i][j] = (f32x4){0.f, 0.f, 0.f, 0.f};

  const int am = tid >> 2, ak = (tid & 3) * 8;

  for (int kk0 = 0; kk0 < K; kk0 += 32) {
    {
      float v[8];
      const bool mok = (m0 + am) < Mvalid;
      #pragma unroll
      for (int t = 0; t < 8; ++t) {
        const int k = kk0 + ak + t;
        v[t] = (mok && k < Kvalid) ? A[(size_t)(m0 + am) * lda + k] : 0.f;
      }
      bf16x8 h8;
      #pragma unroll
      for (int t = 0; t < 8; ++t) h8[t] = (short)f2bf(v[t]);
      *reinterpret_cast<bf16x8*>(&As[am][ak]) = h8;
    }
    #pragma unroll
    for (int i = 0; i < 2; ++i) {
      const int u = i * 256 + tid;
      const int bn = u >> 2;
      const int bk = (u & 3) * 8;
      *reinterpret_cast<us8*>(&Bs[bn][bk]) =
          *reinterpret_cast<const us8*>(Bhb + (size_t)(n0 + bn) * ldb + kk0 + bk);
    }
    __syncthreads();
    bf16x8 af[2], bfg[4];
    #pragma unroll
    for (int mi = 0; mi < 2; ++mi)
      af[mi] = *reinterpret_cast<const bf16x8*>(
          &As[wm * 32 + mi * 16 + (lane & 15)][(lane >> 4) * 8]);
    #pragma unroll
    for (int ni = 0; ni < 4; ++ni)
      bfg[ni] = *reinterpret_cast<const bf16x8*>(
          &Bs[wn * 64 + ni * 16 + (lane & 15)][(lane >> 4) * 8]);
    #pragma unroll
    for (int mi = 0; mi < 2; ++mi)
      #pragma unroll
      for (int ni = 0; ni < 4; ++ni)
        acc[mi][ni] = __builtin_amdgcn_mfma_f32_16x16x32_bf16(
            af[mi], bfg[ni], acc[mi][ni], 0, 0, 0);
    __syncthreads();
  }

  #pragma unroll
  for (int mi = 0; mi < 2; ++mi)
    #pragma unroll
    for (int r = 0; r < 4; ++r) {
      const int m = m0 + wm * 32 + mi * 16 + (lane >> 4) * 4 + r;
      if (m >= Mvalid) continue;
      const float bv = bias[m];
      #pragma unroll
      for (int ni = 0; ni < 4; ++ni) {
        const int n = n0 + wn * 64 + ni * 16 + (lane & 15);
        float v = acc[mi][ni][r] + bv;
        if (ADD_RES) v += res[(size_t)b * sCb + (size_t)m * NPIX + n];
        C[(size_t)b * sCb + (size_t)m * NPIX + n] = v;
      }
    }
}

// ================= fi GEMM: 128x128 tile, LDS-staged coalesced bf16 out ======
// H[m][px] = sum_k fiw[m][k]*xnt[px][k] + fib[m].  Grid x=n(128), y=m(8).
__global__ __launch_bounds__(256) void k_fi_gemm(
    const float* __restrict__ A, const ushort* __restrict__ Bt,
    const float* __restrict__ bias, ushort* __restrict__ H)
{
  __shared__ ushort As[128][40];
  __shared__ ushort Bs[128][40];
  __shared__ ushort Cs[64][132];

  const int n0 = blockIdx.x * 128;
  const int m0 = blockIdx.y * 128;
  const int tid = threadIdx.x;
  const int lane = tid & 63;
  const int wave = tid >> 6;
  const int wm = wave >> 1, wn = wave & 1;

  f32x4 acc[4][4];
  #pragma unroll
  for (int i = 0; i < 4; ++i)
    #pragma unroll
    for (int j = 0; j < 4; ++j) acc[i][j] = (f32x4){0.f, 0.f, 0.f, 0.f};

  const int am = tid >> 1, ak = (tid & 1) * 16;

  for (int kk0 = 0; kk0 < CC; kk0 += 32) {
    // A: fiw rows m0+am (128), cols kk0+ak..+16
    {
      const bool mok = (m0 + am) < HID2;
      float v[16];
      #pragma unroll
      for (int t = 0; t < 16; ++t)
        v[t] = mok ? A[(size_t)(m0 + am) * CC + kk0 + ak + t] : 0.f;
      bf16x8 h0, h1;
      #pragma unroll
      for (int t = 0; t < 8; ++t) { h0[t] = (short)f2bf(v[t]); h1[t] = (short)f2bf(v[t + 8]); }
      *reinterpret_cast<bf16x8*>(&As[am][ak])     = h0;
      *reinterpret_cast<bf16x8*>(&As[am][ak + 8]) = h1;
    }
    // B: xnt rows n0+bn (128), 64 B contiguous per 4 lanes
    #pragma unroll
    for (int i = 0; i < 2; ++i) {
      const int u = i * 256 + tid;
      const int bn = u >> 2;
      const int bk = (u & 3) * 8;
      *reinterpret_cast<us8*>(&Bs[bn][bk]) =
          *reinterpret_cast<const us8*>(Bt + (size_t)(n0 + bn) * CC + kk0 + bk);
    }
    __syncthreads();
    bf16x8 af[4], bfg[4];
    #pragma unroll
    for (int mi = 0; mi < 4; ++mi)
      af[mi] = *reinterpret_cast<const bf16x8*>(
          &As[wm * 64 + mi * 16 + (lane & 15)][(lane >> 4) * 8]);
    #pragma unroll
    for (int ni = 0; ni < 4; ++ni)
      bfg[ni] = *reinterpret_cast<const bf16x8*>(
          &Bs[wn * 64 + ni * 16 + (lane & 15)][(lane >> 4) * 8]);
    #pragma unroll
    for (int mi = 0; mi < 4; ++mi)
      #pragma unroll
      for (int ni = 0; ni < 4; ++ni)
        acc[mi][ni] = __builtin_amdgcn_mfma_f32_16x16x32_bf16(
            af[mi], bfg[ni], acc[mi][ni], 0, 0, 0);
    __syncthreads();
  }

  // epilogue: stage 64-row half in LDS, write 16 B/lane coalesced
  #pragma unroll
  for (int half = 0; half < 2; ++half) {
    if (wm == half) {
      #pragma unroll
      for (int mi = 0; mi < 4; ++mi)
        #pragma unroll
        for (int rr = 0; rr < 4; ++rr) {
          const int rloc = mi * 16 + (lane >> 4) * 4 + rr;
          const int m = m0 + half * 64 + rloc;
          const float bv = (m < HID2) ? bias[m] : 0.f;
          #pragma unroll
          for (int ni = 0; ni < 4; ++ni) {
            const int cc = wn * 64 + ni * 16 + (lane & 15);
            Cs[rloc][cc] = f2bf(acc[mi][ni][rr] + bv);
          }
        }
    }
    __syncthreads();
    #pragma unroll
    for (int it = 0; it < 4; ++it) {
      const int r = it * 16 + (tid >> 4);
      const int c8 = (tid & 15) * 8;
      const int m = m0 + half * 64 + r;
      if (m < HID2)
        *reinterpret_cast<us8*>(H + (size_t)m * NPIX + n0 + c8) =
            *reinterpret_cast<const us8*>(&Cs[r][c8]);
    }
    __syncthreads();
  }
}

// ================= attn logits: MFMA 3-pass split-K =================
__global__ __launch_bounds__(256) void k_attn_mfma(
    const ushort* __restrict__ qh, const ushort* __restrict__ ql,
    const ushort* __restrict__ kh, const ushort* __restrict__ kl,
    float* __restrict__ part)
{
  __shared__ ushort As[2][64][40];
  __shared__ ushort Bs[2][64][40];
  const int b = blockIdx.z;
  const int tr = blockIdx.x / 3, tc = blockIdx.x % 3;
  const int r0 = tr * 64, c0 = tc * 64;
  const int k0 = blockIdx.y * (NPIX / KSPLIT);
  const int tid = threadIdx.x;
  const int lane = tid & 63;
  const int wave = tid >> 6;
  const int wm = wave >> 1, wn = wave & 1;

  f32x4 acc[2][2];
  #pragma unroll
  for (int i = 0; i < 2; ++i)
    #pragma unroll
    for (int j = 0; j < 2; ++j) acc[i][j] = (f32x4){0.f, 0.f, 0.f, 0.f};

  const int ar = tid >> 2, ak = (tid & 3) * 8;

  for (int kc = 0; kc < NPIX / KSPLIT; kc += 32) {
    const size_t qo = (size_t)(b * CC + r0 + ar) * NPIX + k0 + kc + ak;
    const size_t ko = (size_t)(b * CC + c0 + ar) * NPIX + k0 + kc + ak;
    *reinterpret_cast<us8*>(&As[0][ar][ak]) = *reinterpret_cast<const us8*>(qh + qo);
    *reinterpret_cast<us8*>(&As[1][ar][ak]) = *reinterpret_cast<const us8*>(ql + qo);
    *reinterpret_cast<us8*>(&Bs[0][ar][ak]) = *reinterpret_cast<const us8*>(kh + ko);
    *reinterpret_cast<us8*>(&Bs[1][ar][ak]) = *reinterpret_cast<const us8*>(kl + ko);
    __syncthreads();
    bf16x8 af[2][2], bfr[2][2];
    #pragma unroll
    for (int mi = 0; mi < 2; ++mi)
      #pragma unroll
      for (int p = 0; p < 2; ++p)
        af[mi][p] = *reinterpret_cast<const bf16x8*>(
            &As[p][wm * 32 + mi * 16 + (lane & 15)][(lane >> 4) * 8]);
    #pragma unroll
    for (int ni = 0; ni < 2; ++ni)
      #pragma unroll
      for (int p = 0; p < 2; ++p)
        bfr[ni][p] = *reinterpret_cast<const bf16x8*>(
            &Bs[p][wn * 32 + ni * 16 + (lane & 15)][(lane >> 4) * 8]);
    #pragma unroll
    for (int mi = 0; mi < 2; ++mi)
      #pragma unroll
      for (int ni = 0; ni < 2; ++ni) {
        acc[mi][ni] = __builtin_amdgcn_mfma_f32_16x16x32_bf16(
            af[mi][0], bfr[ni][0], acc[mi][ni], 0, 0, 0);
        acc[mi][ni] = __builtin_amdgcn_mfma_f32_16x16x32_bf16(
            af[mi][0], bfr[ni][1], acc[mi][ni], 0, 0, 0);
        acc[mi][ni] = __builtin_amdgcn_mfma_f32_16x16x32_bf16(
            af[mi][1], bfr[ni][0], acc[mi][ni], 0, 0, 0);
      }
    __syncthreads();
  }

  float* pp = part + (size_t)(blockIdx.y * BB + b) * CC * CC;
  #pragma unroll
  for (int mi = 0; mi < 2; ++mi)
    #pragma unroll
    for (int r = 0; r < 4; ++r) {
      const int row = r0 + wm * 32 + mi * 16 + (lane >> 4) * 4 + r;
      #pragma unroll
      for (int ni = 0; ni < 2; ++ni) {
        const int col = c0 + wn * 32 + ni * 16 + (lane & 15);
        pp[(size_t)row * CC + col] = acc[mi][ni][r];
      }
    }
}

// ================= depthwise 3x3 =================
__device__ __forceinline__ void dw4(const float* __restrict__ Xc,
                                    const float* __restrict__ wt, float bv,
                                    int h, int w, float out[4])
{
  float a0, a1, a2, a3;
  a0 = a1 = a2 = a3 = bv;
  #pragma unroll
  for (int dy = 0; dy < 3; ++dy) {
    const int hh = h + dy - 1;
    if (hh < 0 || hh >= HHH) continue;
    const float* row = Xc + hh * WWW + w;
    const float xm = (w > 0) ? row[-1] : 0.f;
    const float4 xc = *reinterpret_cast<const float4*>(row);
    const float xp = (w < WWW - 4) ? row[4] : 0.f;
    const float w0 = wt[dy * 3 + 0], w1 = wt[dy * 3 + 1], w2 = wt[dy * 3 + 2];
    a0 += w0 * xm   + w1 * xc.x + w2 * xc.y;
    a1 += w0 * xc.x + w1 * xc.y + w2 * xc.z;
    a2 += w0 * xc.y + w1 * xc.z + w2 * xc.w;
    a3 += w0 * xc.z + w1 * xc.w + w2 * xp;
  }
  out[0] = a0; out[1] = a1; out[2] = a2; out[3] = a3;
}

__global__ __launch_bounds__(256) void k_dw3x3(
    const float* __restrict__ X, const float* __restrict__ W9,
    const float* __restrict__ bias, float* __restrict__ Y)
{
  const int b = blockIdx.z, c = blockIdx.y;
  const int p = blockIdx.x * 1024 + threadIdx.x * 4;
  const int h = p >> 7, w = p & 127;
  float o[4];
  dw4(X + (size_t)(b * CC + c) * NPIX, W9 + c * 9, bias[c], h, w, o);
  *reinterpret_cast<float4*>(Y + (size_t)(b * CC + c) * NPIX + p) =
      make_float4(o[0], o[1], o[2], o[3]);
}

__global__ __launch_bounds__(256) void k_dw3x3_split(
    const float* __restrict__ X, const float* __restrict__ W9,
    const float* __restrict__ bias, ushort* __restrict__ Yh,
    ushort* __restrict__ Yl)
{
  const int b = blockIdx.z, c = blockIdx.y;
  const int p = blockIdx.x * 1024 + threadIdx.x * 4;
  const int h = p >> 7, w = p & 127;
  float o[4];
  dw4(X + (size_t)(b * CC + c) * NPIX, W9 + c * 9, bias[c], h, w, o);
  us4 hi, lo;
  #pragma unroll
  for (int t = 0; t < 4; ++t) {
    const ushort hv = f2bf(o[t]);
    hi.u[t] = hv;
    lo.u[t] = f2bf(o[t] - bf2f(hv));
  }
  const size_t off = (size_t)(b * CC + c) * NPIX + p;
  *reinterpret_cast<us4*>(Yh + off) = hi;
  *reinterpret_cast<us4*>(Yl + off) = lo;
}

// ================= row L2 norms =================
__global__ __launch_bounds__(256) void k_rownorm2(
    const ushort* __restrict__ qh, const ushort* __restrict__ ql,
    const ushort* __restrict__ kh, const ushort* __restrict__ kl,
    float* __restrict__ rq, float* __restrict__ rk)
{
  const int row = blockIdx.x;
  const ushort* H = blockIdx.y ? kh : qh;
  const ushort* L = blockIdx.y ? kl : ql;
  float* R = blockIdx.y ? rk : rq;
  const ushort* Hr = H + (size_t)row * NPIX;
  const ushort* Lr = L + (size_t)row * NPIX;
  float s = 0.f;
  for (int i = threadIdx.x * 8; i < NPIX; i += 2048) {
    const us8 a = *reinterpret_cast<const us8*>(Hr + i);
    const us8 bb = *reinterpret_cast<const us8*>(Lr + i);
    #pragma unroll
    for (int t = 0; t < 8; ++t) {
      const float v = bf2f(a.u[t]) + bf2f(bb.u[t]);
      s += v * v;
    }
  }
  __shared__ float sm[256];
  sm[threadIdx.x] = s; __syncthreads();
  for (int st = 128; st > 0; st >>= 1) {
    if (threadIdx.x < st) sm[threadIdx.x] += sm[threadIdx.x + st];
    __syncthreads();
  }
  if (threadIdx.x == 0) R[row] = 1.f / fmaxf(sqrtf(sm[0]), 1e-12f);
}

// ================= softmax + topk mask =================
__global__ __launch_bounds__(192) void k_softmax_topk(
    const float* __restrict__ part, const float* __restrict__ rq,
    const float* __restrict__ rk, const float* __restrict__ temp,
    float* __restrict__ attnm)
{
  const int c = blockIdx.x, b = blockIdx.y, d = threadIdx.x;
  float s = 0.f;
  for (int ksp = 0; ksp < KSPLIT; ++ksp)
    s += part[(size_t)(ksp * BB + b) * CC * CC + c * CC + d];
  const float logit = s * rq[b * CC + c] * rk[b * CC + d] * temp[0];
  __shared__ float sa[CC], sb[CC];
  sa[d] = logit; __syncthreads();
  float mx = -FLT_MAX;
  for (int j = 0; j < CC; ++j) mx = fmaxf(mx, sa[j]);
  const float e = expf(logit - mx);
  sb[d] = e; __syncthreads();
  float sum = 0.f;
  for (int j = 0; j < CC; ++j) sum += sb[j];
  const float pv = e / sum;
  __syncthreads();
  sa[d] = pv; __syncthreads();
  int greater = 0;
  for (int j = 0; j < CC; ++j) greater += (sa[j] > pv) ? 1 : 0;
  const float cand = (greater < KKEEP) ? pv : FLT_MAX;
  sb[d] = cand; __syncthreads();
  float thr = FLT_MAX;
  for (int j = 0; j < CC; ++j) thr = fminf(thr, sb[j]);
  attnm[(size_t)(b * CC + c) * CC + d] = (pv >= thr) ? pv : 0.f;
}

// ================= M[b] = ow @ attnm[b] =================
__global__ __launch_bounds__(192) void k_mix(
    const float* __restrict__ ow, const float* __restrict__ attnm,
    float* __restrict__ M)
{
  const int c = blockIdx.x, b = blockIdx.y, d = threadIdx.x;
  float acc = 0.f;
  for (int e = 0; e < CC; ++e)
    acc += ow[c * CC + e] * attnm[(size_t)(b * CC + e) * CC + d];
  M[(size_t)(b * CC + c) * CC + d] = acc;
}

// ================= LayerNorm -> transposed bf16 [px][192] =================
__global__ __launch_bounds__(256) void k_ln_t(
    const float* __restrict__ X, const float* __restrict__ lw,
    const float* __restrict__ lb, ushort* __restrict__ Y)
{
  const int b = blockIdx.y;
  const int n = blockIdx.x * 256 + threadIdx.x;
  const float* Xb = X + (size_t)b * CC * NPIX + n;
  float s = 0.f, s2 = 0.f;
  for (int ci = 0; ci < CC; ++ci) {
    const float v = Xb[(size_t)ci * NPIX];
    s += v; s2 += v * v;
  }
  const float mu = s * (1.f / CC);
  const float var = fmaxf(s2 * (1.f / CC) - mu * mu, 0.f);
  const float rstd = rsqrtf(var + 1e-5f);
  ushort* Yb = Y + ((size_t)b * NPIX + n) * CC;
  for (int c8 = 0; c8 < CC / 8; ++c8) {
    bf16x8 sv;
    #pragma unroll
    for (int t = 0; t < 8; ++t) {
      const int c = c8 * 8 + t;
      const float v = Xb[(size_t)c * NPIX];
      sv[t] = (short)f2bf((v - mu) * rstd * lw[c] + lb[c]);
    }
    *reinterpret_cast<bf16x8*>(Yb + c8 * 8) = sv;
  }
}

// ================= fused depthwise 3x3 + GLU, coalesced transposed out ======
__device__ __forceinline__ float gelu_exact(float x) {
  return 0.5f * x * (1.f + erff(x * 0.70710678118654752f));
}

__global__ __launch_bounds__(256) void k_dwglu_t(
    const ushort* __restrict__ Hb, const float* __restrict__ fdw,
    const float* __restrict__ fdb, ushort* __restrict__ gt, int b)
{
  __shared__ ushort hs[64][4][128];
  __shared__ ushort gs[256][32];
  const int tid = threadIdx.x;
  const int h0 = blockIdx.x * 2;
  const int c0 = blockIdx.y * 32;
  const int npairs = min(32, HID - c0);
  #pragma unroll
  for (int i = 0; i < 16; ++i) {
    const int u = i * 256 + tid;
    const int ch = u >> 6;
    const int row = (u >> 4) & 3;
    const int w0 = (u & 15) * 8;
    const int grow = h0 - 1 + row;
    const int cloc = (ch < 32) ? ch : (ch - 32);
    const int gch = (ch < 32) ? (c0 + ch) : (HID + c0 + ch - 32);
    us8 v;
    #pragma unroll
    for (int t = 0; t < 8; ++t) v.u[t] = 0;
    if (c0 + cloc < HID && grow >= 0 && grow < HHH)
      v = *reinterpret_cast<const us8*>(Hb + (size_t)gch * NPIX + grow * WWW + w0);
    *reinterpret_cast<us8*>(&hs[ch][row][w0]) = v;
  }
  __syncthreads();
  const int dh = tid >> 7, w = tid & 127;
  for (int jc = 0; jc < 4; ++jc) {
    bf16x8 sv;
    #pragma unroll
    for (int jj = 0; jj < 8; ++jj) {
      const int j = jc * 8 + jj;
      float val = 0.f;
      if (j < npairs) {
        float x1 = fdb[c0 + j], x2 = fdb[HID + c0 + j];
        const float* w1 = fdw + (size_t)(c0 + j) * 9;
        const float* w2 = fdw + (size_t)(HID + c0 + j) * 9;
        #pragma unroll
        for (int dy = 0; dy < 3; ++dy)
          #pragma unroll
          for (int dx = 0; dx < 3; ++dx) {
            const int ww = w + dx - 1;
            if (ww >= 0 && ww < WWW) {
              x1 += w1[dy * 3 + dx] * bf2f(hs[j][dh + dy][ww]);
              x2 += w2[dy * 3 + dx] * bf2f(hs[32 + j][dh + dy][ww]);
            }
          }
        val = x1 * gelu_exact(x2);
      }
      sv[jj] = (short)f2bf(val);
    }
    *reinterpret_cast<bf16x8*>(&gs[tid][jc * 8]) = sv;
  }
  __syncthreads();
  #pragma unroll
  for (int pp = 0; pp < 4; ++pp) {
    const int px_l = pp * 64 + (tid >> 2);
    const int cseg = (tid & 3) * 8;
    const int px = (h0 + (px_l >> 7)) * WWW + (px_l & 127);
    const us8 v = *reinterpret_cast<const us8*>(&gs[px_l][cseg]);
    *reinterpret_cast<us8*>(gt + ((size_t)b * NPIX + px) * 512 + c0 + cseg) = v;
  }
}

// ================= launch =================
// Workspace (P = 25,165,824; peak 176 MB — same as passing R5):
//  qh [0,P) ql [P,2P) kh [2P,3P) kl [3P,4P)     (dead after attn)
//  vbuf fp32 [4P,6P)                            (dead after Fa gemm)
//  smalls [6P, 6P+10.7M): rq/rk/part/attnm/Mm   (dead after Fa gemm)
//  Fa fp32 [0,2P) ; xnt bf16 [2P,3P)
//  h_b bf16 [3P, 3P+33.4M) ; gt bf16 [3P+33.4M, 3P+100.3M)
//  stage-1 temp = d_out (fully rewritten by final fo gemm)
extern "C" void kernel_launch(void* const* d_in, const int* in_sizes, int n_in,
                              void* d_out, int out_size, void* d_ws, size_t ws_size,
                              hipStream_t stream)
{
  const float* Q    = (const float*)d_in[0];
  const float* Fn   = (const float*)d_in[1];
  const float* temp = (const float*)d_in[2];
  const float* qw1  = (const float*)d_in[3];
  const float* qb1  = (const float*)d_in[4];
  const float* qw2  = (const float*)d_in[5];
  const float* qb2  = (const float*)d_in[6];
  const float* kw1  = (const float*)d_in[7];
  const float* kb1  = (const float*)d_in[8];
  const float* kw2  = (const float*)d_in[9];
  const float* kb2  = (const float*)d_in[10];
  const float* vw1  = (const float*)d_in[11];
  const float* vb1  = (const float*)d_in[12];
  const float* vw2  = (const float*)d_in[13];
  const float* vb2  = (const float*)d_in[14];
  const float* ow   = (const float*)d_in[15];
  const float* ob   = (const float*)d_in[16];
  const float* lnw  = (const float*)d_in[17];
  const float* lnb  = (const float*)d_in[18];
  const float* fiw  = (const float*)d_in[19];
  const float* fib  = (const float*)d_in[20];
  const float* fdw  = (const float*)d_in[21];
  const float* fdb  = (const float*)d_in[22];
  const float* fow  = (const float*)d_in[23];
  const float* fob  = (const float*)d_in[24];
  float* out = (float*)d_out;

  char* ws = (char*)d_ws;
  const size_t P = 25165824UL;
  ushort* qh = (ushort*)(ws + 0 * P);
  ushort* ql = (ushort*)(ws + 1 * P);
  ushort* kh = (ushort*)(ws + 2 * P);
  ushort* kl = (ushort*)(ws + 3 * P);
  float*  vbuf = (float*)(ws + 4 * P);
  char* smb = ws + 6 * P;
  float* rq    = (float*)(smb);
  float* rk    = (float*)(smb + 4096);
  float* part  = (float*)(smb + 8192);
  float* attnm = (float*)(smb + 8192 + 9437184);
  float* Mm    = (float*)(smb + 8192 + 9437184 + 589824);
  float*  Fa  = (float*)(ws + 0 * P);
  ushort* xnt = (ushort*)(ws + 2 * P);
  ushort* h_b = (ushort*)(ws + 3 * P);
  ushort* gt  = (ushort*)(ws + 3 * P + 33423360UL);
  float* bufT = out;

  const long long sX = (long long)CC * NPIX;

  dim3 blk(256);
  dim3 gTN(128, 3, BB);   // x = n (fast), y = m

  // stage-1 1x1 convs via TN-MFMA
  k_gemm_tn<<<gTN, blk, 0, stream>>>(qw1, Q,  qb1, bufT, CC, CC, 0, sX, sX);
  k_dw3x3_split<<<dim3(16, CC, BB), blk, 0, stream>>>(bufT, qw2, qb2, qh, ql);
  k_gemm_tn<<<gTN, blk, 0, stream>>>(kw1, Fn, kb1, bufT, CC, CC, 0, sX, sX);
  k_dw3x3_split<<<dim3(16, CC, BB), blk, 0, stream>>>(bufT, kw2, kb2, kh, kl);
  k_gemm_tn<<<gTN, blk, 0, stream>>>(vw1, Fn, vb1, bufT, CC, CC, 0, sX, sX);
  k_dw3x3<<<dim3(16, CC, BB), blk, 0, stream>>>(bufT, vw2, vb2, vbuf);
  // norms + attention
  k_rownorm2<<<dim3(BB * CC, 2), blk, 0, stream>>>(qh, ql, kh, kl, rq, rk);
  k_attn_mfma<<<dim3(9, KSPLIT, BB), blk, 0, stream>>>(qh, ql, kh, kl, part);
  k_softmax_topk<<<dim3(CC, BB), dim3(192), 0, stream>>>(part, rq, rk, temp, attnm);
  k_mix<<<dim3(CC, BB), dim3(192), 0, stream>>>(ow, attnm, Mm);
  // Fa = Mm @ v + ob
  k_gemm_tn<<<gTN, blk, 0, stream>>>(Mm, vbuf, ob, Fa, CC, CC,
                                     (long long)CC * CC, sX, sX);
  // LN -> xnt
  k_ln_t<<<dim3(64, BB), blk, 0, stream>>>(Fa, lnw, lnb, xnt);
  // FFN per batch: fi (dedicated 128x128 kernel) + dwglu; merged fo
  for (int b = 0; b < BB; ++b) {
    k_fi_gemm<<<dim3(128, 8, 1), blk, 0, stream>>>(
        fiw, xnt + (size_t)b * NPIX * CC, fib, h_b);
    k_dwglu_t<<<dim3(64, 16, 1), blk, 0, stream>>>(h_b, fdw, fdb, gt, b);
  }
  k_ntgemm<true><<<gTN, blk, 0, stream>>>(
      fow, gt, fob, Fa, out, CC, 512, HID, HID, 512,
      (long long)NPIX * 512, sX);
}

// Round 7
// 847.555 us; speedup vs baseline: 2.7863x; 1.1611x over previous
//
#include <hip/hip_runtime.h>
#include <math.h>
#include <float.h>

#define NPIX 16384
#define CC 192
#define BB 4
#define HHH 128
#define WWW 128
#define HID 510
#define HID2 1020
#define KKEEP 172
#define KSPLIT 16

typedef unsigned short ushort;
typedef unsigned int uint32;
using f32x4  = __attribute__((ext_vector_type(4))) float;
using bf16x8 = __attribute__((ext_vector_type(8))) short;

__device__ __forceinline__ float bf2f(ushort u) {
  union { float f; unsigned int i; } x; x.i = ((unsigned int)u) << 16; return x.f;
}
__device__ __forceinline__ ushort f2bf(float f) {
  union { float f; unsigned int i; } x; x.f = f;
  unsigned int r = (x.i + 0x7FFFu + ((x.i >> 16) & 1u)) >> 16;
  return (ushort)r;
}

struct __align__(16) us8 { ushort u[8]; };
struct __align__(8)  us4 { ushort u[4]; };

// ================= weight preconvert: fiw->bf16[1024][192], fow->bf16[192][512]
__global__ __launch_bounds__(256) void k_wconv(
    const float* __restrict__ fiw, const float* __restrict__ fow,
    ushort* __restrict__ fiwb, ushort* __restrict__ fowb)
{
  const int idx = blockIdx.x * 256 + threadIdx.x;
  if (idx < 1024 * 192) {
    const int r = idx / 192, c = idx % 192;
    fiwb[idx] = (r < HID2) ? f2bf(fiw[r * 192 + c]) : (ushort)0;
  }
  const int i2 = idx - 1024 * 192;
  if (i2 >= 0 && i2 < 192 * 512) {
    const int r = i2 / 512, c = i2 % 512;
    fowb[i2] = (c < HID) ? f2bf(fow[r * HID + c]) : (ushort)0;
  }
}

// ================= transpose+split: fp32 [C][NPIX] -> hi/lo bf16 [NPIX][192] ==
// tile 64c x 256px; writes: 8 lanes cover one px's 128 B contiguous.
__global__ __launch_bounds__(256) void k_tsplit(
    const float* __restrict__ X, ushort* __restrict__ Xh, ushort* __restrict__ Xl)
{
  __shared__ float ld[64][261];
  const int b = blockIdx.z;
  const int c0 = blockIdx.y * 64;
  const int px0 = blockIdx.x * 256;
  const int tid = threadIdx.x;
  #pragma unroll
  for (int i = 0; i < 16; ++i) {
    const int u = i * 256 + tid;
    const int r = u >> 6, p4 = (u & 63) * 4;
    const float4 v = *reinterpret_cast<const float4*>(
        X + ((size_t)b * CC + c0 + r) * NPIX + px0 + p4);
    ld[r][p4] = v.x; ld[r][p4 + 1] = v.y; ld[r][p4 + 2] = v.z; ld[r][p4 + 3] = v.w;
  }
  __syncthreads();
  const int c8 = (tid & 7) * 8;
  #pragma unroll
  for (int it = 0; it < 8; ++it) {
    const int pl = it * 32 + (tid >> 3);
    us8 hi, lo;
    #pragma unroll
    for (int j = 0; j < 8; ++j) {
      const float v = ld[c8 + j][pl];
      const ushort h = f2bf(v);
      hi.u[j] = h; lo.u[j] = f2bf(v - bf2f(h));
    }
    const size_t off = ((size_t)b * NPIX + px0 + pl) * CC + c0 + c8;
    *reinterpret_cast<us8*>(Xh + off) = hi;
    *reinterpret_cast<us8*>(Xl + off) = lo;
  }
}

// ================= stage-1 conv GEMM: all-resident NT 3-pass ==================
// C[m][px] = sum_c W[m][c]*X^T[px][c] + bias[m].  64m x 128n, K=192 resident.
__global__ __launch_bounds__(256) void k_nt3res(
    const float* __restrict__ W,
    const ushort* __restrict__ Bh, const ushort* __restrict__ Bl,
    const float* __restrict__ bias, float* __restrict__ C)
{
  __shared__ ushort As[2][64][200];
  __shared__ ushort Bs[2][128][200];
  const int b = blockIdx.z;
  const int n0 = blockIdx.x * 128;
  const int m0 = blockIdx.y * 64;
  const int tid = threadIdx.x;
  const int lane = tid & 63;
  const int wave = tid >> 6;
  const int wm = wave >> 1, wn = wave & 1;
  const ushort* Bhb = Bh + (size_t)b * NPIX * CC;
  const ushort* Blb = Bl + (size_t)b * NPIX * CC;

  // stage A (fp32 -> hi/lo), 12 float4/thread
  #pragma unroll
  for (int i = 0; i < 12; ++i) {
    const int u = i * 256 + tid;
    const int r = u / 48, c = (u % 48) * 4;
    const float4 v = *reinterpret_cast<const float4*>(W + (size_t)(m0 + r) * CC + c);
    const float e[4] = {v.x, v.y, v.z, v.w};
    us4 hi, lo;
    #pragma unroll
    for (int t = 0; t < 4; ++t) {
      const ushort h = f2bf(e[t]);
      hi.u[t] = h; lo.u[t] = f2bf(e[t] - bf2f(h));
    }
    *reinterpret_cast<us4*>(&As[0][r][c]) = hi;
    *reinterpret_cast<us4*>(&As[1][r][c]) = lo;
  }
  // stage B (bf16 planes), 12 us8/thread/plane
  #pragma unroll
  for (int i = 0; i < 12; ++i) {
    const int u = i * 256 + tid;
    const int r = u / 24, c = (u % 24) * 8;
    *reinterpret_cast<us8*>(&Bs[0][r][c]) =
        *reinterpret_cast<const us8*>(Bhb + (size_t)(n0 + r) * CC + c);
    *reinterpret_cast<us8*>(&Bs[1][r][c]) =
        *reinterpret_cast<const us8*>(Blb + (size_t)(n0 + r) * CC + c);
  }
  __syncthreads();

  f32x4 acc[2][4];
  #pragma unroll
  for (int i = 0; i < 2; ++i)
    #pragma unroll
    for (int j = 0; j < 4; ++j) acc[i][j] = (f32x4){0.f, 0.f, 0.f, 0.f};

  #pragma unroll
  for (int kk = 0; kk < 6; ++kk) {
    bf16x8 af[2][2], bfg[4][2];
    #pragma unroll
    for (int mi = 0; mi < 2; ++mi)
      #pragma unroll
      for (int p = 0; p < 2; ++p)
        af[mi][p] = *reinterpret_cast<const bf16x8*>(
            &As[p][wm * 32 + mi * 16 + (lane & 15)][kk * 32 + (lane >> 4) * 8]);
    #pragma unroll
    for (int ni = 0; ni < 4; ++ni)
      #pragma unroll
      for (int p = 0; p < 2; ++p)
        bfg[ni][p] = *reinterpret_cast<const bf16x8*>(
            &Bs[p][wn * 64 + ni * 16 + (lane & 15)][kk * 32 + (lane >> 4) * 8]);
    #pragma unroll
    for (int mi = 0; mi < 2; ++mi)
      #pragma unroll
      for (int ni = 0; ni < 4; ++ni) {
        acc[mi][ni] = __builtin_amdgcn_mfma_f32_16x16x32_bf16(
            af[mi][0], bfg[ni][0], acc[mi][ni], 0, 0, 0);
        acc[mi][ni] = __builtin_amdgcn_mfma_f32_16x16x32_bf16(
            af[mi][0], bfg[ni][1], acc[mi][ni], 0, 0, 0);
        acc[mi][ni] = __builtin_amdgcn_mfma_f32_16x16x32_bf16(
            af[mi][1], bfg[ni][0], acc[mi][ni], 0, 0, 0);
      }
  }

  #pragma unroll
  for (int mi = 0; mi < 2; ++mi)
    #pragma unroll
    for (int r = 0; r < 4; ++r) {
      const int m = m0 + wm * 32 + mi * 16 + (lane >> 4) * 4 + r;
      const float bv = bias[m];
      #pragma unroll
      for (int ni = 0; ni < 4; ++ni) {
        const int n = n0 + wn * 64 + ni * 16 + (lane & 15);
        C[(size_t)b * CC * NPIX + (size_t)m * NPIX + n] = acc[mi][ni][r] + bv;
      }
    }
}

// ================= fi GEMM: A,B fully resident, 1 barrier, bf16 out ==========
// H[m][px] = sum_k fiwb[m][k]*xnt[px][k] + fib[m].  128m x 128n, K=192.
__global__ __launch_bounds__(256) void k_fi(
    const ushort* __restrict__ Aw, const ushort* __restrict__ Bt,
    const float* __restrict__ bias, ushort* __restrict__ H)
{
  __shared__ ushort As[128][200];
  __shared__ ushort Bs[128][200];
  __shared__ ushort Cs[64][132];
  const int z = blockIdx.z;
  const int n0 = blockIdx.x * 128;
  const int m0 = blockIdx.y * 128;
  const int tid = threadIdx.x;
  const int lane = tid & 63;
  const int wave = tid >> 6;
  const int wm = wave >> 1, wn = wave & 1;
  const ushort* Bb = Bt + (size_t)z * NPIX * CC;
  ushort* Hb = H + (size_t)z * 1024 * NPIX;

  #pragma unroll
  for (int i = 0; i < 12; ++i) {
    const int u = i * 256 + tid;
    const int r = u / 24, c = (u % 24) * 8;
    *reinterpret_cast<us8*>(&As[r][c]) =
        *reinterpret_cast<const us8*>(Aw + (size_t)(m0 + r) * CC + c);
    *reinterpret_cast<us8*>(&Bs[r][c]) =
        *reinterpret_cast<const us8*>(Bb + (size_t)(n0 + r) * CC + c);
  }
  __syncthreads();

  f32x4 acc[4][4];
  #pragma unroll
  for (int i = 0; i < 4; ++i)
    #pragma unroll
    for (int j = 0; j < 4; ++j) acc[i][j] = (f32x4){0.f, 0.f, 0.f, 0.f};

  #pragma unroll
  for (int kk = 0; kk < 6; ++kk) {
    bf16x8 af[4], bfg[4];
    #pragma unroll
    for (int mi = 0; mi < 4; ++mi)
      af[mi] = *reinterpret_cast<const bf16x8*>(
          &As[wm * 64 + mi * 16 + (lane & 15)][kk * 32 + (lane >> 4) * 8]);
    #pragma unroll
    for (int ni = 0; ni < 4; ++ni)
      bfg[ni] = *reinterpret_cast<const bf16x8*>(
          &Bs[wn * 64 + ni * 16 + (lane & 15)][kk * 32 + (lane >> 4) * 8]);
    #pragma unroll
    for (int mi = 0; mi < 4; ++mi)
      #pragma unroll
      for (int ni = 0; ni < 4; ++ni)
        acc[mi][ni] = __builtin_amdgcn_mfma_f32_16x16x32_bf16(
            af[mi], bfg[ni], acc[mi][ni], 0, 0, 0);
  }

  // epilogue: stage 64-row half in LDS, write 16 B/lane coalesced
  #pragma unroll
  for (int half = 0; half < 2; ++half) {
    if (wm == half) {
      #pragma unroll
      for (int mi = 0; mi < 4; ++mi)
        #pragma unroll
        for (int rr = 0; rr < 4; ++rr) {
          const int rloc = mi * 16 + (lane >> 4) * 4 + rr;
          const int m = m0 + half * 64 + rloc;
          const float bv = (m < HID2) ? bias[m] : 0.f;
          #pragma unroll
          for (int ni = 0; ni < 4; ++ni) {
            const int cc = wn * 64 + ni * 16 + (lane & 15);
            Cs[rloc][cc] = f2bf(acc[mi][ni][rr] + bv);
          }
        }
    }
    __syncthreads();
    #pragma unroll
    for (int it = 0; it < 4; ++it) {
      const int r = it * 16 + (tid >> 4);
      const int c8 = (tid & 15) * 8;
      const int m = m0 + half * 64 + r;
      *reinterpret_cast<us8*>(Hb + (size_t)m * NPIX + n0 + c8) =
          *reinterpret_cast<const us8*>(&Cs[r][c8]);
    }
    __syncthreads();
  }
}

// ================= fo GEMM: A resident, B double-buffered BK=128 =============
// C[m][px] = sum_k fowb[m][k]*gt[px][k] + fob[m] + res.  64m x 128n, K=512.
__global__ __launch_bounds__(256) void k_fo(
    const ushort* __restrict__ Aw, const ushort* __restrict__ Bt,
    const float* __restrict__ bias, const float* __restrict__ res,
    float* __restrict__ C)
{
  __shared__ ushort As[64][520];
  __shared__ ushort Bs[2][128][136];
  const int z = blockIdx.z;
  const int n0 = blockIdx.x * 128;
  const int m0 = blockIdx.y * 64;
  const int tid = threadIdx.x;
  const int lane = tid & 63;
  const int wave = tid >> 6;
  const int wm = wave >> 1, wn = wave & 1;
  const ushort* Bb = Bt + (size_t)z * NPIX * 512;
  const float* resb = res + (size_t)z * CC * NPIX;
  float* Cb = C + (size_t)z * CC * NPIX;

  // stage A (64x512), 16 us8/thread
  #pragma unroll
  for (int i = 0; i < 16; ++i) {
    const int u = i * 256 + tid;
    const int r = u >> 6, c = (u & 63) * 8;
    *reinterpret_cast<us8*>(&As[r][c]) =
        *reinterpret_cast<const us8*>(Aw + (size_t)(m0 + r) * 512 + c);
  }
  // stage B chunk 0
  #pragma unroll
  for (int i = 0; i < 8; ++i) {
    const int u = i * 256 + tid;
    const int r = u >> 4, c = (u & 15) * 8;
    *reinterpret_cast<us8*>(&Bs[0][r][c]) =
        *reinterpret_cast<const us8*>(Bb + (size_t)(n0 + r) * 512 + c);
  }
  __syncthreads();

  f32x4 acc[2][4];
  #pragma unroll
  for (int i = 0; i < 2; ++i)
    #pragma unroll
    for (int j = 0; j < 4; ++j) acc[i][j] = (f32x4){0.f, 0.f, 0.f, 0.f};

  for (int t = 0; t < 4; ++t) {
    us8 rg[8];
    if (t < 3) {
      #pragma unroll
      for (int i = 0; i < 8; ++i) {
        const int u = i * 256 + tid;
        const int r = u >> 4, c = (u & 15) * 8;
        rg[i] = *reinterpret_cast<const us8*>(
            Bb + (size_t)(n0 + r) * 512 + (t + 1) * 128 + c);
      }
    }
    const int cur = t & 1;
    #pragma unroll
    for (int ks = 0; ks < 4; ++ks) {
      bf16x8 af[2], bfg[4];
      #pragma unroll
      for (int mi = 0; mi < 2; ++mi)
        af[mi] = *reinterpret_cast<const bf16x8*>(
            &As[wm * 32 + mi * 16 + (lane & 15)][t * 128 + ks * 32 + (lane >> 4) * 8]);
      #pragma unroll
      for (int ni = 0; ni < 4; ++ni)
        bfg[ni] = *reinterpret_cast<const bf16x8*>(
            &Bs[cur][wn * 64 + ni * 16 + (lane & 15)][ks * 32 + (lane >> 4) * 8]);
      #pragma unroll
      for (int mi = 0; mi < 2; ++mi)
        #pragma unroll
        for (int ni = 0; ni < 4; ++ni)
          acc[mi][ni] = __builtin_amdgcn_mfma_f32_16x16x32_bf16(
              af[mi], bfg[ni], acc[mi][ni], 0, 0, 0);
    }
    if (t < 3) {
      #pragma unroll
      for (int i = 0; i < 8; ++i) {
        const int u = i * 256 + tid;
        const int r = u >> 4, c = (u & 15) * 8;
        *reinterpret_cast<us8*>(&Bs[cur ^ 1][r][c]) = rg[i];
      }
    }
    __syncthreads();
  }

  #pragma unroll
  for (int mi = 0; mi < 2; ++mi)
    #pragma unroll
    for (int r = 0; r < 4; ++r) {
      const int m = m0 + wm * 32 + mi * 16 + (lane >> 4) * 4 + r;
      const float bv = bias[m];
      #pragma unroll
      for (int ni = 0; ni < 4; ++ni) {
        const int n = n0 + wn * 64 + ni * 16 + (lane & 15);
        Cb[(size_t)m * NPIX + n] = acc[mi][ni][r] + bv + resb[(size_t)m * NPIX + n];
      }
    }
}

// ================= TN-MFMA GEMM (Fa: 3-pass split, B fp32) — R5/R6 verified ==
__global__ __launch_bounds__(256) void k_gemm_tn(
    const float* __restrict__ A, const float* __restrict__ B,
    const float* __restrict__ bias, float* __restrict__ C,
    int K, int lda,
    long long sAb, long long sBb, long long sCb)
{
  __shared__ ushort As[2][64][40];
  __shared__ ushort Bs[2][128][40];

  const int b = blockIdx.z;
  const int m0 = blockIdx.y * 64;
  const int n0 = blockIdx.x * 128;
  const int tid = threadIdx.x;
  const int lane = tid & 63;
  const int wave = tid >> 6;
  const int wm = wave >> 1, wn = wave & 1;

  const float* Ab = A + (size_t)b * sAb;
  const float* Bb = B + (size_t)b * sBb;

  f32x4 acc[2][4];
  #pragma unroll
  for (int i = 0; i < 2; ++i)
    #pragma unroll
    for (int j = 0; j < 4; ++j) acc[i][j] = (f32x4){0.f, 0.f, 0.f, 0.f};

  const int am = tid >> 2, ak = (tid & 3) * 8;

  for (int kk0 = 0; kk0 < K; kk0 += 32) {
    {
      float v[8];
      #pragma unroll
      for (int t = 0; t < 8; ++t)
        v[t] = Ab[(size_t)(m0 + am) * lda + kk0 + ak + t];
      bf16x8 h8, l8;
      #pragma unroll
      for (int t = 0; t < 8; ++t) {
        const ushort h = f2bf(v[t]);
        h8[t] = (short)h;
        l8[t] = (short)f2bf(v[t] - bf2f(h));
      }
      *reinterpret_cast<bf16x8*>(&As[0][am][ak]) = h8;
      *reinterpret_cast<bf16x8*>(&As[1][am][ak]) = l8;
    }
    #pragma unroll
    for (int i = 0; i < 2; ++i) {
      const int u = i * 256 + tid;
      const int krp = u >> 5;
      const int n = (u & 31) * 4;
      const float4 f0 = *reinterpret_cast<const float4*>(
          Bb + (size_t)(kk0 + 2 * krp) * NPIX + n0 + n);
      const float4 f1 = *reinterpret_cast<const float4*>(
          Bb + (size_t)(kk0 + 2 * krp + 1) * NPIX + n0 + n);
      const float e0[4] = {f0.x, f0.y, f0.z, f0.w};
      const float e1[4] = {f1.x, f1.y, f1.z, f1.w};
      #pragma unroll
      for (int j = 0; j < 4; ++j) {
        const ushort h0 = f2bf(e0[j]), h1 = f2bf(e1[j]);
        const ushort l0 = f2bf(e0[j] - bf2f(h0)), l1 = f2bf(e1[j] - bf2f(h1));
        *reinterpret_cast<uint32*>(&Bs[0][n + j][2 * krp]) =
            (uint32)h0 | ((uint32)h1 << 16);
        *reinterpret_cast<uint32*>(&Bs[1][n + j][2 * krp]) =
            (uint32)l0 | ((uint32)l1 << 16);
      }
    }
    __syncthreads();
    bf16x8 af[2][2], bfg[4][2];
    #pragma unroll
    for (int mi = 0; mi < 2; ++mi)
      #pragma unroll
      for (int p = 0; p < 2; ++p)
        af[mi][p] = *reinterpret_cast<const bf16x8*>(
            &As[p][wm * 32 + mi * 16 + (lane & 15)][(lane >> 4) * 8]);
    #pragma unroll
    for (int ni = 0; ni < 4; ++ni)
      #pragma unroll
      for (int p = 0; p < 2; ++p)
        bfg[ni][p] = *reinterpret_cast<const bf16x8*>(
            &Bs[p][wn * 64 + ni * 16 + (lane & 15)][(lane >> 4) * 8]);
    #pragma unroll
    for (int mi = 0; mi < 2; ++mi)
      #pragma unroll
      for (int ni = 0; ni < 4; ++ni) {
        acc[mi][ni] = __builtin_amdgcn_mfma_f32_16x16x32_bf16(
            af[mi][0], bfg[ni][0], acc[mi][ni], 0, 0, 0);
        acc[mi][ni] = __builtin_amdgcn_mfma_f32_16x16x32_bf16(
            af[mi][0], bfg[ni][1], acc[mi][ni], 0, 0, 0);
        acc[mi][ni] = __builtin_amdgcn_mfma_f32_16x16x32_bf16(
            af[mi][1], bfg[ni][0], acc[mi][ni], 0, 0, 0);
      }
    __syncthreads();
  }

  #pragma unroll
  for (int mi = 0; mi < 2; ++mi)
    #pragma unroll
    for (int r = 0; r < 4; ++r) {
      const int m = m0 + wm * 32 + mi * 16 + (lane >> 4) * 4 + r;
      const float bv = bias[m];
      #pragma unroll
      for (int ni = 0; ni < 4; ++ni) {
        const int n = n0 + wn * 64 + ni * 16 + (lane & 15);
        C[(size_t)b * sCb + (size_t)m * NPIX + n] = acc[mi][ni][r] + bv;
      }
    }
}

// ================= attn logits: MFMA 3-pass split-K — verified ===============
__global__ __launch_bounds__(256) void k_attn_mfma(
    const ushort* __restrict__ qh, const ushort* __restrict__ ql,
    const ushort* __restrict__ kh, const ushort* __restrict__ kl,
    float* __restrict__ part)
{
  __shared__ ushort As[2][64][40];
  __shared__ ushort Bs[2][64][40];
  const int b = blockIdx.z;
  const int tr = blockIdx.x / 3, tc = blockIdx.x % 3;
  const int r0 = tr * 64, c0 = tc * 64;
  const int k0 = blockIdx.y * (NPIX / KSPLIT);
  const int tid = threadIdx.x;
  const int lane = tid & 63;
  const int wave = tid >> 6;
  const int wm = wave >> 1, wn = wave & 1;

  f32x4 acc[2][2];
  #pragma unroll
  for (int i = 0; i < 2; ++i)
    #pragma unroll
    for (int j = 0; j < 2; ++j) acc[i][j] = (f32x4){0.f, 0.f, 0.f, 0.f};

  const int ar = tid >> 2, ak = (tid & 3) * 8;

  for (int kc = 0; kc < NPIX / KSPLIT; kc += 32) {
    const size_t qo = (size_t)(b * CC + r0 + ar) * NPIX + k0 + kc + ak;
    const size_t ko = (size_t)(b * CC + c0 + ar) * NPIX + k0 + kc + ak;
    *reinterpret_cast<us8*>(&As[0][ar][ak]) = *reinterpret_cast<const us8*>(qh + qo);
    *reinterpret_cast<us8*>(&As[1][ar][ak]) = *reinterpret_cast<const us8*>(ql + qo);
    *reinterpret_cast<us8*>(&Bs[0][ar][ak]) = *reinterpret_cast<const us8*>(kh + ko);
    *reinterpret_cast<us8*>(&Bs[1][ar][ak]) = *reinterpret_cast<const us8*>(kl + ko);
    __syncthreads();
    bf16x8 af[2][2], bfr[2][2];
    #pragma unroll
    for (int mi = 0; mi < 2; ++mi)
      #pragma unroll
      for (int p = 0; p < 2; ++p)
        af[mi][p] = *reinterpret_cast<const bf16x8*>(
            &As[p][wm * 32 + mi * 16 + (lane & 15)][(lane >> 4) * 8]);
    #pragma unroll
    for (int ni = 0; ni < 2; ++ni)
      #pragma unroll
      for (int p = 0; p < 2; ++p)
        bfr[ni][p] = *reinterpret_cast<const bf16x8*>(
            &Bs[p][wn * 32 + ni * 16 + (lane & 15)][(lane >> 4) * 8]);
    #pragma unroll
    for (int mi = 0; mi < 2; ++mi)
      #pragma unroll
      for (int ni = 0; ni < 2; ++ni) {
        acc[mi][ni] = __builtin_amdgcn_mfma_f32_16x16x32_bf16(
            af[mi][0], bfr[ni][0], acc[mi][ni], 0, 0, 0);
        acc[mi][ni] = __builtin_amdgcn_mfma_f32_16x16x32_bf16(
            af[mi][0], bfr[ni][1], acc[mi][ni], 0, 0, 0);
        acc[mi][ni] = __builtin_amdgcn_mfma_f32_16x16x32_bf16(
            af[mi][1], bfr[ni][0], acc[mi][ni], 0, 0, 0);
      }
    __syncthreads();
  }

  float* pp = part + (size_t)(blockIdx.y * BB + b) * CC * CC;
  #pragma unroll
  for (int mi = 0; mi < 2; ++mi)
    #pragma unroll
    for (int r = 0; r < 4; ++r) {
      const int row = r0 + wm * 32 + mi * 16 + (lane >> 4) * 4 + r;
      #pragma unroll
      for (int ni = 0; ni < 2; ++ni) {
        const int col = c0 + wn * 32 + ni * 16 + (lane & 15);
        pp[(size_t)row * CC + col] = acc[mi][ni][r];
      }
    }
}

// ================= depthwise 3x3 =================
__device__ __forceinline__ void dw4(const float* __restrict__ Xc,
                                    const float* __restrict__ wt, float bv,
                                    int h, int w, float out[4])
{
  float a0, a1, a2, a3;
  a0 = a1 = a2 = a3 = bv;
  #pragma unroll
  for (int dy = 0; dy < 3; ++dy) {
    const int hh = h + dy - 1;
    if (hh < 0 || hh >= HHH) continue;
    const float* row = Xc + hh * WWW + w;
    const float xm = (w > 0) ? row[-1] : 0.f;
    const float4 xc = *reinterpret_cast<const float4*>(row);
    const float xp = (w < WWW - 4) ? row[4] : 0.f;
    const float w0 = wt[dy * 3 + 0], w1 = wt[dy * 3 + 1], w2 = wt[dy * 3 + 2];
    a0 += w0 * xm   + w1 * xc.x + w2 * xc.y;
    a1 += w0 * xc.x + w1 * xc.y + w2 * xc.z;
    a2 += w0 * xc.y + w1 * xc.z + w2 * xc.w;
    a3 += w0 * xc.z + w1 * xc.w + w2 * xp;
  }
  out[0] = a0; out[1] = a1; out[2] = a2; out[3] = a3;
}

__global__ __launch_bounds__(256) void k_dw3x3(
    const float* __restrict__ X, const float* __restrict__ W9,
    const float* __restrict__ bias, float* __restrict__ Y)
{
  const int b = blockIdx.z, c = blockIdx.y;
  const int p = blockIdx.x * 1024 + threadIdx.x * 4;
  const int h = p >> 7, w = p & 127;
  float o[4];
  dw4(X + (size_t)(b * CC + c) * NPIX, W9 + c * 9, bias[c], h, w, o);
  *reinterpret_cast<float4*>(Y + (size_t)(b * CC + c) * NPIX + p) =
      make_float4(o[0], o[1], o[2], o[3]);
}

__global__ __launch_bounds__(256) void k_dw3x3_split(
    const float* __restrict__ X, const float* __restrict__ W9,
    const float* __restrict__ bias, ushort* __restrict__ Yh,
    ushort* __restrict__ Yl)
{
  const int b = blockIdx.z, c = blockIdx.y;
  const int p = blockIdx.x * 1024 + threadIdx.x * 4;
  const int h = p >> 7, w = p & 127;
  float o[4];
  dw4(X + (size_t)(b * CC + c) * NPIX, W9 + c * 9, bias[c], h, w, o);
  us4 hi, lo;
  #pragma unroll
  for (int t = 0; t < 4; ++t) {
    const ushort hv = f2bf(o[t]);
    hi.u[t] = hv;
    lo.u[t] = f2bf(o[t] - bf2f(hv));
  }
  const size_t off = (size_t)(b * CC + c) * NPIX + p;
  *reinterpret_cast<us4*>(Yh + off) = hi;
  *reinterpret_cast<us4*>(Yl + off) = lo;
}

// ================= row L2 norms =================
__global__ __launch_bounds__(256) void k_rownorm2(
    const ushort* __restrict__ qh, const ushort* __restrict__ ql,
    const ushort* __restrict__ kh, const ushort* __restrict__ kl,
    float* __restrict__ rq, float* __restrict__ rk)
{
  const int row = blockIdx.x;
  const ushort* H = blockIdx.y ? kh : qh;
  const ushort* L = blockIdx.y ? kl : ql;
  float* R = blockIdx.y ? rk : rq;
  const ushort* Hr = H + (size_t)row * NPIX;
  const ushort* Lr = L + (size_t)row * NPIX;
  float s = 0.f;
  for (int i = threadIdx.x * 8; i < NPIX; i += 2048) {
    const us8 a = *reinterpret_cast<const us8*>(Hr + i);
    const us8 bb = *reinterpret_cast<const us8*>(Lr + i);
    #pragma unroll
    for (int t = 0; t < 8; ++t) {
      const float v = bf2f(a.u[t]) + bf2f(bb.u[t]);
      s += v * v;
    }
  }
  __shared__ float sm[256];
  sm[threadIdx.x] = s; __syncthreads();
  for (int st = 128; st > 0; st >>= 1) {
    if (threadIdx.x < st) sm[threadIdx.x] += sm[threadIdx.x + st];
    __syncthreads();
  }
  if (threadIdx.x == 0) R[row] = 1.f / fmaxf(sqrtf(sm[0]), 1e-12f);
}

// ================= softmax + topk mask =================
__global__ __launch_bounds__(192) void k_softmax_topk(
    const float* __restrict__ part, const float* __restrict__ rq,
    const float* __restrict__ rk, const float* __restrict__ temp,
    float* __restrict__ attnm)
{
  const int c = blockIdx.x, b = blockIdx.y, d = threadIdx.x;
  float s = 0.f;
  for (int ksp = 0; ksp < KSPLIT; ++ksp)
    s += part[(size_t)(ksp * BB + b) * CC * CC + c * CC + d];
  const float logit = s * rq[b * CC + c] * rk[b * CC + d] * temp[0];
  __shared__ float sa[CC], sb[CC];
  sa[d] = logit; __syncthreads();
  float mx = -FLT_MAX;
  for (int j = 0; j < CC; ++j) mx = fmaxf(mx, sa[j]);
  const float e = expf(logit - mx);
  sb[d] = e; __syncthreads();
  float sum = 0.f;
  for (int j = 0; j < CC; ++j) sum += sb[j];
  const float pv = e / sum;
  __syncthreads();
  sa[d] = pv; __syncthreads();
  int greater = 0;
  for (int j = 0; j < CC; ++j) greater += (sa[j] > pv) ? 1 : 0;
  const float cand = (greater < KKEEP) ? pv : FLT_MAX;
  sb[d] = cand; __syncthreads();
  float thr = FLT_MAX;
  for (int j = 0; j < CC; ++j) thr = fminf(thr, sb[j]);
  attnm[(size_t)(b * CC + c) * CC + d] = (pv >= thr) ? pv : 0.f;
}

// ================= M[b] = ow @ attnm[b] =================
__global__ __launch_bounds__(192) void k_mix(
    const float* __restrict__ ow, const float* __restrict__ attnm,
    float* __restrict__ M)
{
  const int c = blockIdx.x, b = blockIdx.y, d = threadIdx.x;
  float acc = 0.f;
  for (int e = 0; e < CC; ++e)
    acc += ow[c * CC + e] * attnm[(size_t)(b * CC + e) * CC + d];
  M[(size_t)(b * CC + c) * CC + d] = acc;
}

// ================= LayerNorm -> transposed bf16 [px][192] =================
__global__ __launch_bounds__(256) void k_ln_t(
    const float* __restrict__ X, const float* __restrict__ lw,
    const float* __restrict__ lb, ushort* __restrict__ Y)
{
  const int b = blockIdx.y;
  const int n = blockIdx.x * 256 + threadIdx.x;
  const float* Xb = X + (size_t)b * CC * NPIX + n;
  float s = 0.f, s2 = 0.f;
  for (int ci = 0; ci < CC; ++ci) {
    const float v = Xb[(size_t)ci * NPIX];
    s += v; s2 += v * v;
  }
  const float mu = s * (1.f / CC);
  const float var = fmaxf(s2 * (1.f / CC) - mu * mu, 0.f);
  const float rstd = rsqrtf(var + 1e-5f);
  ushort* Yb = Y + ((size_t)b * NPIX + n) * CC;
  for (int c8 = 0; c8 < CC / 8; ++c8) {
    bf16x8 sv;
    #pragma unroll
    for (int t = 0; t < 8; ++t) {
      const int c = c8 * 8 + t;
      const float v = Xb[(size_t)c * NPIX];
      sv[t] = (short)f2bf((v - mu) * rstd * lw[c] + lb[c]);
    }
    *reinterpret_cast<bf16x8*>(Yb + c8 * 8) = sv;
  }
}

// ================= fused depthwise 3x3 + GLU (2-batch grid) =================
__device__ __forceinline__ float gelu_exact(float x) {
  return 0.5f * x * (1.f + erff(x * 0.70710678118654752f));
}

__global__ __launch_bounds__(256) void k_dwglu_t(
    const ushort* __restrict__ Hp, const float* __restrict__ fdw,
    const float* __restrict__ fdb, ushort* __restrict__ gt)
{
  __shared__ ushort hs[64][4][128];
  __shared__ ushort gs[256][32];
  const int z = blockIdx.z;
  const int tid = threadIdx.x;
  const int h0 = blockIdx.x * 2;
  const int c0 = blockIdx.y * 32;
  const int npairs = min(32, HID - c0);
  const ushort* Hb = Hp + (size_t)z * 1024 * NPIX;
  #pragma unroll
  for (int i = 0; i < 16; ++i) {
    const int u = i * 256 + tid;
    const int ch = u >> 6;
    const int row = (u >> 4) & 3;
    const int w0 = (u & 15) * 8;
    const int grow = h0 - 1 + row;
    const int cloc = (ch < 32) ? ch : (ch - 32);
    const int gch = (ch < 32) ? (c0 + ch) : (HID + c0 + ch - 32);
    us8 v;
    #pragma unroll
    for (int t = 0; t < 8; ++t) v.u[t] = 0;
    if (c0 + cloc < HID && grow >= 0 && grow < HHH)
      v = *reinterpret_cast<const us8*>(Hb + (size_t)gch * NPIX + grow * WWW + w0);
    *reinterpret_cast<us8*>(&hs[ch][row][w0]) = v;
  }
  __syncthreads();
  const int dh = tid >> 7, w = tid & 127;
  for (int jc = 0; jc < 4; ++jc) {
    bf16x8 sv;
    #pragma unroll
    for (int jj = 0; jj < 8; ++jj) {
      const int j = jc * 8 + jj;
      float val = 0.f;
      if (j < npairs) {
        float x1 = fdb[c0 + j], x2 = fdb[HID + c0 + j];
        const float* w1 = fdw + (size_t)(c0 + j) * 9;
        const float* w2 = fdw + (size_t)(HID + c0 + j) * 9;
        #pragma unroll
        for (int dy = 0; dy < 3; ++dy)
          #pragma unroll
          for (int dx = 0; dx < 3; ++dx) {
            const int ww = w + dx - 1;
            if (ww >= 0 && ww < WWW) {
              x1 += w1[dy * 3 + dx] * bf2f(hs[j][dh + dy][ww]);
              x2 += w2[dy * 3 + dx] * bf2f(hs[32 + j][dh + dy][ww]);
            }
          }
        val = x1 * gelu_exact(x2);
      }
      sv[jj] = (short)f2bf(val);
    }
    *reinterpret_cast<bf16x8*>(&gs[tid][jc * 8]) = sv;
  }
  __syncthreads();
  #pragma unroll
  for (int pp = 0; pp < 4; ++pp) {
    const int px_l = pp * 64 + (tid >> 2);
    const int cseg = (tid & 3) * 8;
    const int px = (h0 + (px_l >> 7)) * WWW + (px_l & 127);
    const us8 v = *reinterpret_cast<const us8*>(&gs[px_l][cseg]);
    *reinterpret_cast<us8*>(gt + ((size_t)z * NPIX + px) * 512 + c0 + cseg) = v;
  }
}

// ================= launch =================
// Workspace lifetimes (P = 25,165,824; peak 185.1 MB ≤ 201 known-good):
//  Qt [0,2P) -> dead after q stage-1;  Fnt [2P,4P) -> dead after v stage-1
//  qh [4P,5P) ql [5P,6P) -> dead after attn;  kh [0,P) kl [P,2P) -> dead after attn
//  vbuf fp32 [2P,4P) (over Fnt) -> dead after Fa gemm
//  smalls [6P,6P+10.7M) -> dead after Fa gemm
//  Fa [4P,6P) (over qh/ql), live to end;  xnt [0,P) (over kh)
//  h2 [P,P+67.1M) (over kl+vbuf);  gt2 [6P,6P+33.6M) (over smalls)
//  fiwb/fowb [6P+33.6M, +0.6M);  stage-1 temp = d_out
extern "C" void kernel_launch(void* const* d_in, const int* in_sizes, int n_in,
                              void* d_out, int out_size, void* d_ws, size_t ws_size,
                              hipStream_t stream)
{
  const float* Q    = (const float*)d_in[0];
  const float* Fn   = (const float*)d_in[1];
  const float* temp = (const float*)d_in[2];
  const float* qw1  = (const float*)d_in[3];
  const float* qb1  = (const float*)d_in[4];
  const float* qw2  = (const float*)d_in[5];
  const float* qb2  = (const float*)d_in[6];
  const float* kw1  = (const float*)d_in[7];
  const float* kb1  = (const float*)d_in[8];
  const float* kw2  = (const float*)d_in[9];
  const float* kb2  = (const float*)d_in[10];
  const float* vw1  = (const float*)d_in[11];
  const float* vb1  = (const float*)d_in[12];
  const float* vw2  = (const float*)d_in[13];
  const float* vb2  = (const float*)d_in[14];
  const float* ow   = (const float*)d_in[15];
  const float* ob   = (const float*)d_in[16];
  const float* lnw  = (const float*)d_in[17];
  const float* lnb  = (const float*)d_in[18];
  const float* fiw  = (const float*)d_in[19];
  const float* fib  = (const float*)d_in[20];
  const float* fdw  = (const float*)d_in[21];
  const float* fdb  = (const float*)d_in[22];
  const float* fow  = (const float*)d_in[23];
  const float* fob  = (const float*)d_in[24];
  float* out = (float*)d_out;

  char* ws = (char*)d_ws;
  const size_t P = 25165824UL;
  ushort* Qth = (ushort*)(ws + 0 * P);
  ushort* Qtl = (ushort*)(ws + 1 * P);
  ushort* Fth = (ushort*)(ws + 2 * P);
  ushort* Ftl = (ushort*)(ws + 3 * P);
  ushort* qh  = (ushort*)(ws + 4 * P);
  ushort* ql  = (ushort*)(ws + 5 * P);
  ushort* kh  = (ushort*)(ws + 0 * P);
  ushort* kl  = (ushort*)(ws + 1 * P);
  float*  vbuf = (float*)(ws + 2 * P);
  char* smb = ws + 6 * P;
  float* rq    = (float*)(smb);
  float* rk    = (float*)(smb + 4096);
  float* part  = (float*)(smb + 8192);
  float* attnm = (float*)(smb + 8192 + 9437184);
  float* Mm    = (float*)(smb + 8192 + 9437184 + 589824);
  float*  Fa   = (float*)(ws + 4 * P);
  ushort* xnt  = (ushort*)(ws + 0 * P);
  ushort* h2   = (ushort*)(ws + 1 * P);                         // 67,108,864 B
  ushort* gt2  = (ushort*)(ws + 6 * P);                         // 33,554,432 B
  ushort* fiwb = (ushort*)(ws + 6 * P + 33554432UL);            //    393,216 B
  ushort* fowb = (ushort*)(ws + 6 * P + 33554432UL + 393216UL); //    196,608 B
  float* bufT = out;

  const long long sX = (long long)CC * NPIX;
  dim3 blk(256);

  // weight preconvert + input transpose-splits
  k_wconv<<<dim3(1152), blk, 0, stream>>>(fiw, fow, fiwb, fowb);
  k_tsplit<<<dim3(64, 3, BB), blk, 0, stream>>>(Q,  Qth, Qtl);
  k_tsplit<<<dim3(64, 3, BB), blk, 0, stream>>>(Fn, Fth, Ftl);
  // stage-1 1x1 convs (resident NT 3-pass) + depthwise
  k_nt3res<<<dim3(128, 3, BB), blk, 0, stream>>>(qw1, Qth, Qtl, qb1, bufT);
  k_dw3x3_split<<<dim3(16, CC, BB), blk, 0, stream>>>(bufT, qw2, qb2, qh, ql);
  k_nt3res<<<dim3(128, 3, BB), blk, 0, stream>>>(kw1, Fth, Ftl, kb1, bufT);
  k_dw3x3_split<<<dim3(16, CC, BB), blk, 0, stream>>>(bufT, kw2, kb2, kh, kl);
  k_nt3res<<<dim3(128, 3, BB), blk, 0, stream>>>(vw1, Fth, Ftl, vb1, bufT);
  k_dw3x3<<<dim3(16, CC, BB), blk, 0, stream>>>(bufT, vw2, vb2, vbuf);
  // norms + attention
  k_rownorm2<<<dim3(BB * CC, 2), blk, 0, stream>>>(qh, ql, kh, kl, rq, rk);
  k_attn_mfma<<<dim3(9, KSPLIT, BB), blk, 0, stream>>>(qh, ql, kh, kl, part);
  k_softmax_topk<<<dim3(CC, BB), dim3(192), 0, stream>>>(part, rq, rk, temp, attnm);
  k_mix<<<dim3(CC, BB), dim3(192), 0, stream>>>(ow, attnm, Mm);
  // Fa = Mm @ v + ob
  k_gemm_tn<<<dim3(128, 3, BB), blk, 0, stream>>>(Mm, vbuf, ob, Fa, CC, CC,
                                                  (long long)CC * CC, sX, sX);
  // LN -> xnt (all 4 batches)
  k_ln_t<<<dim3(64, BB), blk, 0, stream>>>(Fa, lnw, lnb, xnt);
  // FFN in 2-batch pairs: fi -> dwglu -> fo
  for (int p = 0; p < 2; ++p) {
    const ushort* xn_p = xnt + (size_t)(2 * p) * NPIX * CC;
    const float*  fa_p = Fa + (size_t)(2 * p) * CC * NPIX;
    float* out_p = out + (size_t)(2 * p) * CC * NPIX;
    k_fi<<<dim3(128, 8, 2), blk, 0, stream>>>(fiwb, xn_p, fib, h2);
    k_dwglu_t<<<dim3(64, 16, 2), blk, 0, stream>>>(h2, fdw, fdb, gt2);
    k_fo<<<dim3(128, 3, 2), blk, 0, stream>>>(fowb, gt2, fob, fa_p, out_p);
  }
}

// Round 8
// 713.843 us; speedup vs baseline: 3.3082x; 1.1873x over previous
//
#include <hip/hip_runtime.h>
#include <math.h>
#include <float.h>

#define NPIX 16384
#define CC 192
#define BB 4
#define HHH 128
#define WWW 128
#define HID 510
#define HID2 1020
#define KKEEP 172
#define KSPLIT 16

typedef unsigned short ushort;
typedef unsigned int uint32;
using f32x4  = __attribute__((ext_vector_type(4))) float;
using bf16x8 = __attribute__((ext_vector_type(8))) short;

__device__ __forceinline__ float bf2f(ushort u) {
  union { float f; unsigned int i; } x; x.i = ((unsigned int)u) << 16; return x.f;
}
__device__ __forceinline__ ushort f2bf(float f) {
  union { float f; unsigned int i; } x; x.f = f;
  unsigned int r = (x.i + 0x7FFFu + ((x.i >> 16) & 1u)) >> 16;
  return (ushort)r;
}

struct __align__(16) us8 { ushort u[8]; };
struct __align__(8)  us4 { ushort u[4]; };

// ================= weight preconvert =================
__global__ __launch_bounds__(256) void k_wconv(
    const float* __restrict__ fiw, const float* __restrict__ fow,
    ushort* __restrict__ fiwb, ushort* __restrict__ fowb)
{
  const int idx = blockIdx.x * 256 + threadIdx.x;
  if (idx < 1024 * 192) {
    const int r = idx / 192, c = idx % 192;
    fiwb[idx] = (r < HID2) ? f2bf(fiw[r * 192 + c]) : (ushort)0;
  }
  const int i2 = idx - 1024 * 192;
  if (i2 >= 0 && i2 < 192 * 512) {
    const int r = i2 / 512, c = i2 % 512;
    fowb[i2] = (c < HID) ? f2bf(fow[r * HID + c]) : (ushort)0;
  }
}

// ================= transpose+split: fp32 [C][NPIX] -> hi/lo bf16 [NPIX][192] ==
__global__ __launch_bounds__(256) void k_tsplit(
    const float* __restrict__ X, ushort* __restrict__ Xh, ushort* __restrict__ Xl)
{
  __shared__ float ld[64][261];
  const int b = blockIdx.z;
  const int c0 = blockIdx.y * 64;
  const int px0 = blockIdx.x * 256;
  const int tid = threadIdx.x;
  #pragma unroll
  for (int i = 0; i < 16; ++i) {
    const int u = i * 256 + tid;
    const int r = u >> 6, p4 = (u & 63) * 4;
    const float4 v = *reinterpret_cast<const float4*>(
        X + ((size_t)b * CC + c0 + r) * NPIX + px0 + p4);
    ld[r][p4] = v.x; ld[r][p4 + 1] = v.y; ld[r][p4 + 2] = v.z; ld[r][p4 + 3] = v.w;
  }
  __syncthreads();
  const int c8 = (tid & 7) * 8;
  #pragma unroll
  for (int it = 0; it < 8; ++it) {
    const int pl = it * 32 + (tid >> 3);
    us8 hi, lo;
    #pragma unroll
    for (int j = 0; j < 8; ++j) {
      const float v = ld[c8 + j][pl];
      const ushort h = f2bf(v);
      hi.u[j] = h; lo.u[j] = f2bf(v - bf2f(h));
    }
    const size_t off = ((size_t)b * NPIX + px0 + pl) * CC + c0 + c8;
    *reinterpret_cast<us8*>(Xh + off) = hi;
    *reinterpret_cast<us8*>(Xl + off) = lo;
  }
}

// ================= resident NT 3-pass GEMM (stage-1 convs + Fa) ==============
// C[m][n] = sum_c A[m][c]*B^T[n][c] + bias[m].  64m x 128n, K=192 resident.
__global__ __launch_bounds__(256) void k_nt3res(
    const float* __restrict__ W,
    const ushort* __restrict__ Bh, const ushort* __restrict__ Bl,
    const float* __restrict__ bias, float* __restrict__ C,
    long long sAb)
{
  __shared__ ushort As[2][64][200];
  __shared__ ushort Bs[2][128][200];
  const int b = blockIdx.z;
  const int n0 = blockIdx.x * 128;
  const int m0 = blockIdx.y * 64;
  const int tid = threadIdx.x;
  const int lane = tid & 63;
  const int wave = tid >> 6;
  const int wm = wave >> 1, wn = wave & 1;
  const float*  Wb  = W  + (size_t)b * sAb;
  const ushort* Bhb = Bh + (size_t)b * NPIX * CC;
  const ushort* Blb = Bl + (size_t)b * NPIX * CC;

  #pragma unroll
  for (int i = 0; i < 12; ++i) {
    const int u = i * 256 + tid;
    const int r = u / 48, c = (u % 48) * 4;
    const float4 v = *reinterpret_cast<const float4*>(Wb + (size_t)(m0 + r) * CC + c);
    const float e[4] = {v.x, v.y, v.z, v.w};
    us4 hi, lo;
    #pragma unroll
    for (int t = 0; t < 4; ++t) {
      const ushort h = f2bf(e[t]);
      hi.u[t] = h; lo.u[t] = f2bf(e[t] - bf2f(h));
    }
    *reinterpret_cast<us4*>(&As[0][r][c]) = hi;
    *reinterpret_cast<us4*>(&As[1][r][c]) = lo;
  }
  #pragma unroll
  for (int i = 0; i < 12; ++i) {
    const int u = i * 256 + tid;
    const int r = u / 24, c = (u % 24) * 8;
    *reinterpret_cast<us8*>(&Bs[0][r][c]) =
        *reinterpret_cast<const us8*>(Bhb + (size_t)(n0 + r) * CC + c);
    *reinterpret_cast<us8*>(&Bs[1][r][c]) =
        *reinterpret_cast<const us8*>(Blb + (size_t)(n0 + r) * CC + c);
  }
  __syncthreads();

  f32x4 acc[2][4];
  #pragma unroll
  for (int i = 0; i < 2; ++i)
    #pragma unroll
    for (int j = 0; j < 4; ++j) acc[i][j] = (f32x4){0.f, 0.f, 0.f, 0.f};

  #pragma unroll
  for (int kk = 0; kk < 6; ++kk) {
    bf16x8 af[2][2], bfg[4][2];
    #pragma unroll
    for (int mi = 0; mi < 2; ++mi)
      #pragma unroll
      for (int p = 0; p < 2; ++p)
        af[mi][p] = *reinterpret_cast<const bf16x8*>(
            &As[p][wm * 32 + mi * 16 + (lane & 15)][kk * 32 + (lane >> 4) * 8]);
    #pragma unroll
    for (int ni = 0; ni < 4; ++ni)
      #pragma unroll
      for (int p = 0; p < 2; ++p)
        bfg[ni][p] = *reinterpret_cast<const bf16x8*>(
            &Bs[p][wn * 64 + ni * 16 + (lane & 15)][kk * 32 + (lane >> 4) * 8]);
    #pragma unroll
    for (int mi = 0; mi < 2; ++mi)
      #pragma unroll
      for (int ni = 0; ni < 4; ++ni) {
        acc[mi][ni] = __builtin_amdgcn_mfma_f32_16x16x32_bf16(
            af[mi][0], bfg[ni][0], acc[mi][ni], 0, 0, 0);
        acc[mi][ni] = __builtin_amdgcn_mfma_f32_16x16x32_bf16(
            af[mi][0], bfg[ni][1], acc[mi][ni], 0, 0, 0);
        acc[mi][ni] = __builtin_amdgcn_mfma_f32_16x16x32_bf16(
            af[mi][1], bfg[ni][0], acc[mi][ni], 0, 0, 0);
      }
  }

  #pragma unroll
  for (int mi = 0; mi < 2; ++mi)
    #pragma unroll
    for (int r = 0; r < 4; ++r) {
      const int m = m0 + wm * 32 + mi * 16 + (lane >> 4) * 4 + r;
      const float bv = bias[m];
      #pragma unroll
      for (int ni = 0; ni < 4; ++ni) {
        const int n = n0 + wn * 64 + ni * 16 + (lane & 15);
        C[(size_t)b * CC * NPIX + (size_t)m * NPIX + n] = acc[mi][ni][r] + bv;
      }
    }
}

// ================= fi GEMM: A,B fully resident, 1 barrier, bf16 out ==========
__global__ __launch_bounds__(256) void k_fi(
    const ushort* __restrict__ Aw, const ushort* __restrict__ Bt,
    const float* __restrict__ bias, ushort* __restrict__ H)
{
  __shared__ ushort As[128][200];
  __shared__ ushort Bs[128][200];
  __shared__ ushort Cs[64][132];
  const int z = blockIdx.z;
  const int n0 = blockIdx.x * 128;
  const int m0 = blockIdx.y * 128;
  const int tid = threadIdx.x;
  const int lane = tid & 63;
  const int wave = tid >> 6;
  const int wm = wave >> 1, wn = wave & 1;
  const ushort* Bb = Bt + (size_t)z * NPIX * CC;
  ushort* Hb = H + (size_t)z * 1024 * NPIX;

  #pragma unroll
  for (int i = 0; i < 12; ++i) {
    const int u = i * 256 + tid;
    const int r = u / 24, c = (u % 24) * 8;
    *reinterpret_cast<us8*>(&As[r][c]) =
        *reinterpret_cast<const us8*>(Aw + (size_t)(m0 + r) * CC + c);
    *reinterpret_cast<us8*>(&Bs[r][c]) =
        *reinterpret_cast<const us8*>(Bb + (size_t)(n0 + r) * CC + c);
  }
  __syncthreads();

  f32x4 acc[4][4];
  #pragma unroll
  for (int i = 0; i < 4; ++i)
    #pragma unroll
    for (int j = 0; j < 4; ++j) acc[i][j] = (f32x4){0.f, 0.f, 0.f, 0.f};

  #pragma unroll
  for (int kk = 0; kk < 6; ++kk) {
    bf16x8 af[4], bfg[4];
    #pragma unroll
    for (int mi = 0; mi < 4; ++mi)
      af[mi] = *reinterpret_cast<const bf16x8*>(
          &As[wm * 64 + mi * 16 + (lane & 15)][kk * 32 + (lane >> 4) * 8]);
    #pragma unroll
    for (int ni = 0; ni < 4; ++ni)
      bfg[ni] = *reinterpret_cast<const bf16x8*>(
          &Bs[wn * 64 + ni * 16 + (lane & 15)][kk * 32 + (lane >> 4) * 8]);
    #pragma unroll
    for (int mi = 0; mi < 4; ++mi)
      #pragma unroll
      for (int ni = 0; ni < 4; ++ni)
        acc[mi][ni] = __builtin_amdgcn_mfma_f32_16x16x32_bf16(
            af[mi], bfg[ni], acc[mi][ni], 0, 0, 0);
  }

  #pragma unroll
  for (int half = 0; half < 2; ++half) {
    if (wm == half) {
      #pragma unroll
      for (int mi = 0; mi < 4; ++mi)
        #pragma unroll
        for (int rr = 0; rr < 4; ++rr) {
          const int rloc = mi * 16 + (lane >> 4) * 4 + rr;
          const int m = m0 + half * 64 + rloc;
          const float bv = (m < HID2) ? bias[m] : 0.f;
          #pragma unroll
          for (int ni = 0; ni < 4; ++ni) {
            const int cc = wn * 64 + ni * 16 + (lane & 15);
            Cs[rloc][cc] = f2bf(acc[mi][ni][rr] + bv);
          }
        }
    }
    __syncthreads();
    #pragma unroll
    for (int it = 0; it < 4; ++it) {
      const int r = it * 16 + (tid >> 4);
      const int c8 = (tid & 15) * 8;
      const int m = m0 + half * 64 + r;
      *reinterpret_cast<us8*>(Hb + (size_t)m * NPIX + n0 + c8) =
          *reinterpret_cast<const us8*>(&Cs[r][c8]);
    }
    __syncthreads();
  }
}

// ================= fo GEMM: A resident, B double-buffered BK=128 =============
__global__ __launch_bounds__(256) void k_fo(
    const ushort* __restrict__ Aw, const ushort* __restrict__ Bt,
    const float* __restrict__ bias, const float* __restrict__ res,
    float* __restrict__ C)
{
  __shared__ ushort As[64][520];
  __shared__ ushort Bs[2][128][136];
  const int z = blockIdx.z;
  const int n0 = blockIdx.x * 128;
  const int m0 = blockIdx.y * 64;
  const int tid = threadIdx.x;
  const int lane = tid & 63;
  const int wave = tid >> 6;
  const int wm = wave >> 1, wn = wave & 1;
  const ushort* Bb = Bt + (size_t)z * NPIX * 512;
  const float* resb = res + (size_t)z * CC * NPIX;
  float* Cb = C + (size_t)z * CC * NPIX;

  #pragma unroll
  for (int i = 0; i < 16; ++i) {
    const int u = i * 256 + tid;
    const int r = u >> 6, c = (u & 63) * 8;
    *reinterpret_cast<us8*>(&As[r][c]) =
        *reinterpret_cast<const us8*>(Aw + (size_t)(m0 + r) * 512 + c);
  }
  #pragma unroll
  for (int i = 0; i < 8; ++i) {
    const int u = i * 256 + tid;
    const int r = u >> 4, c = (u & 15) * 8;
    *reinterpret_cast<us8*>(&Bs[0][r][c]) =
        *reinterpret_cast<const us8*>(Bb + (size_t)(n0 + r) * 512 + c);
  }
  __syncthreads();

  f32x4 acc[2][4];
  #pragma unroll
  for (int i = 0; i < 2; ++i)
    #pragma unroll
    for (int j = 0; j < 4; ++j) acc[i][j] = (f32x4){0.f, 0.f, 0.f, 0.f};

  for (int t = 0; t < 4; ++t) {
    us8 rg[8];
    if (t < 3) {
      #pragma unroll
      for (int i = 0; i < 8; ++i) {
        const int u = i * 256 + tid;
        const int r = u >> 4, c = (u & 15) * 8;
        rg[i] = *reinterpret_cast<const us8*>(
            Bb + (size_t)(n0 + r) * 512 + (t + 1) * 128 + c);
      }
    }
    const int cur = t & 1;
    #pragma unroll
    for (int ks = 0; ks < 4; ++ks) {
      bf16x8 af[2], bfg[4];
      #pragma unroll
      for (int mi = 0; mi < 2; ++mi)
        af[mi] = *reinterpret_cast<const bf16x8*>(
            &As[wm * 32 + mi * 16 + (lane & 15)][t * 128 + ks * 32 + (lane >> 4) * 8]);
      #pragma unroll
      for (int ni = 0; ni < 4; ++ni)
        bfg[ni] = *reinterpret_cast<const bf16x8*>(
            &Bs[cur][wn * 64 + ni * 16 + (lane & 15)][ks * 32 + (lane >> 4) * 8]);
      #pragma unroll
      for (int mi = 0; mi < 2; ++mi)
        #pragma unroll
        for (int ni = 0; ni < 4; ++ni)
          acc[mi][ni] = __builtin_amdgcn_mfma_f32_16x16x32_bf16(
              af[mi], bfg[ni], acc[mi][ni], 0, 0, 0);
    }
    if (t < 3) {
      #pragma unroll
      for (int i = 0; i < 8; ++i) {
        const int u = i * 256 + tid;
        const int r = u >> 4, c = (u & 15) * 8;
        *reinterpret_cast<us8*>(&Bs[cur ^ 1][r][c]) = rg[i];
      }
    }
    __syncthreads();
  }

  #pragma unroll
  for (int mi = 0; mi < 2; ++mi)
    #pragma unroll
    for (int r = 0; r < 4; ++r) {
      const int m = m0 + wm * 32 + mi * 16 + (lane >> 4) * 4 + r;
      const float bv = bias[m];
      #pragma unroll
      for (int ni = 0; ni < 4; ++ni) {
        const int n = n0 + wn * 64 + ni * 16 + (lane & 15);
        Cb[(size_t)m * NPIX + n] = acc[mi][ni][r] + bv + resb[(size_t)m * NPIX + n];
      }
    }
}

// ================= attn logits: MFMA 3-pass split-K — verified ===============
__global__ __launch_bounds__(256) void k_attn_mfma(
    const ushort* __restrict__ qh, const ushort* __restrict__ ql,
    const ushort* __restrict__ kh, const ushort* __restrict__ kl,
    float* __restrict__ part)
{
  __shared__ ushort As[2][64][40];
  __shared__ ushort Bs[2][64][40];
  const int b = blockIdx.z;
  const int tr = blockIdx.x / 3, tc = blockIdx.x % 3;
  const int r0 = tr * 64, c0 = tc * 64;
  const int k0 = blockIdx.y * (NPIX / KSPLIT);
  const int tid = threadIdx.x;
  const int lane = tid & 63;
  const int wave = tid >> 6;
  const int wm = wave >> 1, wn = wave & 1;

  f32x4 acc[2][2];
  #pragma unroll
  for (int i = 0; i < 2; ++i)
    #pragma unroll
    for (int j = 0; j < 2; ++j) acc[i][j] = (f32x4){0.f, 0.f, 0.f, 0.f};

  const int ar = tid >> 2, ak = (tid & 3) * 8;

  for (int kc = 0; kc < NPIX / KSPLIT; kc += 32) {
    const size_t qo = (size_t)(b * CC + r0 + ar) * NPIX + k0 + kc + ak;
    const size_t ko = (size_t)(b * CC + c0 + ar) * NPIX + k0 + kc + ak;
    *reinterpret_cast<us8*>(&As[0][ar][ak]) = *reinterpret_cast<const us8*>(qh + qo);
    *reinterpret_cast<us8*>(&As[1][ar][ak]) = *reinterpret_cast<const us8*>(ql + qo);
    *reinterpret_cast<us8*>(&Bs[0][ar][ak]) = *reinterpret_cast<const us8*>(kh + ko);
    *reinterpret_cast<us8*>(&Bs[1][ar][ak]) = *reinterpret_cast<const us8*>(kl + ko);
    __syncthreads();
    bf16x8 af[2][2], bfr[2][2];
    #pragma unroll
    for (int mi = 0; mi < 2; ++mi)
      #pragma unroll
      for (int p = 0; p < 2; ++p)
        af[mi][p] = *reinterpret_cast<const bf16x8*>(
            &As[p][wm * 32 + mi * 16 + (lane & 15)][(lane >> 4) * 8]);
    #pragma unroll
    for (int ni = 0; ni < 2; ++ni)
      #pragma unroll
      for (int p = 0; p < 2; ++p)
        bfr[ni][p] = *reinterpret_cast<const bf16x8*>(
            &Bs[p][wn * 32 + ni * 16 + (lane & 15)][(lane >> 4) * 8]);
    #pragma unroll
    for (int mi = 0; mi < 2; ++mi)
      #pragma unroll
      for (int ni = 0; ni < 2; ++ni) {
        acc[mi][ni] = __builtin_amdgcn_mfma_f32_16x16x32_bf16(
            af[mi][0], bfr[ni][0], acc[mi][ni], 0, 0, 0);
        acc[mi][ni] = __builtin_amdgcn_mfma_f32_16x16x32_bf16(
            af[mi][0], bfr[ni][1], acc[mi][ni], 0, 0, 0);
        acc[mi][ni] = __builtin_amdgcn_mfma_f32_16x16x32_bf16(
            af[mi][1], bfr[ni][0], acc[mi][ni], 0, 0, 0);
      }
    __syncthreads();
  }

  float* pp = part + (size_t)(blockIdx.y * BB + b) * CC * CC;
  #pragma unroll
  for (int mi = 0; mi < 2; ++mi)
    #pragma unroll
    for (int r = 0; r < 4; ++r) {
      const int row = r0 + wm * 32 + mi * 16 + (lane >> 4) * 4 + r;
      #pragma unroll
      for (int ni = 0; ni < 2; ++ni) {
        const int col = c0 + wn * 32 + ni * 16 + (lane & 15);
        pp[(size_t)row * CC + col] = acc[mi][ni][r];
      }
    }
}

// ================= depthwise 3x3 (fp32, stage-1) =================
__device__ __forceinline__ void dw4(const float* __restrict__ Xc,
                                    const float* __restrict__ wt, float bv,
                                    int h, int w, float out[4])
{
  float a0, a1, a2, a3;
  a0 = a1 = a2 = a3 = bv;
  #pragma unroll
  for (int dy = 0; dy < 3; ++dy) {
    const int hh = h + dy - 1;
    if (hh < 0 || hh >= HHH) continue;
    const float* row = Xc + hh * WWW + w;
    const float xm = (w > 0) ? row[-1] : 0.f;
    const float4 xc = *reinterpret_cast<const float4*>(row);
    const float xp = (w < WWW - 4) ? row[4] : 0.f;
    const float w0 = wt[dy * 3 + 0], w1 = wt[dy * 3 + 1], w2 = wt[dy * 3 + 2];
    a0 += w0 * xm   + w1 * xc.x + w2 * xc.y;
    a1 += w0 * xc.x + w1 * xc.y + w2 * xc.z;
    a2 += w0 * xc.y + w1 * xc.z + w2 * xc.w;
    a3 += w0 * xc.z + w1 * xc.w + w2 * xp;
  }
  out[0] = a0; out[1] = a1; out[2] = a2; out[3] = a3;
}

__global__ __launch_bounds__(256) void k_dw3x3(
    const float* __restrict__ X, const float* __restrict__ W9,
    const float* __restrict__ bias, float* __restrict__ Y)
{
  const int b = blockIdx.z, c = blockIdx.y;
  const int p = blockIdx.x * 1024 + threadIdx.x * 4;
  const int h = p >> 7, w = p & 127;
  float o[4];
  dw4(X + (size_t)(b * CC + c) * NPIX, W9 + c * 9, bias[c], h, w, o);
  *reinterpret_cast<float4*>(Y + (size_t)(b * CC + c) * NPIX + p) =
      make_float4(o[0], o[1], o[2], o[3]);
}

__global__ __launch_bounds__(256) void k_dw3x3_split(
    const float* __restrict__ X, const float* __restrict__ W9,
    const float* __restrict__ bias, ushort* __restrict__ Yh,
    ushort* __restrict__ Yl)
{
  const int b = blockIdx.z, c = blockIdx.y;
  const int p = blockIdx.x * 1024 + threadIdx.x * 4;
  const int h = p >> 7, w = p & 127;
  float o[4];
  dw4(X + (size_t)(b * CC + c) * NPIX, W9 + c * 9, bias[c], h, w, o);
  us4 hi, lo;
  #pragma unroll
  for (int t = 0; t < 4; ++t) {
    const ushort hv = f2bf(o[t]);
    hi.u[t] = hv;
    lo.u[t] = f2bf(o[t] - bf2f(hv));
  }
  const size_t off = (size_t)(b * CC + c) * NPIX + p;
  *reinterpret_cast<us4*>(Yh + off) = hi;
  *reinterpret_cast<us4*>(Yl + off) = lo;
}

// ================= row L2 norms =================
__global__ __launch_bounds__(256) void k_rownorm2(
    const ushort* __restrict__ qh, const ushort* __restrict__ ql,
    const ushort* __restrict__ kh, const ushort* __restrict__ kl,
    float* __restrict__ rq, float* __restrict__ rk)
{
  const int row = blockIdx.x;
  const ushort* H = blockIdx.y ? kh : qh;
  const ushort* L = blockIdx.y ? kl : ql;
  float* R = blockIdx.y ? rk : rq;
  const ushort* Hr = H + (size_t)row * NPIX;
  const ushort* Lr = L + (size_t)row * NPIX;
  float s = 0.f;
  for (int i = threadIdx.x * 8; i < NPIX; i += 2048) {
    const us8 a = *reinterpret_cast<const us8*>(Hr + i);
    const us8 bb = *reinterpret_cast<const us8*>(Lr + i);
    #pragma unroll
    for (int t = 0; t < 8; ++t) {
      const float v = bf2f(a.u[t]) + bf2f(bb.u[t]);
      s += v * v;
    }
  }
  __shared__ float sm[256];
  sm[threadIdx.x] = s; __syncthreads();
  for (int st = 128; st > 0; st >>= 1) {
    if (threadIdx.x < st) sm[threadIdx.x] += sm[threadIdx.x + st];
    __syncthreads();
  }
  if (threadIdx.x == 0) R[row] = 1.f / fmaxf(sqrtf(sm[0]), 1e-12f);
}

// ================= softmax + topk mask =================
__global__ __launch_bounds__(192) void k_softmax_topk(
    const float* __restrict__ part, const float* __restrict__ rq,
    const float* __restrict__ rk, const float* __restrict__ temp,
    float* __restrict__ attnm)
{
  const int c = blockIdx.x, b = blockIdx.y, d = threadIdx.x;
  float s = 0.f;
  for (int ksp = 0; ksp < KSPLIT; ++ksp)
    s += part[(size_t)(ksp * BB + b) * CC * CC + c * CC + d];
  const float logit = s * rq[b * CC + c] * rk[b * CC + d] * temp[0];
  __shared__ float sa[CC], sb[CC];
  sa[d] = logit; __syncthreads();
  float mx = -FLT_MAX;
  for (int j = 0; j < CC; ++j) mx = fmaxf(mx, sa[j]);
  const float e = expf(logit - mx);
  sb[d] = e; __syncthreads();
  float sum = 0.f;
  for (int j = 0; j < CC; ++j) sum += sb[j];
  const float pv = e / sum;
  __syncthreads();
  sa[d] = pv; __syncthreads();
  int greater = 0;
  for (int j = 0; j < CC; ++j) greater += (sa[j] > pv) ? 1 : 0;
  const float cand = (greater < KKEEP) ? pv : FLT_MAX;
  sb[d] = cand; __syncthreads();
  float thr = FLT_MAX;
  for (int j = 0; j < CC; ++j) thr = fminf(thr, sb[j]);
  attnm[(size_t)(b * CC + c) * CC + d] = (pv >= thr) ? pv : 0.f;
}

// ================= M[b] = ow @ attnm[b] =================
__global__ __launch_bounds__(192) void k_mix(
    const float* __restrict__ ow, const float* __restrict__ attnm,
    float* __restrict__ M)
{
  const int c = blockIdx.x, b = blockIdx.y, d = threadIdx.x;
  float acc = 0.f;
  for (int e = 0; e < CC; ++e)
    acc += ow[c * CC + e] * attnm[(size_t)(b * CC + e) * CC + d];
  M[(size_t)(b * CC + c) * CC + d] = acc;
}

// ================= LayerNorm -> transposed bf16 [px][192] =================
__global__ __launch_bounds__(256) void k_ln_t(
    const float* __restrict__ X, const float* __restrict__ lw,
    const float* __restrict__ lb, ushort* __restrict__ Y)
{
  const int b = blockIdx.y;
  const int n = blockIdx.x * 256 + threadIdx.x;
  const float* Xb = X + (size_t)b * CC * NPIX + n;
  float s = 0.f, s2 = 0.f;
  for (int ci = 0; ci < CC; ++ci) {
    const float v = Xb[(size_t)ci * NPIX];
    s += v; s2 += v * v;
  }
  const float mu = s * (1.f / CC);
  const float var = fmaxf(s2 * (1.f / CC) - mu * mu, 0.f);
  const float rstd = rsqrtf(var + 1e-5f);
  ushort* Yb = Y + ((size_t)b * NPIX + n) * CC;
  for (int c8 = 0; c8 < CC / 8; ++c8) {
    bf16x8 sv;
    #pragma unroll
    for (int t = 0; t < 8; ++t) {
      const int c = c8 * 8 + t;
      const float v = Xb[(size_t)c * NPIX];
      sv[t] = (short)f2bf((v - mu) * rstd * lw[c] + lb[c]);
    }
    *reinterpret_cast<bf16x8*>(Yb + c8 * 8) = sv;
  }
}

// ================= fused depthwise 3x3 + GLU v3 ==============================
// Small tiles: 8 pairs x 256 px; hs 16 KB (halo zero-staged); register convs;
// gs stride-129-dword layout -> conflict-free column read-out.
// Grid: x = c-block (64, FAST: L2-merges 16B/px gt sectors), y = h-block (64), z = 2.
__device__ __forceinline__ float gelu_exact(float x) {
  return 0.5f * x * (1.f + erff(x * 0.70710678118654752f));
}

__global__ __launch_bounds__(256) void k_dwglu3(
    const ushort* __restrict__ Hp, const float* __restrict__ fdw,
    const float* __restrict__ fdb, ushort* __restrict__ gt)
{
  __shared__ ushort hs[16][4][128];
  __shared__ uint32 gsd[8 * 129];
  const int z = blockIdx.z;
  const int c0 = blockIdx.x * 8;
  const int h0 = blockIdx.y * 2;
  const int tid = threadIdx.x;
  const int npairs = min(8, HID - c0);
  const ushort* Hb = Hp + (size_t)z * 1024 * NPIX;

  // stage 16 channels x 4 rows (halo zero-filled) x 128 w
  #pragma unroll
  for (int i = 0; i < 4; ++i) {
    const int u = i * 256 + tid;
    const int ch = u >> 6;
    const int row = (u >> 4) & 3;
    const int w0 = (u & 15) * 8;
    const int grow = h0 - 1 + row;
    const int cloc = ch & 7;
    const int gch = (ch < 8) ? (c0 + cloc) : (HID + c0 + cloc);
    us8 v;
    #pragma unroll
    for (int t = 0; t < 8; ++t) v.u[t] = 0;
    if (c0 + cloc < HID && grow >= 0 && grow < HHH)
      v = *reinterpret_cast<const us8*>(Hb + (size_t)gch * NPIX + grow * WWW + w0);
    *reinterpret_cast<us8*>(&hs[ch][row][w0]) = v;
  }
  __syncthreads();

  const int q = tid & 63;
  const int jp = tid >> 6;
  const int px_l = q * 4;
  const int dh = px_l >> 7;
  const int w = px_l & 127;

  #pragma unroll
  for (int jj = 0; jj < 2; ++jj) {
    const int j = jp * 2 + jj;         // wave-uniform
    uint32 p0 = 0, p1 = 0;
    if (j < npairs) {
      const float* w1 = fdw + (size_t)(c0 + j) * 9;
      const float* w2 = fdw + (size_t)(HID + c0 + j) * 9;
      float x1[4], x2[4];
      const float b1 = fdb[c0 + j], b2 = fdb[HID + c0 + j];
      #pragma unroll
      for (int i = 0; i < 4; ++i) { x1[i] = b1; x2[i] = b2; }
      #pragma unroll
      for (int dy = 0; dy < 3; ++dy) {
        const int row = dh + dy;
        const ushort* r1 = &hs[j][row][0];
        const ushort* r2 = &hs[8 + j][row][0];
        const float am1 = (w > 0) ? bf2f(r1[w - 1]) : 0.f;
        const float am2 = (w > 0) ? bf2f(r2[w - 1]) : 0.f;
        const us4 c1 = *reinterpret_cast<const us4*>(&r1[w]);
        const us4 c2 = *reinterpret_cast<const us4*>(&r2[w]);
        const float ap1 = (w < 124) ? bf2f(r1[w + 4]) : 0.f;
        const float ap2 = (w < 124) ? bf2f(r2[w + 4]) : 0.f;
        const float e10 = bf2f(c1.u[0]), e11 = bf2f(c1.u[1]);
        const float e12 = bf2f(c1.u[2]), e13 = bf2f(c1.u[3]);
        const float e20 = bf2f(c2.u[0]), e21 = bf2f(c2.u[1]);
        const float e22 = bf2f(c2.u[2]), e23 = bf2f(c2.u[3]);
        const float wa0 = w1[dy * 3 + 0], wa1 = w1[dy * 3 + 1], wa2 = w1[dy * 3 + 2];
        const float wb0 = w2[dy * 3 + 0], wb1 = w2[dy * 3 + 1], wb2 = w2[dy * 3 + 2];
        x1[0] += wa0 * am1 + wa1 * e10 + wa2 * e11;
        x1[1] += wa0 * e10 + wa1 * e11 + wa2 * e12;
        x1[2] += wa0 * e11 + wa1 * e12 + wa2 * e13;
        x1[3] += wa0 * e12 + wa1 * e13 + wa2 * ap1;
        x2[0] += wb0 * am2 + wb1 * e20 + wb2 * e21;
        x2[1] += wb0 * e20 + wb1 * e21 + wb2 * e22;
        x2[2] += wb0 * e21 + wb1 * e22 + wb2 * e23;
        x2[3] += wb0 * e22 + wb1 * e23 + wb2 * ap2;
      }
      const ushort v0 = f2bf(x1[0] * gelu_exact(x2[0]));
      const ushort v1 = f2bf(x1[1] * gelu_exact(x2[1]));
      const ushort v2 = f2bf(x1[2] * gelu_exact(x2[2]));
      const ushort v3 = f2bf(x1[3] * gelu_exact(x2[3]));
      p0 = (uint32)v0 | ((uint32)v1 << 16);
      p1 = (uint32)v2 | ((uint32)v3 << 16);
    }
    gsd[j * 129 + (px_l >> 1)] = p0;
    gsd[j * 129 + (px_l >> 1) + 1] = p1;
  }
  __syncthreads();

  // write-out: one us8 (8 channels) per pixel per thread, conflict-free column reads
  const ushort* gsu = (const ushort*)gsd;
  const int px_l2 = tid;
  const int px = (h0 + (px_l2 >> 7)) * WWW + (px_l2 & 127);
  us8 v;
  #pragma unroll
  for (int t = 0; t < 8; ++t) v.u[t] = gsu[t * 258 + px_l2];
  *reinterpret_cast<us8*>(gt + ((size_t)z * NPIX + px) * 512 + c0) = v;
}

// ================= launch =================
// Workspace lifetimes (P = 25,165,824; peak 185.1 MB — same as passing R7):
//  Qt [0,2P) -> dead after q stage-1;  Fnt [2P,4P) -> dead after v stage-1
//  qh [4P,5P) ql [5P,6P) -> dead after attn;  kh [0,P) kl [P,2P) -> dead after attn
//  vbuf fp32 [2P,4P) -> dead after v-tsplit;  vth [0,P) vtl [P,2P) (over kh/kl)
//  smalls [6P,6P+10.7M) -> dead after Fa gemm
//  Fa [4P,6P) (over qh/ql), live to end;  xnt [0,P) (over vth, dead after Fa gemm)
//  h2 [P,P+67.1M) (over vtl+vbuf);  gt2 [6P,6P+33.6M);  fiwb/fowb after gt2
extern "C" void kernel_launch(void* const* d_in, const int* in_sizes, int n_in,
                              void* d_out, int out_size, void* d_ws, size_t ws_size,
                              hipStream_t stream)
{
  const float* Q    = (const float*)d_in[0];
  const float* Fn   = (const float*)d_in[1];
  const float* temp = (const float*)d_in[2];
  const float* qw1  = (const float*)d_in[3];
  const float* qb1  = (const float*)d_in[4];
  const float* qw2  = (const float*)d_in[5];
  const float* qb2  = (const float*)d_in[6];
  const float* kw1  = (const float*)d_in[7];
  const float* kb1  = (const float*)d_in[8];
  const float* kw2  = (const float*)d_in[9];
  const float* kb2  = (const float*)d_in[10];
  const float* vw1  = (const float*)d_in[11];
  const float* vb1  = (const float*)d_in[12];
  const float* vw2  = (const float*)d_in[13];
  const float* vb2  = (const float*)d_in[14];
  const float* ow   = (const float*)d_in[15];
  const float* ob   = (const float*)d_in[16];
  const float* lnw  = (const float*)d_in[17];
  const float* lnb  = (const float*)d_in[18];
  const float* fiw  = (const float*)d_in[19];
  const float* fib  = (const float*)d_in[20];
  const float* fdw  = (const float*)d_in[21];
  const float* fdb  = (const float*)d_in[22];
  const float* fow  = (const float*)d_in[23];
  const float* fob  = (const float*)d_in[24];
  float* out = (float*)d_out;

  char* ws = (char*)d_ws;
  const size_t P = 25165824UL;
  ushort* Qth = (ushort*)(ws + 0 * P);
  ushort* Qtl = (ushort*)(ws + 1 * P);
  ushort* Fth = (ushort*)(ws + 2 * P);
  ushort* Ftl = (ushort*)(ws + 3 * P);
  ushort* qh  = (ushort*)(ws + 4 * P);
  ushort* ql  = (ushort*)(ws + 5 * P);
  ushort* kh  = (ushort*)(ws + 0 * P);
  ushort* kl  = (ushort*)(ws + 1 * P);
  float*  vbuf = (float*)(ws + 2 * P);
  ushort* vth = (ushort*)(ws + 0 * P);
  ushort* vtl = (ushort*)(ws + 1 * P);
  char* smb = ws + 6 * P;
  float* rq    = (float*)(smb);
  float* rk    = (float*)(smb + 4096);
  float* part  = (float*)(smb + 8192);
  float* attnm = (float*)(smb + 8192 + 9437184);
  float* Mm    = (float*)(smb + 8192 + 9437184 + 589824);
  float*  Fa   = (float*)(ws + 4 * P);
  ushort* xnt  = (ushort*)(ws + 0 * P);
  ushort* h2   = (ushort*)(ws + 1 * P);
  ushort* gt2  = (ushort*)(ws + 6 * P);
  ushort* fiwb = (ushort*)(ws + 6 * P + 33554432UL);
  ushort* fowb = (ushort*)(ws + 6 * P + 33554432UL + 393216UL);
  float* bufT = out;

  dim3 blk(256);

  // weight preconvert + input transpose-splits
  k_wconv<<<dim3(1152), blk, 0, stream>>>(fiw, fow, fiwb, fowb);
  k_tsplit<<<dim3(64, 3, BB), blk, 0, stream>>>(Q,  Qth, Qtl);
  k_tsplit<<<dim3(64, 3, BB), blk, 0, stream>>>(Fn, Fth, Ftl);
  // stage-1 1x1 convs (resident NT 3-pass) + depthwise
  k_nt3res<<<dim3(128, 3, BB), blk, 0, stream>>>(qw1, Qth, Qtl, qb1, bufT, 0);
  k_dw3x3_split<<<dim3(16, CC, BB), blk, 0, stream>>>(bufT, qw2, qb2, qh, ql);
  k_nt3res<<<dim3(128, 3, BB), blk, 0, stream>>>(kw1, Fth, Ftl, kb1, bufT, 0);
  k_dw3x3_split<<<dim3(16, CC, BB), blk, 0, stream>>>(bufT, kw2, kb2, kh, kl);
  k_nt3res<<<dim3(128, 3, BB), blk, 0, stream>>>(vw1, Fth, Ftl, vb1, bufT, 0);
  k_dw3x3<<<dim3(16, CC, BB), blk, 0, stream>>>(bufT, vw2, vb2, vbuf);
  // norms + attention
  k_rownorm2<<<dim3(BB * CC, 2), blk, 0, stream>>>(qh, ql, kh, kl, rq, rk);
  k_attn_mfma<<<dim3(9, KSPLIT, BB), blk, 0, stream>>>(qh, ql, kh, kl, part);
  k_softmax_topk<<<dim3(CC, BB), dim3(192), 0, stream>>>(part, rq, rk, temp, attnm);
  k_mix<<<dim3(CC, BB), dim3(192), 0, stream>>>(ow, attnm, Mm);
  // v -> transposed hi/lo planes (over dead kh/kl), then resident Fa gemm
  k_tsplit<<<dim3(64, 3, BB), blk, 0, stream>>>(vbuf, vth, vtl);
  k_nt3res<<<dim3(128, 3, BB), blk, 0, stream>>>(Mm, vth, vtl, ob, Fa,
                                                 (long long)CC * CC);
  // LN -> xnt
  k_ln_t<<<dim3(64, BB), blk, 0, stream>>>(Fa, lnw, lnb, xnt);
  // FFN in 2-batch pairs: fi -> dwglu -> fo
  for (int p = 0; p < 2; ++p) {
    const ushort* xn_p = xnt + (size_t)(2 * p) * NPIX * CC;
    const float*  fa_p = Fa + (size_t)(2 * p) * CC * NPIX;
    float* out_p = out + (size_t)(2 * p) * CC * NPIX;
    k_fi<<<dim3(128, 8, 2), blk, 0, stream>>>(fiwb, xn_p, fib, h2);
    k_dwglu3<<<dim3(64, 64, 2), blk, 0, stream>>>(h2, fdw, fdb, gt2);
    k_fo<<<dim3(128, 3, 2), blk, 0, stream>>>(fowb, gt2, fob, fa_p, out_p);
  }
}

// Round 9
// 652.411 us; speedup vs baseline: 3.6198x; 1.0942x over previous
//
#include <hip/hip_runtime.h>
#include <math.h>
#include <float.h>

#define NPIX 16384
#define CC 192
#define BB 4
#define HHH 128
#define WWW 128
#define HID 510
#define HID2 1020
#define KKEEP 172
#define KSPLIT 16

typedef unsigned short ushort;
typedef unsigned int uint32;
using f32x4  = __attribute__((ext_vector_type(4))) float;
using bf16x8 = __attribute__((ext_vector_type(8))) short;

__device__ __forceinline__ float bf2f(ushort u) {
  union { float f; unsigned int i; } x; x.i = ((unsigned int)u) << 16; return x.f;
}
__device__ __forceinline__ ushort f2bf(float f) {
  union { float f; unsigned int i; } x; x.f = f;
  unsigned int r = (x.i + 0x7FFFu + ((x.i >> 16) & 1u)) >> 16;
  return (ushort)r;
}

struct __align__(16) us8 { ushort u[8]; };
struct __align__(8)  us4 { ushort u[4]; };

// ================= weight preconvert =================
__global__ __launch_bounds__(256) void k_wconv(
    const float* __restrict__ fiw, const float* __restrict__ fow,
    ushort* __restrict__ fiwb, ushort* __restrict__ fowb)
{
  const int idx = blockIdx.x * 256 + threadIdx.x;
  if (idx < 1024 * 192) {
    const int r = idx / 192, c = idx % 192;
    fiwb[idx] = (r < HID2) ? f2bf(fiw[r * 192 + c]) : (ushort)0;
  }
  const int i2 = idx - 1024 * 192;
  if (i2 >= 0 && i2 < 192 * 512) {
    const int r = i2 / 512, c = i2 % 512;
    fowb[i2] = (c < HID) ? f2bf(fow[r * HID + c]) : (ushort)0;
  }
}

// ================= transpose+split: fp32 [C][NPIX] -> hi/lo bf16 [NPIX][192] ==
__global__ __launch_bounds__(256) void k_tsplit(
    const float* __restrict__ X, ushort* __restrict__ Xh, ushort* __restrict__ Xl)
{
  __shared__ float ld[64][261];
  const int b = blockIdx.z;
  const int c0 = blockIdx.y * 64;
  const int px0 = blockIdx.x * 256;
  const int tid = threadIdx.x;
  #pragma unroll
  for (int i = 0; i < 16; ++i) {
    const int u = i * 256 + tid;
    const int r = u >> 6, p4 = (u & 63) * 4;
    const float4 v = *reinterpret_cast<const float4*>(
        X + ((size_t)b * CC + c0 + r) * NPIX + px0 + p4);
    ld[r][p4] = v.x; ld[r][p4 + 1] = v.y; ld[r][p4 + 2] = v.z; ld[r][p4 + 3] = v.w;
  }
  __syncthreads();
  const int c8 = (tid & 7) * 8;
  #pragma unroll
  for (int it = 0; it < 8; ++it) {
    const int pl = it * 32 + (tid >> 3);
    us8 hi, lo;
    #pragma unroll
    for (int j = 0; j < 8; ++j) {
      const float v = ld[c8 + j][pl];
      const ushort h = f2bf(v);
      hi.u[j] = h; lo.u[j] = f2bf(v - bf2f(h));
    }
    const size_t off = ((size_t)b * NPIX + px0 + pl) * CC + c0 + c8;
    *reinterpret_cast<us8*>(Xh + off) = hi;
    *reinterpret_cast<us8*>(Xl + off) = lo;
  }
}

// ================= resident NT 3-pass GEMM (q stage-1 + Fa) ==============
__global__ __launch_bounds__(256) void k_nt3res(
    const float* __restrict__ W,
    const ushort* __restrict__ Bh, const ushort* __restrict__ Bl,
    const float* __restrict__ bias, float* __restrict__ C,
    long long sAb)
{
  __shared__ ushort As[2][64][200];
  __shared__ ushort Bs[2][128][200];
  const int b = blockIdx.z;
  const int n0 = blockIdx.x * 128;
  const int m0 = blockIdx.y * 64;
  const int tid = threadIdx.x;
  const int lane = tid & 63;
  const int wave = tid >> 6;
  const int wm = wave >> 1, wn = wave & 1;
  const float*  Wb  = W  + (size_t)b * sAb;
  const ushort* Bhb = Bh + (size_t)b * NPIX * CC;
  const ushort* Blb = Bl + (size_t)b * NPIX * CC;

  #pragma unroll
  for (int i = 0; i < 12; ++i) {
    const int u = i * 256 + tid;
    const int r = u / 48, c = (u % 48) * 4;
    const float4 v = *reinterpret_cast<const float4*>(Wb + (size_t)(m0 + r) * CC + c);
    const float e[4] = {v.x, v.y, v.z, v.w};
    us4 hi, lo;
    #pragma unroll
    for (int t = 0; t < 4; ++t) {
      const ushort h = f2bf(e[t]);
      hi.u[t] = h; lo.u[t] = f2bf(e[t] - bf2f(h));
    }
    *reinterpret_cast<us4*>(&As[0][r][c]) = hi;
    *reinterpret_cast<us4*>(&As[1][r][c]) = lo;
  }
  #pragma unroll
  for (int i = 0; i < 12; ++i) {
    const int u = i * 256 + tid;
    const int r = u / 24, c = (u % 24) * 8;
    *reinterpret_cast<us8*>(&Bs[0][r][c]) =
        *reinterpret_cast<const us8*>(Bhb + (size_t)(n0 + r) * CC + c);
    *reinterpret_cast<us8*>(&Bs[1][r][c]) =
        *reinterpret_cast<const us8*>(Blb + (size_t)(n0 + r) * CC + c);
  }
  __syncthreads();

  f32x4 acc[2][4];
  #pragma unroll
  for (int i = 0; i < 2; ++i)
    #pragma unroll
    for (int j = 0; j < 4; ++j) acc[i][j] = (f32x4){0.f, 0.f, 0.f, 0.f};

  #pragma unroll
  for (int kk = 0; kk < 6; ++kk) {
    bf16x8 af[2][2], bfg[4][2];
    #pragma unroll
    for (int mi = 0; mi < 2; ++mi)
      #pragma unroll
      for (int p = 0; p < 2; ++p)
        af[mi][p] = *reinterpret_cast<const bf16x8*>(
            &As[p][wm * 32 + mi * 16 + (lane & 15)][kk * 32 + (lane >> 4) * 8]);
    #pragma unroll
    for (int ni = 0; ni < 4; ++ni)
      #pragma unroll
      for (int p = 0; p < 2; ++p)
        bfg[ni][p] = *reinterpret_cast<const bf16x8*>(
            &Bs[p][wn * 64 + ni * 16 + (lane & 15)][kk * 32 + (lane >> 4) * 8]);
    #pragma unroll
    for (int mi = 0; mi < 2; ++mi)
      #pragma unroll
      for (int ni = 0; ni < 4; ++ni) {
        acc[mi][ni] = __builtin_amdgcn_mfma_f32_16x16x32_bf16(
            af[mi][0], bfg[ni][0], acc[mi][ni], 0, 0, 0);
        acc[mi][ni] = __builtin_amdgcn_mfma_f32_16x16x32_bf16(
            af[mi][0], bfg[ni][1], acc[mi][ni], 0, 0, 0);
        acc[mi][ni] = __builtin_amdgcn_mfma_f32_16x16x32_bf16(
            af[mi][1], bfg[ni][0], acc[mi][ni], 0, 0, 0);
      }
  }

  #pragma unroll
  for (int mi = 0; mi < 2; ++mi)
    #pragma unroll
    for (int r = 0; r < 4; ++r) {
      const int m = m0 + wm * 32 + mi * 16 + (lane >> 4) * 4 + r;
      const float bv = bias[m];
      #pragma unroll
      for (int ni = 0; ni < 4; ++ni) {
        const int n = n0 + wn * 64 + ni * 16 + (lane & 15);
        C[(size_t)b * CC * NPIX + (size_t)m * NPIX + n] = acc[mi][ni][r] + bv;
      }
    }
}

// ================= merged k+v stage-1: two weight sets, one B staging ========
// blockIdx.y in [0,6): y<3 -> k-conv (W1->C1), y>=3 -> v-conv (W2->C2).
__global__ __launch_bounds__(256) void k_nt3res2(
    const float* __restrict__ W1, const float* __restrict__ W2,
    const ushort* __restrict__ Bh, const ushort* __restrict__ Bl,
    const float* __restrict__ b1, const float* __restrict__ b2,
    float* __restrict__ C1, float* __restrict__ C2)
{
  __shared__ ushort As[2][64][200];
  __shared__ ushort Bs[2][128][200];
  const int b = blockIdx.z;
  const int n0 = blockIdx.x * 128;
  const bool sel = blockIdx.y >= 3;
  const int m0 = (sel ? (blockIdx.y - 3) : blockIdx.y) * 64;
  const float* W = sel ? W2 : W1;
  const float* bias = sel ? b2 : b1;
  float* C = sel ? C2 : C1;
  const int tid = threadIdx.x;
  const int lane = tid & 63;
  const int wave = tid >> 6;
  const int wm = wave >> 1, wn = wave & 1;
  const ushort* Bhb = Bh + (size_t)b * NPIX * CC;
  const ushort* Blb = Bl + (size_t)b * NPIX * CC;

  #pragma unroll
  for (int i = 0; i < 12; ++i) {
    const int u = i * 256 + tid;
    const int r = u / 48, c = (u % 48) * 4;
    const float4 v = *reinterpret_cast<const float4*>(W + (size_t)(m0 + r) * CC + c);
    const float e[4] = {v.x, v.y, v.z, v.w};
    us4 hi, lo;
    #pragma unroll
    for (int t = 0; t < 4; ++t) {
      const ushort h = f2bf(e[t]);
      hi.u[t] = h; lo.u[t] = f2bf(e[t] - bf2f(h));
    }
    *reinterpret_cast<us4*>(&As[0][r][c]) = hi;
    *reinterpret_cast<us4*>(&As[1][r][c]) = lo;
  }
  #pragma unroll
  for (int i = 0; i < 12; ++i) {
    const int u = i * 256 + tid;
    const int r = u / 24, c = (u % 24) * 8;
    *reinterpret_cast<us8*>(&Bs[0][r][c]) =
        *reinterpret_cast<const us8*>(Bhb + (size_t)(n0 + r) * CC + c);
    *reinterpret_cast<us8*>(&Bs[1][r][c]) =
        *reinterpret_cast<const us8*>(Blb + (size_t)(n0 + r) * CC + c);
  }
  __syncthreads();

  f32x4 acc[2][4];
  #pragma unroll
  for (int i = 0; i < 2; ++i)
    #pragma unroll
    for (int j = 0; j < 4; ++j) acc[i][j] = (f32x4){0.f, 0.f, 0.f, 0.f};

  #pragma unroll
  for (int kk = 0; kk < 6; ++kk) {
    bf16x8 af[2][2], bfg[4][2];
    #pragma unroll
    for (int mi = 0; mi < 2; ++mi)
      #pragma unroll
      for (int p = 0; p < 2; ++p)
        af[mi][p] = *reinterpret_cast<const bf16x8*>(
            &As[p][wm * 32 + mi * 16 + (lane & 15)][kk * 32 + (lane >> 4) * 8]);
    #pragma unroll
    for (int ni = 0; ni < 4; ++ni)
      #pragma unroll
      for (int p = 0; p < 2; ++p)
        bfg[ni][p] = *reinterpret_cast<const bf16x8*>(
            &Bs[p][wn * 64 + ni * 16 + (lane & 15)][kk * 32 + (lane >> 4) * 8]);
    #pragma unroll
    for (int mi = 0; mi < 2; ++mi)
      #pragma unroll
      for (int ni = 0; ni < 4; ++ni) {
        acc[mi][ni] = __builtin_amdgcn_mfma_f32_16x16x32_bf16(
            af[mi][0], bfg[ni][0], acc[mi][ni], 0, 0, 0);
        acc[mi][ni] = __builtin_amdgcn_mfma_f32_16x16x32_bf16(
            af[mi][0], bfg[ni][1], acc[mi][ni], 0, 0, 0);
        acc[mi][ni] = __builtin_amdgcn_mfma_f32_16x16x32_bf16(
            af[mi][1], bfg[ni][0], acc[mi][ni], 0, 0, 0);
      }
  }

  #pragma unroll
  for (int mi = 0; mi < 2; ++mi)
    #pragma unroll
    for (int r = 0; r < 4; ++r) {
      const int m = m0 + wm * 32 + mi * 16 + (lane >> 4) * 4 + r;
      const float bv = bias[m];
      #pragma unroll
      for (int ni = 0; ni < 4; ++ni) {
        const int n = n0 + wn * 64 + ni * 16 + (lane & 15);
        C[(size_t)b * CC * NPIX + (size_t)m * NPIX + n] = acc[mi][ni][r] + bv;
      }
    }
}

// ================= fi GEMM v2: 64m x 128n, 76.8 KB LDS (2 blocks/CU) =========
// H[m][px] = sum_k fiwb[m][k]*xnt[px][k] + fib[m].  Cs aliased over As.
__global__ __launch_bounds__(256) void k_fi(
    const ushort* __restrict__ Aw, const ushort* __restrict__ Bt,
    const float* __restrict__ bias, ushort* __restrict__ H)
{
  __shared__ ushort lds[64 * 200 + 128 * 200];   // 76,800 B
  ushort (*As)[200] = reinterpret_cast<ushort(*)[200]>(lds);
  ushort (*Bs)[200] = reinterpret_cast<ushort(*)[200]>(lds + 64 * 200);
  ushort (*Cs)[132] = reinterpret_cast<ushort(*)[132]>(lds);  // over As (dead)
  const int z = blockIdx.z;
  const int n0 = blockIdx.x * 128;
  const int m0 = blockIdx.y * 64;
  const int tid = threadIdx.x;
  const int lane = tid & 63;
  const int wave = tid >> 6;
  const int wm = wave >> 1, wn = wave & 1;
  const ushort* Bb = Bt + (size_t)z * NPIX * CC;
  ushort* Hb = H + (size_t)z * 1024 * NPIX;

  #pragma unroll
  for (int i = 0; i < 6; ++i) {
    const int u = i * 256 + tid;
    const int r = u / 24, c = (u % 24) * 8;
    *reinterpret_cast<us8*>(&As[r][c]) =
        *reinterpret_cast<const us8*>(Aw + (size_t)(m0 + r) * CC + c);
  }
  #pragma unroll
  for (int i = 0; i < 12; ++i) {
    const int u = i * 256 + tid;
    const int r = u / 24, c = (u % 24) * 8;
    *reinterpret_cast<us8*>(&Bs[r][c]) =
        *reinterpret_cast<const us8*>(Bb + (size_t)(n0 + r) * CC + c);
  }
  __syncthreads();

  f32x4 acc[2][4];
  #pragma unroll
  for (int i = 0; i < 2; ++i)
    #pragma unroll
    for (int j = 0; j < 4; ++j) acc[i][j] = (f32x4){0.f, 0.f, 0.f, 0.f};

  #pragma unroll
  for (int kk = 0; kk < 6; ++kk) {
    bf16x8 af[2], bfg[4];
    #pragma unroll
    for (int mi = 0; mi < 2; ++mi)
      af[mi] = *reinterpret_cast<const bf16x8*>(
          &As[wm * 32 + mi * 16 + (lane & 15)][kk * 32 + (lane >> 4) * 8]);
    #pragma unroll
    for (int ni = 0; ni < 4; ++ni)
      bfg[ni] = *reinterpret_cast<const bf16x8*>(
          &Bs[wn * 64 + ni * 16 + (lane & 15)][kk * 32 + (lane >> 4) * 8]);
    #pragma unroll
    for (int mi = 0; mi < 2; ++mi)
      #pragma unroll
      for (int ni = 0; ni < 4; ++ni)
        acc[mi][ni] = __builtin_amdgcn_mfma_f32_16x16x32_bf16(
            af[mi], bfg[ni], acc[mi][ni], 0, 0, 0);
  }

  __syncthreads();   // As dead; Cs aliases it
  #pragma unroll
  for (int mi = 0; mi < 2; ++mi)
    #pragma unroll
    for (int rr = 0; rr < 4; ++rr) {
      const int rloc = wm * 32 + mi * 16 + (lane >> 4) * 4 + rr;
      const int m = m0 + rloc;
      const float bv = (m < HID2) ? bias[m] : 0.f;
      #pragma unroll
      for (int ni = 0; ni < 4; ++ni) {
        const int cc = wn * 64 + ni * 16 + (lane & 15);
        Cs[rloc][cc] = f2bf(acc[mi][ni][rr] + bv);
      }
    }
  __syncthreads();
  #pragma unroll
  for (int it = 0; it < 4; ++it) {
    const int r = it * 16 + (tid >> 4);
    const int c8 = (tid & 15) * 8;
    *reinterpret_cast<us8*>(Hb + (size_t)(m0 + r) * NPIX + n0 + c8) =
        *reinterpret_cast<const us8*>(&Cs[r][c8]);
  }
}

// ================= fo GEMM: A resident, B double-buffered BK=128 =============
__global__ __launch_bounds__(256) void k_fo(
    const ushort* __restrict__ Aw, const ushort* __restrict__ Bt,
    const float* __restrict__ bias, const float* __restrict__ res,
    float* __restrict__ C)
{
  __shared__ ushort As[64][520];
  __shared__ ushort Bs[2][128][136];
  const int z = blockIdx.z;
  const int n0 = blockIdx.x * 128;
  const int m0 = blockIdx.y * 64;
  const int tid = threadIdx.x;
  const int lane = tid & 63;
  const int wave = tid >> 6;
  const int wm = wave >> 1, wn = wave & 1;
  const ushort* Bb = Bt + (size_t)z * NPIX * 512;
  const float* resb = res + (size_t)z * CC * NPIX;
  float* Cb = C + (size_t)z * CC * NPIX;

  #pragma unroll
  for (int i = 0; i < 16; ++i) {
    const int u = i * 256 + tid;
    const int r = u >> 6, c = (u & 63) * 8;
    *reinterpret_cast<us8*>(&As[r][c]) =
        *reinterpret_cast<const us8*>(Aw + (size_t)(m0 + r) * 512 + c);
  }
  #pragma unroll
  for (int i = 0; i < 8; ++i) {
    const int u = i * 256 + tid;
    const int r = u >> 4, c = (u & 15) * 8;
    *reinterpret_cast<us8*>(&Bs[0][r][c]) =
        *reinterpret_cast<const us8*>(Bb + (size_t)(n0 + r) * 512 + c);
  }
  __syncthreads();

  f32x4 acc[2][4];
  #pragma unroll
  for (int i = 0; i < 2; ++i)
    #pragma unroll
    for (int j = 0; j < 4; ++j) acc[i][j] = (f32x4){0.f, 0.f, 0.f, 0.f};

  for (int t = 0; t < 4; ++t) {
    us8 rg[8];
    if (t < 3) {
      #pragma unroll
      for (int i = 0; i < 8; ++i) {
        const int u = i * 256 + tid;
        const int r = u >> 4, c = (u & 15) * 8;
        rg[i] = *reinterpret_cast<const us8*>(
            Bb + (size_t)(n0 + r) * 512 + (t + 1) * 128 + c);
      }
    }
    const int cur = t & 1;
    #pragma unroll
    for (int ks = 0; ks < 4; ++ks) {
      bf16x8 af[2], bfg[4];
      #pragma unroll
      for (int mi = 0; mi < 2; ++mi)
        af[mi] = *reinterpret_cast<const bf16x8*>(
            &As[wm * 32 + mi * 16 + (lane & 15)][t * 128 + ks * 32 + (lane >> 4) * 8]);
      #pragma unroll
      for (int ni = 0; ni < 4; ++ni)
        bfg[ni] = *reinterpret_cast<const bf16x8*>(
            &Bs[cur][wn * 64 + ni * 16 + (lane & 15)][ks * 32 + (lane >> 4) * 8]);
      #pragma unroll
      for (int mi = 0; mi < 2; ++mi)
        #pragma unroll
        for (int ni = 0; ni < 4; ++ni)
          acc[mi][ni] = __builtin_amdgcn_mfma_f32_16x16x32_bf16(
              af[mi], bfg[ni], acc[mi][ni], 0, 0, 0);
    }
    if (t < 3) {
      #pragma unroll
      for (int i = 0; i < 8; ++i) {
        const int u = i * 256 + tid;
        const int r = u >> 4, c = (u & 15) * 8;
        *reinterpret_cast<us8*>(&Bs[cur ^ 1][r][c]) = rg[i];
      }
    }
    __syncthreads();
  }

  #pragma unroll
  for (int mi = 0; mi < 2; ++mi)
    #pragma unroll
    for (int r = 0; r < 4; ++r) {
      const int m = m0 + wm * 32 + mi * 16 + (lane >> 4) * 4 + r;
      const float bv = bias[m];
      #pragma unroll
      for (int ni = 0; ni < 4; ++ni) {
        const int n = n0 + wn * 64 + ni * 16 + (lane & 15);
        Cb[(size_t)m * NPIX + n] = acc[mi][ni][r] + bv + resb[(size_t)m * NPIX + n];
      }
    }
}

// ================= attn logits: MFMA 3-pass split-K — verified ===============
__global__ __launch_bounds__(256) void k_attn_mfma(
    const ushort* __restrict__ qh, const ushort* __restrict__ ql,
    const ushort* __restrict__ kh, const ushort* __restrict__ kl,
    float* __restrict__ part)
{
  __shared__ ushort As[2][64][40];
  __shared__ ushort Bs[2][64][40];
  const int b = blockIdx.z;
  const int tr = blockIdx.x / 3, tc = blockIdx.x % 3;
  const int r0 = tr * 64, c0 = tc * 64;
  const int k0 = blockIdx.y * (NPIX / KSPLIT);
  const int tid = threadIdx.x;
  const int lane = tid & 63;
  const int wave = tid >> 6;
  const int wm = wave >> 1, wn = wave & 1;

  f32x4 acc[2][2];
  #pragma unroll
  for (int i = 0; i < 2; ++i)
    #pragma unroll
    for (int j = 0; j < 2; ++j) acc[i][j] = (f32x4){0.f, 0.f, 0.f, 0.f};

  const int ar = tid >> 2, ak = (tid & 3) * 8;

  for (int kc = 0; kc < NPIX / KSPLIT; kc += 32) {
    const size_t qo = (size_t)(b * CC + r0 + ar) * NPIX + k0 + kc + ak;
    const size_t ko = (size_t)(b * CC + c0 + ar) * NPIX + k0 + kc + ak;
    *reinterpret_cast<us8*>(&As[0][ar][ak]) = *reinterpret_cast<const us8*>(qh + qo);
    *reinterpret_cast<us8*>(&As[1][ar][ak]) = *reinterpret_cast<const us8*>(ql + qo);
    *reinterpret_cast<us8*>(&Bs[0][ar][ak]) = *reinterpret_cast<const us8*>(kh + ko);
    *reinterpret_cast<us8*>(&Bs[1][ar][ak]) = *reinterpret_cast<const us8*>(kl + ko);
    __syncthreads();
    bf16x8 af[2][2], bfr[2][2];
    #pragma unroll
    for (int mi = 0; mi < 2; ++mi)
      #pragma unroll
      for (int p = 0; p < 2; ++p)
        af[mi][p] = *reinterpret_cast<const bf16x8*>(
            &As[p][wm * 32 + mi * 16 + (lane & 15)][(lane >> 4) * 8]);
    #pragma unroll
    for (int ni = 0; ni < 2; ++ni)
      #pragma unroll
      for (int p = 0; p < 2; ++p)
        bfr[ni][p] = *reinterpret_cast<const bf16x8*>(
            &Bs[p][wn * 32 + ni * 16 + (lane & 15)][(lane >> 4) * 8]);
    #pragma unroll
    for (int mi = 0; mi < 2; ++mi)
      #pragma unroll
      for (int ni = 0; ni < 2; ++ni) {
        acc[mi][ni] = __builtin_amdgcn_mfma_f32_16x16x32_bf16(
            af[mi][0], bfr[ni][0], acc[mi][ni], 0, 0, 0);
        acc[mi][ni] = __builtin_amdgcn_mfma_f32_16x16x32_bf16(
            af[mi][0], bfr[ni][1], acc[mi][ni], 0, 0, 0);
        acc[mi][ni] = __builtin_amdgcn_mfma_f32_16x16x32_bf16(
            af[mi][1], bfr[ni][0], acc[mi][ni], 0, 0, 0);
      }
    __syncthreads();
  }

  float* pp = part + (size_t)(blockIdx.y * BB + b) * CC * CC;
  #pragma unroll
  for (int mi = 0; mi < 2; ++mi)
    #pragma unroll
    for (int r = 0; r < 4; ++r) {
      const int row = r0 + wm * 32 + mi * 16 + (lane >> 4) * 4 + r;
      #pragma unroll
      for (int ni = 0; ni < 2; ++ni) {
        const int col = c0 + wn * 32 + ni * 16 + (lane & 15);
        pp[(size_t)row * CC + col] = acc[mi][ni][r];
      }
    }
}

// ================= depthwise 3x3 (fp32, stage-1) =================
__device__ __forceinline__ void dw4(const float* __restrict__ Xc,
                                    const float* __restrict__ wt, float bv,
                                    int h, int w, float out[4])
{
  float a0, a1, a2, a3;
  a0 = a1 = a2 = a3 = bv;
  #pragma unroll
  for (int dy = 0; dy < 3; ++dy) {
    const int hh = h + dy - 1;
    if (hh < 0 || hh >= HHH) continue;
    const float* row = Xc + hh * WWW + w;
    const float xm = (w > 0) ? row[-1] : 0.f;
    const float4 xc = *reinterpret_cast<const float4*>(row);
    const float xp = (w < WWW - 4) ? row[4] : 0.f;
    const float w0 = wt[dy * 3 + 0], w1 = wt[dy * 3 + 1], w2 = wt[dy * 3 + 2];
    a0 += w0 * xm   + w1 * xc.x + w2 * xc.y;
    a1 += w0 * xc.x + w1 * xc.y + w2 * xc.z;
    a2 += w0 * xc.y + w1 * xc.z + w2 * xc.w;
    a3 += w0 * xc.z + w1 * xc.w + w2 * xp;
  }
  out[0] = a0; out[1] = a1; out[2] = a2; out[3] = a3;
}

__global__ __launch_bounds__(256) void k_dw3x3(
    const float* __restrict__ X, const float* __restrict__ W9,
    const float* __restrict__ bias, float* __restrict__ Y)
{
  const int b = blockIdx.z, c = blockIdx.y;
  const int p = blockIdx.x * 1024 + threadIdx.x * 4;
  const int h = p >> 7, w = p & 127;
  float o[4];
  dw4(X + (size_t)(b * CC + c) * NPIX, W9 + c * 9, bias[c], h, w, o);
  *reinterpret_cast<float4*>(Y + (size_t)(b * CC + c) * NPIX + p) =
      make_float4(o[0], o[1], o[2], o[3]);
}

__global__ __launch_bounds__(256) void k_dw3x3_split(
    const float* __restrict__ X, const float* __restrict__ W9,
    const float* __restrict__ bias, ushort* __restrict__ Yh,
    ushort* __restrict__ Yl)
{
  const int b = blockIdx.z, c = blockIdx.y;
  const int p = blockIdx.x * 1024 + threadIdx.x * 4;
  const int h = p >> 7, w = p & 127;
  float o[4];
  dw4(X + (size_t)(b * CC + c) * NPIX, W9 + c * 9, bias[c], h, w, o);
  us4 hi, lo;
  #pragma unroll
  for (int t = 0; t < 4; ++t) {
    const ushort hv = f2bf(o[t]);
    hi.u[t] = hv;
    lo.u[t] = f2bf(o[t] - bf2f(hv));
  }
  const size_t off = (size_t)(b * CC + c) * NPIX + p;
  *reinterpret_cast<us4*>(Yh + off) = hi;
  *reinterpret_cast<us4*>(Yl + off) = lo;
}

// ================= row L2 norms =================
__global__ __launch_bounds__(256) void k_rownorm2(
    const ushort* __restrict__ qh, const ushort* __restrict__ ql,
    const ushort* __restrict__ kh, const ushort* __restrict__ kl,
    float* __restrict__ rq, float* __restrict__ rk)
{
  const int row = blockIdx.x;
  const ushort* H = blockIdx.y ? kh : qh;
  const ushort* L = blockIdx.y ? kl : ql;
  float* R = blockIdx.y ? rk : rq;
  const ushort* Hr = H + (size_t)row * NPIX;
  const ushort* Lr = L + (size_t)row * NPIX;
  float s = 0.f;
  for (int i = threadIdx.x * 8; i < NPIX; i += 2048) {
    const us8 a = *reinterpret_cast<const us8*>(Hr + i);
    const us8 bb = *reinterpret_cast<const us8*>(Lr + i);
    #pragma unroll
    for (int t = 0; t < 8; ++t) {
      const float v = bf2f(a.u[t]) + bf2f(bb.u[t]);
      s += v * v;
    }
  }
  __shared__ float sm[256];
  sm[threadIdx.x] = s; __syncthreads();
  for (int st = 128; st > 0; st >>= 1) {
    if (threadIdx.x < st) sm[threadIdx.x] += sm[threadIdx.x + st];
    __syncthreads();
  }
  if (threadIdx.x == 0) R[row] = 1.f / fmaxf(sqrtf(sm[0]), 1e-12f);
}

// ================= softmax + topk mask =================
__global__ __launch_bounds__(192) void k_softmax_topk(
    const float* __restrict__ part, const float* __restrict__ rq,
    const float* __restrict__ rk, const float* __restrict__ temp,
    float* __restrict__ attnm)
{
  const int c = blockIdx.x, b = blockIdx.y, d = threadIdx.x;
  float s = 0.f;
  for (int ksp = 0; ksp < KSPLIT; ++ksp)
    s += part[(size_t)(ksp * BB + b) * CC * CC + c * CC + d];
  const float logit = s * rq[b * CC + c] * rk[b * CC + d] * temp[0];
  __shared__ float sa[CC], sb[CC];
  sa[d] = logit; __syncthreads();
  float mx = -FLT_MAX;
  for (int j = 0; j < CC; ++j) mx = fmaxf(mx, sa[j]);
  const float e = expf(logit - mx);
  sb[d] = e; __syncthreads();
  float sum = 0.f;
  for (int j = 0; j < CC; ++j) sum += sb[j];
  const float pv = e / sum;
  __syncthreads();
  sa[d] = pv; __syncthreads();
  int greater = 0;
  for (int j = 0; j < CC; ++j) greater += (sa[j] > pv) ? 1 : 0;
  const float cand = (greater < KKEEP) ? pv : FLT_MAX;
  sb[d] = cand; __syncthreads();
  float thr = FLT_MAX;
  for (int j = 0; j < CC; ++j) thr = fminf(thr, sb[j]);
  attnm[(size_t)(b * CC + c) * CC + d] = (pv >= thr) ? pv : 0.f;
}

// ================= M[b] = ow @ attnm[b] =================
__global__ __launch_bounds__(192) void k_mix(
    const float* __restrict__ ow, const float* __restrict__ attnm,
    float* __restrict__ M)
{
  const int c = blockIdx.x, b = blockIdx.y, d = threadIdx.x;
  float acc = 0.f;
  for (int e = 0; e < CC; ++e)
    acc += ow[c * CC + e] * attnm[(size_t)(b * CC + e) * CC + d];
  M[(size_t)(b * CC + c) * CC + d] = acc;
}

// ================= LayerNorm -> transposed bf16 [px][192] =================
__global__ __launch_bounds__(256) void k_ln_t(
    const float* __restrict__ X, const float* __restrict__ lw,
    const float* __restrict__ lb, ushort* __restrict__ Y)
{
  const int b = blockIdx.y;
  const int n = blockIdx.x * 256 + threadIdx.x;
  const float* Xb = X + (size_t)b * CC * NPIX + n;
  float s = 0.f, s2 = 0.f;
  for (int ci = 0; ci < CC; ++ci) {
    const float v = Xb[(size_t)ci * NPIX];
    s += v; s2 += v * v;
  }
  const float mu = s * (1.f / CC);
  const float var = fmaxf(s2 * (1.f / CC) - mu * mu, 0.f);
  const float rstd = rsqrtf(var + 1e-5f);
  ushort* Yb = Y + ((size_t)b * NPIX + n) * CC;
  for (int c8 = 0; c8 < CC / 8; ++c8) {
    bf16x8 sv;
    #pragma unroll
    for (int t = 0; t < 8; ++t) {
      const int c = c8 * 8 + t;
      const float v = Xb[(size_t)c * NPIX];
      sv[t] = (short)f2bf((v - mu) * rstd * lw[c] + lb[c]);
    }
    *reinterpret_cast<bf16x8*>(Yb + c8 * 8) = sv;
  }
}

// ================= fused depthwise 3x3 + GLU v3 — verified R8 ================
__device__ __forceinline__ float gelu_exact(float x) {
  return 0.5f * x * (1.f + erff(x * 0.70710678118654752f));
}

__global__ __launch_bounds__(256) void k_dwglu3(
    const ushort* __restrict__ Hp, const float* __restrict__ fdw,
    const float* __restrict__ fdb, ushort* __restrict__ gt)
{
  __shared__ ushort hs[16][4][128];
  __shared__ uint32 gsd[8 * 129];
  const int z = blockIdx.z;
  const int c0 = blockIdx.x * 8;
  const int h0 = blockIdx.y * 2;
  const int tid = threadIdx.x;
  const int npairs = min(8, HID - c0);
  const ushort* Hb = Hp + (size_t)z * 1024 * NPIX;

  #pragma unroll
  for (int i = 0; i < 4; ++i) {
    const int u = i * 256 + tid;
    const int ch = u >> 6;
    const int row = (u >> 4) & 3;
    const int w0 = (u & 15) * 8;
    const int grow = h0 - 1 + row;
    const int cloc = ch & 7;
    const int gch = (ch < 8) ? (c0 + cloc) : (HID + c0 + cloc);
    us8 v;
    #pragma unroll
    for (int t = 0; t < 8; ++t) v.u[t] = 0;
    if (c0 + cloc < HID && grow >= 0 && grow < HHH)
      v = *reinterpret_cast<const us8*>(Hb + (size_t)gch * NPIX + grow * WWW + w0);
    *reinterpret_cast<us8*>(&hs[ch][row][w0]) = v;
  }
  __syncthreads();

  const int q = tid & 63;
  const int jp = tid >> 6;
  const int px_l = q * 4;
  const int dh = px_l >> 7;
  const int w = px_l & 127;

  #pragma unroll
  for (int jj = 0; jj < 2; ++jj) {
    const int j = jp * 2 + jj;
    uint32 p0 = 0, p1 = 0;
    if (j < npairs) {
      const float* w1 = fdw + (size_t)(c0 + j) * 9;
      const float* w2 = fdw + (size_t)(HID + c0 + j) * 9;
      float x1[4], x2[4];
      const float b1 = fdb[c0 + j], b2 = fdb[HID + c0 + j];
      #pragma unroll
      for (int i = 0; i < 4; ++i) { x1[i] = b1; x2[i] = b2; }
      #pragma unroll
      for (int dy = 0; dy < 3; ++dy) {
        const int row = dh + dy;
        const ushort* r1 = &hs[j][row][0];
        const ushort* r2 = &hs[8 + j][row][0];
        const float am1 = (w > 0) ? bf2f(r1[w - 1]) : 0.f;
        const float am2 = (w > 0) ? bf2f(r2[w - 1]) : 0.f;
        const us4 c1 = *reinterpret_cast<const us4*>(&r1[w]);
        const us4 c2 = *reinterpret_cast<const us4*>(&r2[w]);
        const float ap1 = (w < 124) ? bf2f(r1[w + 4]) : 0.f;
        const float ap2 = (w < 124) ? bf2f(r2[w + 4]) : 0.f;
        const float e10 = bf2f(c1.u[0]), e11 = bf2f(c1.u[1]);
        const float e12 = bf2f(c1.u[2]), e13 = bf2f(c1.u[3]);
        const float e20 = bf2f(c2.u[0]), e21 = bf2f(c2.u[1]);
        const float e22 = bf2f(c2.u[2]), e23 = bf2f(c2.u[3]);
        const float wa0 = w1[dy * 3 + 0], wa1 = w1[dy * 3 + 1], wa2 = w1[dy * 3 + 2];
        const float wb0 = w2[dy * 3 + 0], wb1 = w2[dy * 3 + 1], wb2 = w2[dy * 3 + 2];
        x1[0] += wa0 * am1 + wa1 * e10 + wa2 * e11;
        x1[1] += wa0 * e10 + wa1 * e11 + wa2 * e12;
        x1[2] += wa0 * e11 + wa1 * e12 + wa2 * e13;
        x1[3] += wa0 * e12 + wa1 * e13 + wa2 * ap1;
        x2[0] += wb0 * am2 + wb1 * e20 + wb2 * e21;
        x2[1] += wb0 * e20 + wb1 * e21 + wb2 * e22;
        x2[2] += wb0 * e21 + wb1 * e22 + wb2 * e23;
        x2[3] += wb0 * e22 + wb1 * e23 + wb2 * ap2;
      }
      const ushort v0 = f2bf(x1[0] * gelu_exact(x2[0]));
      const ushort v1 = f2bf(x1[1] * gelu_exact(x2[1]));
      const ushort v2 = f2bf(x1[2] * gelu_exact(x2[2]));
      const ushort v3 = f2bf(x1[3] * gelu_exact(x2[3]));
      p0 = (uint32)v0 | ((uint32)v1 << 16);
      p1 = (uint32)v2 | ((uint32)v3 << 16);
    }
    gsd[j * 129 + (px_l >> 1)] = p0;
    gsd[j * 129 + (px_l >> 1) + 1] = p1;
  }
  __syncthreads();

  const ushort* gsu = (const ushort*)gsd;
  const int px_l2 = tid;
  const int px = (h0 + (px_l2 >> 7)) * WWW + (px_l2 & 127);
  us8 v;
  #pragma unroll
  for (int t = 0; t < 8; ++t) v.u[t] = gsu[t * 258 + px_l2];
  *reinterpret_cast<us8*>(gt + ((size_t)z * NPIX + px) * 512 + c0) = v;
}

// ================= launch =================
// Workspace lifetimes (P = 25,165,824; peak 185.1 MB — same as passing R8):
//  Qt [0,2P) -> dead after q stage-1
//  Fnt [2P,4P) -> dead after merged kv stage-1
//  qh [4P,5P) ql [5P,6P) -> dead after attn
//  v-stage1 temp [0,2P) (over Qt) -> dead after dw-v
//  vbuf fp32 [2P,4P) (over Fnt) -> dead after v-tsplit
//  kh [0,P) kl [P,2P) (over v-temp, written AFTER dw-v) -> dead after attn
//  smalls [6P,6P+10.7M) -> dead after Fa gemm
//  vth [0,P) vtl [P,2P) (over kh/kl) -> dead after Fa gemm
//  Fa [4P,6P) (over qh/ql), live to end;  xnt [0,P) (over vth)
//  h2 [P,P+67.1M);  gt2 [6P,6P+33.6M);  fiwb/fowb after gt2
extern "C" void kernel_launch(void* const* d_in, const int* in_sizes, int n_in,
                              void* d_out, int out_size, void* d_ws, size_t ws_size,
                              hipStream_t stream)
{
  const float* Q    = (const float*)d_in[0];
  const float* Fn   = (const float*)d_in[1];
  const float* temp = (const float*)d_in[2];
  const float* qw1  = (const float*)d_in[3];
  const float* qb1  = (const float*)d_in[4];
  const float* qw2  = (const float*)d_in[5];
  const float* qb2  = (const float*)d_in[6];
  const float* kw1  = (const float*)d_in[7];
  const float* kb1  = (const float*)d_in[8];
  const float* kw2  = (const float*)d_in[9];
  const float* kb2  = (const float*)d_in[10];
  const float* vw1  = (const float*)d_in[11];
  const float* vb1  = (const float*)d_in[12];
  const float* vw2  = (const float*)d_in[13];
  const float* vb2  = (const float*)d_in[14];
  const float* ow   = (const float*)d_in[15];
  const float* ob   = (const float*)d_in[16];
  const float* lnw  = (const float*)d_in[17];
  const float* lnb  = (const float*)d_in[18];
  const float* fiw  = (const float*)d_in[19];
  const float* fib  = (const float*)d_in[20];
  const float* fdw  = (const float*)d_in[21];
  const float* fdb  = (const float*)d_in[22];
  const float* fow  = (const float*)d_in[23];
  const float* fob  = (const float*)d_in[24];
  float* out = (float*)d_out;

  char* ws = (char*)d_ws;
  const size_t P = 25165824UL;
  ushort* Qth = (ushort*)(ws + 0 * P);
  ushort* Qtl = (ushort*)(ws + 1 * P);
  ushort* Fth = (ushort*)(ws + 2 * P);
  ushort* Ftl = (ushort*)(ws + 3 * P);
  ushort* qh  = (ushort*)(ws + 4 * P);
  ushort* ql  = (ushort*)(ws + 5 * P);
  float*  vtmp = (float*)(ws + 0 * P);   // v stage-1 out (over Qt)
  float*  vbuf = (float*)(ws + 2 * P);   // v after dw (over Fnt)
  ushort* kh  = (ushort*)(ws + 0 * P);   // written after dw-v
  ushort* kl  = (ushort*)(ws + 1 * P);
  ushort* vth = (ushort*)(ws + 0 * P);   // over kh/kl after attn
  ushort* vtl = (ushort*)(ws + 1 * P);
  char* smb = ws + 6 * P;
  float* rq    = (float*)(smb);
  float* rk    = (float*)(smb + 4096);
  float* part  = (float*)(smb + 8192);
  float* attnm = (float*)(smb + 8192 + 9437184);
  float* Mm    = (float*)(smb + 8192 + 9437184 + 589824);
  float*  Fa   = (float*)(ws + 4 * P);
  ushort* xnt  = (ushort*)(ws + 0 * P);
  ushort* h2   = (ushort*)(ws + 1 * P);
  ushort* gt2  = (ushort*)(ws + 6 * P);
  ushort* fiwb = (ushort*)(ws + 6 * P + 33554432UL);
  ushort* fowb = (ushort*)(ws + 6 * P + 33554432UL + 393216UL);
  float* bufT = out;

  dim3 blk(256);

  // weight preconvert + input transpose-splits
  k_wconv<<<dim3(1152), blk, 0, stream>>>(fiw, fow, fiwb, fowb);
  k_tsplit<<<dim3(64, 3, BB), blk, 0, stream>>>(Q,  Qth, Qtl);
  k_tsplit<<<dim3(64, 3, BB), blk, 0, stream>>>(Fn, Fth, Ftl);
  // q stage-1 + dw
  k_nt3res<<<dim3(128, 3, BB), blk, 0, stream>>>(qw1, Qth, Qtl, qb1, bufT, 0);
  k_dw3x3_split<<<dim3(16, CC, BB), blk, 0, stream>>>(bufT, qw2, qb2, qh, ql);
  // merged k+v stage-1 (one B staging), then dw-v (frees Fnt) then dw-k
  k_nt3res2<<<dim3(128, 6, BB), blk, 0, stream>>>(kw1, vw1, Fth, Ftl,
                                                  kb1, vb1, bufT, vtmp);
  k_dw3x3<<<dim3(16, CC, BB), blk, 0, stream>>>(vtmp, vw2, vb2, vbuf);
  k_dw3x3_split<<<dim3(16, CC, BB), blk, 0, stream>>>(bufT, kw2, kb2, kh, kl);
  // norms + attention
  k_rownorm2<<<dim3(BB * CC, 2), blk, 0, stream>>>(qh, ql, kh, kl, rq, rk);
  k_attn_mfma<<<dim3(9, KSPLIT, BB), blk, 0, stream>>>(qh, ql, kh, kl, part);
  k_softmax_topk<<<dim3(CC, BB), dim3(192), 0, stream>>>(part, rq, rk, temp, attnm);
  k_mix<<<dim3(CC, BB), dim3(192), 0, stream>>>(ow, attnm, Mm);
  // v -> transposed hi/lo planes (over dead kh/kl), then resident Fa gemm
  k_tsplit<<<dim3(64, 3, BB), blk, 0, stream>>>(vbuf, vth, vtl);
  k_nt3res<<<dim3(128, 3, BB), blk, 0, stream>>>(Mm, vth, vtl, ob, Fa,
                                                 (long long)CC * CC);
  // LN -> xnt
  k_ln_t<<<dim3(64, BB), blk, 0, stream>>>(Fa, lnw, lnb, xnt);
  // FFN in 2-batch pairs: fi -> dwglu -> fo
  for (int p = 0; p < 2; ++p) {
    const ushort* xn_p = xnt + (size_t)(2 * p) * NPIX * CC;
    const float*  fa_p = Fa + (size_t)(2 * p) * CC * NPIX;
    float* out_p = out + (size_t)(2 * p) * CC * NPIX;
    k_fi<<<dim3(128, 16, 2), blk, 0, stream>>>(fiwb, xn_p, fib, h2);
    k_dwglu3<<<dim3(64, 64, 2), blk, 0, stream>>>(h2, fdw, fdb, gt2);
    k_fo<<<dim3(128, 3, 2), blk, 0, stream>>>(fowb, gt2, fob, fa_p, out_p);
  }
}